// Round 7
// baseline (1237.756 us; speedup 1.0000x reference)
//
#include <hip/hip_runtime.h>
#include <hip/hip_bf16.h>
#include <math.h>

#define N_NODE 30000
#define N_TRI  200000
#define DIM    128
#define OUTD   768
#define BATCH  2048
#define NROWA  4096
#define EPAD   30080   // 235*128
#define PADN   80      // EPAD - N_NODE
#define NTILE_E 235
#define NTILE_A 32
#define TILE_ELEMS (128*OUTD)
#define KBLK_ELEMS (128*32)
#define GAMMA_C 3.0f
#define LAMB_C  30.0f
#define TAU_C   10.0f

typedef __attribute__((ext_vector_type(8))) __bf16 bf16x8;
typedef __attribute__((ext_vector_type(2))) __bf16 bf16x2;
typedef __attribute__((ext_vector_type(4))) float f32x4;

__device__ __forceinline__ float waveSum(float v){
#pragma unroll
  for (int m=1;m<64;m<<=1) v += __shfl_xor(v, m, 64);
  return v;
}
__device__ __forceinline__ float waveMax(float v){
#pragma unroll
  for (int m=1;m<64;m<<=1) v = fmaxf(v, __shfl_xor(v, m, 64));
  return v;
}

__device__ __forceinline__ void atomicMinF(float* a, float v){
  if (v >= 0.f) atomicMin((int*)a, __float_as_int(v));
  else          atomicMax((unsigned int*)a, __float_as_uint(v));
}

__device__ __forceinline__ void gl2lds16(const void* g, void* l){
  __builtin_amdgcn_global_load_lds(
      (const __attribute__((address_space(1))) char*)g,
      (__attribute__((address_space(3))) char*)l, 16, 0, 0);
}

__device__ __forceinline__ int swz_off(int r, int q){
  return r*32 + ((q ^ ((r>>1)&3))<<3);
}

// ---------------- fill ----------------
__global__ void k_fill(float* __restrict__ p, long n, float v){
  long i = (long)blockIdx.x*blockDim.x + threadIdx.x;
  long st = (long)gridDim.x*blockDim.x;
  for (; i<n; i+=st) p[i]=v;
}

// ---------------- CSR build ----------------
__global__ __launch_bounds__(256) void k_hist(const int* __restrict__ rows, int* __restrict__ cnt){
  int t = blockIdx.x*256 + threadIdx.x;
  if (t < N_TRI) atomicAdd(&cnt[rows[t]], 1);
}

__global__ __launch_bounds__(256) void k_scan3(
    const int* __restrict__ c0, int* __restrict__ r0,
    const int* __restrict__ c1, int* __restrict__ r1,
    const int* __restrict__ c2, int* __restrict__ r2, int n){
  const int* cnt = blockIdx.x==0 ? c0 : (blockIdx.x==1 ? c1 : c2);
  int* rp        = blockIdx.x==0 ? r0 : (blockIdx.x==1 ? r1 : r2);
  __shared__ int buf[256];
  __shared__ int carry;
  if (threadIdx.x==0) carry = 0;
  __syncthreads();
  for (int base=0; base<n; base+=256){
    int i = base + threadIdx.x;
    int v = (i<n) ? cnt[i] : 0;
    buf[threadIdx.x] = v;
    __syncthreads();
    for (int off=1; off<256; off<<=1){
      int t = (threadIdx.x>=off) ? buf[threadIdx.x-off] : 0;
      __syncthreads();
      buf[threadIdx.x] += t;
      __syncthreads();
    }
    if (i<n) rp[i] = carry + buf[threadIdx.x] - v;
    int tot = buf[255];
    __syncthreads();
    if (threadIdx.x==0) carry += tot;
    __syncthreads();
  }
  if (threadIdx.x==0) rp[n] = carry;
}

__global__ __launch_bounds__(256) void k_place(const int* __restrict__ rows, const int* __restrict__ vals,
                        const int* __restrict__ rowptr, int* __restrict__ cur, int* __restrict__ idx, int mode){
  int t = blockIdx.x*256 + threadIdx.x;
  if (t < N_TRI){
    int r = rows[t];
    int p = atomicAdd(&cur[r], 1);
    idx[rowptr[r] + p] = mode ? vals[t] : t;
  }
}

// ---------------- fused sparse means + tanh ----------------
__global__ __launch_bounds__(256) void k_feat0(
    const int* __restrict__ rpE, const int* __restrict__ idxE,
    const int* __restrict__ rpR, const int* __restrict__ idxR,
    const float* __restrict__ ent_emb, const float* __restrict__ rel_emb,
    float* __restrict__ out){
  int wave = threadIdx.x>>6, lane = threadIdx.x&63;
  int i = blockIdx.x*4 + wave;
  if (i >= N_NODE) return;
  int bE = rpE[i], eE = rpE[i+1];
  int bR = rpR[i], eR = rpR[i+1];
  float2 aE = {0.f,0.f}, aR = {0.f,0.f};
  for (int k=bE; k<eE; ++k){
    int c = idxE[k];
    float2 v = *(const float2*)(ent_emb + (size_t)c*DIM + lane*2);
    aE.x += v.x; aE.y += v.y;
  }
  for (int k=bR; k<eR; ++k){
    int c = idxR[k];
    float2 v = *(const float2*)(rel_emb + (size_t)c*DIM + lane*2);
    aR.x += v.x; aR.y += v.y;
  }
  float ie = 1.f/fmaxf((float)(eE-bE), 1.f);
  float ir = 1.f/fmaxf((float)(eR-bR), 1.f);
  float2 oE = { tanhf(aE.x*ie), tanhf(aE.y*ie) };
  float2 oR = { tanhf(aR.x*ir), tanhf(aR.y*ir) };
  *(float2*)(out + (size_t)i*OUTD +   0 + lane*2) = oE;
  *(float2*)(out + (size_t)i*OUTD + 384 + lane*2) = oR;
}

// ---------------- tri_rel + norm(bf16) + att logits + LAYER-1 dots ----------------
// u_t in registers: also compute dotA = u.out[c,0:128], dotB = u.out[c,384:512]
__global__ __launch_bounds__(256) void k_trinorm(
    const int* __restrict__ ridx1, const float* __restrict__ rval,
    const float* __restrict__ rel_emb, const int* __restrict__ cols,
    const float* __restrict__ out,
    __bf16* __restrict__ tri, const float* __restrict__ attnE,
    const float* __restrict__ attnR, float* __restrict__ att4,
    float* __restrict__ dotA, float* __restrict__ dotB){
  __shared__ float ak[4][DIM];
  int tid = threadIdx.x;
  for (int idx=tid; idx<4*DIM; idx+=256){
    int k = idx>>7, d = idx&127;
    ak[k][d] = (k<2) ? attnE[k*DIM + d] : attnR[(k-2)*DIM + d];
  }
  __syncthreads();
  int wave = tid>>6, lane = tid&63;
  int t = blockIdx.x*4 + wave;
  if (t >= N_TRI) return;
  int rr = ridx1[t];
  float rv = rval[t];
  float2 v = *(const float2*)(rel_emb + (size_t)rr*DIM + lane*2);
  v.x *= rv; v.y *= rv;
  float ss = waveSum(v.x*v.x + v.y*v.y);
  float inv = 1.f/fmaxf(sqrtf(ss), 1e-12f);
  v.x *= inv; v.y *= inv;
  bf16x2 b; b[0] = (__bf16)v.x; b[1] = (__bf16)v.y;
  *(bf16x2*)(tri + (size_t)t*DIM + lane*2) = b;
  float ux = (float)b[0], uy = (float)b[1];
#pragma unroll
  for (int k=0;k<4;k++){
    float p = waveSum(v.x*ak[k][lane*2] + v.y*ak[k][lane*2+1]);
    if (lane==0) att4[(size_t)k*N_TRI + t] = p;
  }
  // layer-1 dots
  int c = cols[t];
  float2 fA = *(const float2*)(out + (size_t)c*OUTD +   0 + lane*2);
  float2 fB = *(const float2*)(out + (size_t)c*OUTD + 384 + lane*2);
  float dA = waveSum(fA.x*ux + fA.y*uy);
  float dB = waveSum(fB.x*ux + fB.y*uy);
  if (lane==0){ dotA[t] = dA; dotB[t] = dB; }
}

// ---------------- per-triple dots for layer 2 ----------------
__global__ __launch_bounds__(256) void k_tdot(
    const int* __restrict__ cols, const __bf16* __restrict__ tri,
    const float* __restrict__ out, int inA, int inB,
    float* __restrict__ dotA, float* __restrict__ dotB){
  int wave = threadIdx.x>>6, lane = threadIdx.x&63;
  int t = blockIdx.x*4 + wave;
  if (t >= N_TRI) return;
  int c = cols[t];
  bf16x2 ub = *(const bf16x2*)(tri + (size_t)t*DIM + lane*2);
  float ux = (float)ub[0], uy = (float)ub[1];
  float2 fA = *(const float2*)(out + (size_t)c*OUTD + inA + lane*2);
  float2 fB = *(const float2*)(out + (size_t)c*OUTD + inB + lane*2);
  float dA = waveSum(fA.x*ux + fA.y*uy);
  float dB = waveSum(fB.x*ux + fB.y*uy);
  if (lane==0){ dotA[t] = dA; dotB[t] = dB; }
}

// ---------------- fused GAT layer (both branches), precomputed dots ----------------
__global__ __launch_bounds__(256) void k_gat(
    const int* __restrict__ rowptr, const int* __restrict__ idx, const int* __restrict__ cols,
    const __bf16* __restrict__ tri,
    const float* __restrict__ attA, const float* __restrict__ attB,
    const float* __restrict__ dotA, const float* __restrict__ dotB,
    float* __restrict__ out, int inA, int outA, int inB, int outB){
  int wave = threadIdx.x>>6, lane = threadIdx.x&63;
  int i = blockIdx.x*4 + wave;
  if (i >= N_NODE) return;
  int beg = rowptr[i], end = rowptr[i+1];
  float2 accA = {0.f,0.f}, accB = {0.f,0.f};
  if (end > beg){
    float mA = -1e30f, mB = -1e30f;
    for (int k=beg+lane; k<end; k+=64){
      int t = idx[k];
      mA = fmaxf(mA, attA[t]); mB = fmaxf(mB, attB[t]);
    }
    mA = waveMax(mA); mB = waveMax(mB);
    float zA = 0.f, zB = 0.f;
    for (int k=beg+lane; k<end; k+=64){
      int t = idx[k];
      zA += __expf(attA[t]-mA); zB += __expf(attB[t]-mB);
    }
    zA = waveSum(zA); zB = waveSum(zB);
    float izA = 1.f/zA, izB = 1.f/zB;
    for (int k=beg; k<end; ++k){
      int t = idx[k];
      int c = cols[t];
      bf16x2 ub = *(const bf16x2*)(tri + (size_t)t*DIM + lane*2);
      float ux = (float)ub[0], uy = (float)ub[1];
      float2 fA = *(const float2*)(out + (size_t)c*OUTD + inA + lane*2);
      float2 fB = *(const float2*)(out + (size_t)c*OUTD + inB + lane*2);
      float dA2 = 2.f*dotA[t], dB2 = 2.f*dotB[t];
      float wA = __expf(attA[t]-mA)*izA;
      float wB = __expf(attB[t]-mB)*izB;
      accA.x = fmaf(wA, fmaf(-dA2, ux, fA.x), accA.x);
      accA.y = fmaf(wA, fmaf(-dA2, uy, fA.y), accA.y);
      accB.x = fmaf(wB, fmaf(-dB2, ux, fB.x), accB.x);
      accB.y = fmaf(wB, fmaf(-dB2, uy, fB.y), accB.y);
    }
  }
  float2 oA = { tanhf(accA.x), tanhf(accA.y) };
  float2 oB = { tanhf(accB.x), tanhf(accB.y) };
  *(float2*)(out + (size_t)i*OUTD + outA + lane*2) = oA;
  *(float2*)(out + (size_t)i*OUTD + outB + lane*2) = oB;
}

// ---------------- pack E ----------------
__global__ __launch_bounds__(256) void k_packE(const float* __restrict__ out, __bf16* __restrict__ Ep, float* __restrict__ esq){
  int wave = threadIdx.x>>6, lane = threadIdx.x&63;
  int j = blockIdx.x*4 + wave;
  if (j >= EPAD) return;
  int jt = j>>7, r = j&127;
  __bf16* tb = Ep + (size_t)jt*TILE_ELEMS;
  float ss = 0.f;
  for (int c=lane; c<96; c+=64){
    int kb = c>>2, q = c&3;
    bf16x8 o;
    if (j < N_NODE){
      const float* src = out + (size_t)j*OUTD + c*8;
#pragma unroll
      for (int e=0;e<8;e++){ float v = src[e]; ss += v*v; o[e] = (__bf16)v; }
    } else {
#pragma unroll
      for (int e=0;e<8;e++) o[e] = (__bf16)0.f;
    }
    *(bf16x8*)(tb + kb*KBLK_ELEMS + swz_off(r, q)) = o;
  }
  ss = waveSum(ss);
  if (lane==0) esq[j] = (j < N_NODE) ? ss : 0.f;
}

__global__ __launch_bounds__(256) void k_packA(const int* __restrict__ pairs, const __bf16* __restrict__ Ep,
    const float* __restrict__ out, const float* __restrict__ esq,
    __bf16* __restrict__ Ap, float* __restrict__ asq, float* __restrict__ pos){
  int wave = threadIdx.x>>6, lane = threadIdx.x&63;
  int p = blockIdx.x*4 + wave;
  if (p >= BATCH) return;
  int l = pairs[2*p], r = pairs[2*p+1];
  float ss = 0.f;
#pragma unroll
  for (int c=0;c<12;c++){
    int d = c*64 + lane;
    float dl = out[(size_t)l*OUTD + d], dr = out[(size_t)r*OUTD + d];
    ss += (dl-dr)*(dl-dr);
  }
  ss = waveSum(ss);
  if (lane==0){ pos[p] = ss; asq[p] = esq[l]; asq[p+BATCH] = esq[r]; }
  int lt = l>>7, lr = l&127;
  int rt2 = r>>7, rr = r&127;
  int p0t = p>>7, p0r = p&127;
  int p1t = (p+BATCH)>>7, p1r = (p+BATCH)&127;
  for (int c=lane; c<96; c+=64){
    int kb = c>>2, q = c&3;
    bf16x8 vl = *(const bf16x8*)(Ep + (size_t)lt*TILE_ELEMS + kb*KBLK_ELEMS + swz_off(lr, q));
    *(bf16x8*)(Ap + (size_t)p0t*TILE_ELEMS + kb*KBLK_ELEMS + swz_off(p0r, q)) = vl;
    bf16x8 vr = *(const bf16x8*)(Ep + (size_t)rt2*TILE_ELEMS + kb*KBLK_ELEMS + swz_off(rr, q));
    *(bf16x8*)(Ap + (size_t)p1t*TILE_ELEMS + kb*KBLK_ELEMS + swz_off(p1r, q)) = vr;
  }
}

// ---------------- GEMM (BK=64): pass1 = moments; pass2 = exp ----------------
__global__ __launch_bounds__(256) void k_gemm(
    const __bf16* __restrict__ Ap, const __bf16* __restrict__ Ep,
    const float* __restrict__ asq, const float* __restrict__ esq,
    const float* __restrict__ pos, const int* __restrict__ pairs,
    float* __restrict__ rs1, float* __restrict__ rs2, float* __restrict__ rmin,
    const float* __restrict__ CC, const float* __restrict__ AL,
    float* __restrict__ rexp, int pass)
{
  __shared__ __bf16 sA[2*KBLK_ELEMS];   // 16 KB
  __shared__ __bf16 sB[2*KBLK_ELEMS];   // 16 KB
  __shared__ float red[768];
  int tid = threadIdx.x;

  int wave = tid>>6, lane = tid&63, quad = lane>>4, l16 = lane&15;
  int bi = blockIdx.x, bj = blockIdx.y;
  int wi = wave>>1, wj = wave&1;

  const __bf16* Asrc = Ap + (size_t)bi*TILE_ELEMS;
  const __bf16* Bsrc = Ep + (size_t)bj*TILE_ELEMS;

  int a_off[4], b_off[4];
#pragma unroll
  for (int rt=0; rt<4; ++rt){ int row = wi*64 + rt*16 + l16; a_off[rt] = swz_off(row, quad); }
#pragma unroll
  for (int ct=0; ct<4; ++ct){ int row = wj*64 + ct*16 + l16; b_off[ct] = swz_off(row, quad); }

  const __bf16* gsrc = (wave<2 ? Asrc : Bsrc);
  __bf16* ldsb = (wave<2 ? sA : sB);
  int half = (wave&1)*KBLK_ELEMS;   // each wave stages one 4096-elem k-block

  const f32x4 zf = {0.f,0.f,0.f,0.f};
  f32x4 acc[4][4];
#pragma unroll
  for (int rt=0; rt<4; ++rt)
#pragma unroll
    for (int ct=0; ct<4; ++ct) acc[rt][ct] = zf;

  for (int kb2=0; kb2<12; ++kb2){
    __syncthreads();
    const __bf16* g = gsrc + kb2*(2*KBLK_ELEMS) + half + lane*8;
#pragma unroll
    for (int s=0; s<8; ++s)
      gl2lds16(g + s*512, ldsb + half + s*512);
    __syncthreads();
#pragma unroll
    for (int ks=0; ks<2; ++ks){
      int o = ks*KBLK_ELEMS;
      bf16x8 af[4], bf[4];
#pragma unroll
      for (int rt=0; rt<4; ++rt) af[rt] = *(const bf16x8*)(sA + o + a_off[rt]);
#pragma unroll
      for (int ct=0; ct<4; ++ct) bf[ct] = *(const bf16x8*)(sB + o + b_off[ct]);
#pragma unroll
      for (int rt=0; rt<4; ++rt)
#pragma unroll
        for (int ct=0; ct<4; ++ct)
          acc[rt][ct] = __builtin_amdgcn_mfma_f32_16x16x32_bf16(af[rt], bf[ct], acc[rt][ct], 0,0,0);
    }
  }

  // ---- epilogue ----
  int jbase = bj*128 + wj*64;
  float esqv[4]; bool val[4]; int jcol[4];
#pragma unroll
  for (int ct=0; ct<4; ++ct){
    jcol[ct] = jbase + ct*16 + l16;
    val[ct] = jcol[ct] < N_NODE;
    esqv[ct] = esq[jcol[ct]];
  }

  if (pass == 1){
#pragma unroll
    for (int rt=0; rt<4; ++rt){
#pragma unroll
      for (int reg=0; reg<4; ++reg){
        int il = wi*64 + rt*16 + quad*4 + reg;
        int i  = bi*128 + il;
        int p  = i & (BATCH-1);
        int li = pairs[2*p], ri = pairs[2*p+1];
        float av = asq[i];
        float s=0.f, q=0.f, mn=1e30f;
#pragma unroll
        for (int ct=0; ct<4; ++ct){
          float neg = (av + esqv[ct]) - 2.f*acc[rt][ct][reg];
          s += neg;
          q = fmaf(neg, neg, q);
          bool bad = (jcol[ct]==li) | (jcol[ct]==ri) | (!val[ct]);
          mn = fminf(mn, bad ? 1e30f : neg);
        }
#pragma unroll
        for (int m=1;m<16;m<<=1){
          s += __shfl_xor(s,m,64); q += __shfl_xor(q,m,64);
          mn = fminf(mn, __shfl_xor(mn,m,64));
        }
        if (l16 == 0){
          red[il*2+wj] = s; red[256 + il*2+wj] = q; red[512 + il*2+wj] = mn;
        }
      }
    }
    __syncthreads();
    if (tid < 128){
      int i = bi*128 + tid;
      atomicAdd(rs1+i, red[tid*2] + red[tid*2+1]);
      atomicAdd(rs2+i, red[256 + tid*2] + red[256 + tid*2+1]);
      atomicMinF(rmin+i, fminf(red[512 + tid*2], red[512 + tid*2+1]));
    }
  } else {
#pragma unroll
    for (int rt=0; rt<4; ++rt){
#pragma unroll
      for (int reg=0; reg<4; ++reg){
        int il = wi*64 + rt*16 + quad*4 + reg;
        int i  = bi*128 + il;
        int p  = i & (BATCH-1);
        int li = pairs[2*p], ri = pairs[2*p+1];
        float av = asq[i];
        float C = CC[i], A = AL[i];
        float s = 0.f;
#pragma unroll
        for (int ct=0; ct<4; ++ct){
          float neg = (av + esqv[ct]) - 2.f*acc[rt][ct][reg];
          bool bad = (jcol[ct]==li) | (jcol[ct]==ri) | (!val[ct]);
          s += bad ? 0.f : __expf(fmaf(-A, neg, C));
        }
#pragma unroll
        for (int m=1;m<16;m<<=1) s += __shfl_xor(s,m,64);
        if (l16 == 0) red[il*2+wj] = s;
      }
    }
    __syncthreads();
    if (tid < 128){
      int i = bi*128 + tid;
      atomicAdd(rexp+i, red[tid*2] + red[tid*2+1]);
    }
  }
}

// ---------------- per-row special-column dots ----------------
__global__ __launch_bounds__(256) void k_corr(
    const int* __restrict__ pairs, const __bf16* __restrict__ Ap, const __bf16* __restrict__ Ep,
    const float* __restrict__ asq, const float* __restrict__ esq,
    float* __restrict__ negl, float* __restrict__ negr)
{
  int wave = threadIdx.x>>6, lane = threadIdx.x&63;
  int i = blockIdx.x*4 + wave;
  if (i >= NROWA) return;
  int p = i & (BATCH-1);
  int li = pairs[2*p], ri = pairs[2*p+1];
  const __bf16* Ar = Ap + (size_t)(i>>7)*TILE_ELEMS;  int ra = i&127;
  const __bf16* E1 = Ep + (size_t)(li>>7)*TILE_ELEMS; int r1 = li&127;
  const __bf16* E2 = Ep + (size_t)(ri>>7)*TILE_ELEMS; int r2 = ri&127;
  float d1=0.f, d2=0.f;
  for (int c=lane; c<96; c+=64){
    int kb = c>>2, q = c&3;
    bf16x8 a  = *(const bf16x8*)(Ar + kb*KBLK_ELEMS + swz_off(ra, q));
    bf16x8 e1 = *(const bf16x8*)(E1 + kb*KBLK_ELEMS + swz_off(r1, q));
    bf16x8 e2 = *(const bf16x8*)(E2 + kb*KBLK_ELEMS + swz_off(r2, q));
#pragma unroll
    for (int e=0;e<8;e++){
      d1 = fmaf((float)a[e], (float)e1[e], d1);
      d2 = fmaf((float)a[e], (float)e2[e], d2);
    }
  }
  d1 = waveSum(d1); d2 = waveSum(d2);
  if (lane==0){
    float av = asq[i];
    negl[i] = av + esq[li] - 2.f*d1;
    negr[i] = av + esq[ri] - 2.f*d2;
  }
}

// ---------------- stats ----------------
__global__ __launch_bounds__(256) void k_stats(
    const float* __restrict__ rs1, const float* __restrict__ rs2, const float* __restrict__ rmin,
    const float* __restrict__ negl, const float* __restrict__ negr,
    const float* __restrict__ asq, const float* __restrict__ pos, const int* __restrict__ pairs,
    float* __restrict__ MM, float* __restrict__ CC, float* __restrict__ AL, float* __restrict__ rexp)
{
  int i = blockIdx.x*256 + threadIdx.x;
  if (i >= NROWA) return;
  int p = i & (BATCH-1);
  int li = pairs[2*p], ri = pairs[2*p+1];
  float K = pos[p] + GAMMA_C;
  float av = asq[i];
  float S1 = rs1[i] - (float)PADN*av;
  float S2 = rs2[i] - (float)PADN*av*av;
  float nl = negl[i], nr = negr[i];
  float Sx, Sxx, mx;
  const float invN = 1.f/(float)N_NODE;
  if (li != ri){
    Sx  = -(S1 - nl - nr) - 2.f*K;
    Sxx = (S2 - nl*nl - nr*nr) + 2.f*K*K;
    mx  = fmaxf(K - rmin[i], 0.f);
    float mu = K + Sx*invN;
    float m2 = Sx*invN;
    float var = Sxx*invN - m2*m2;
    float sd = sqrtf(fmaxf(var, 1e-30f));
    float M = LAMB_C*(mx-mu)/sd + TAU_C;
    MM[i] = M; CC[i] = LAMB_C*(K-mu)/sd + TAU_C - M; AL[i] = LAMB_C/sd;
    rexp[i] = 2.f*__expf(LAMB_C*(0.f-mu)/sd + TAU_C - M);
  } else {
    float lossm = nl - K;
    float x = lossm - K;
    Sx  = -(S1 - nl) + x;
    Sxx = (S2 - nl*nl) + x*x;
    mx  = fmaxf(K - rmin[i], lossm);
    float mu = K + Sx*invN;
    float m2 = Sx*invN;
    float var = Sxx*invN - m2*m2;
    float sd = sqrtf(fmaxf(var, 1e-30f));
    float M = LAMB_C*(mx-mu)/sd + TAU_C;
    MM[i] = M; CC[i] = LAMB_C*(K-mu)/sd + TAU_C - M; AL[i] = LAMB_C/sd;
    rexp[i] = __expf(LAMB_C*(lossm-mu)/sd + TAU_C - M);
  }
}

__global__ __launch_bounds__(256) void k_final(const float* __restrict__ mm, const float* __restrict__ rexp, float* __restrict__ out){
  __shared__ float red[256];
  float s = 0.f;
  for (int i=threadIdx.x; i<NROWA; i+=256) s += mm[i] + logf(rexp[i]);
  red[threadIdx.x] = s; __syncthreads();
  for (int st=128; st>0; st>>=1){ if (threadIdx.x<st) red[threadIdx.x]+=red[threadIdx.x+st]; __syncthreads(); }
  if (threadIdx.x==0) out[0] = red[0]*(1.f/BATCH);
}

extern "C" void kernel_launch(void* const* d_in, const int* in_sizes, int n_in,
                              void* d_out, int out_size, void* d_ws, size_t ws_size,
                              hipStream_t stream) {
  const int*   pairs   = (const int*)d_in[0];
  const int*   ent_adj = (const int*)d_in[1];
  const int*   rel_adj = (const int*)d_in[2];
  const int*   adj     = (const int*)d_in[3];
  const int*   r_index = (const int*)d_in[4];
  const float* r_val   = (const float*)d_in[5];
  const float* ent_emb = (const float*)d_in[7];
  const float* rel_emb = (const float*)d_in[8];
  const float* attn_e  = (const float*)d_in[9];
  const float* attn_r  = (const float*)d_in[10];

  char* base = (char*)d_ws;
  size_t off = 0;
  auto take = [&](size_t bytes)->char*{
    char* p = base + off;
    off = (off + bytes + 511) & ~(size_t)511;
    return p;
  };
  // persistent GEMM-phase region
  __bf16* EP    = (__bf16*)take((size_t)NTILE_E*TILE_ELEMS*2); // 46.2 MB
  __bf16* AP    = (__bf16*)take((size_t)NTILE_A*TILE_ELEMS*2); // 6.3 MB
  float*  ESQ   = (float*)take((size_t)EPAD*4);
  float*  ASQ   = (float*)take((size_t)NROWA*4);
  float*  POS   = (float*)take((size_t)BATCH*4);
  float*  RS1   = (float*)take((size_t)NROWA*4);
  float*  RS2   = (float*)take((size_t)NROWA*4);
  float*  RMIN  = (float*)take((size_t)NROWA*4);
  float*  NEGL  = (float*)take((size_t)NROWA*4);
  float*  NEGR  = (float*)take((size_t)NROWA*4);
  float*  MM    = (float*)take((size_t)NROWA*4);
  float*  CCv   = (float*)take((size_t)NROWA*4);
  float*  ALv   = (float*)take((size_t)NROWA*4);
  float*  REXP  = (float*)take((size_t)NROWA*4);

  // graph-phase region
  float*  OUT  = (float*)take((size_t)N_NODE*OUTD*4);      // 92.16 MB
  __bf16* TRI  = (__bf16*)take((size_t)N_TRI*DIM*2);       // 51.2 MB
  float*  ATT4 = (float*)take((size_t)4*N_TRI*4);          // 3.2 MB
  float*  DOTA = (float*)take((size_t)N_TRI*4);
  float*  DOTB = (float*)take((size_t)N_TRI*4);
  int* RP_E  = (int*)take((size_t)(N_NODE+1)*4);
  int* RP_R  = (int*)take((size_t)(N_NODE+1)*4);
  int* RP_A  = (int*)take((size_t)(N_NODE+1)*4);
  int* IDX_E = (int*)take((size_t)N_TRI*4);
  int* IDX_R = (int*)take((size_t)N_TRI*4);
  int* IDX_A = (int*)take((size_t)N_TRI*4);
  int* CNT6  = (int*)take((size_t)6*N_NODE*4);
  int* CNT_E = CNT6,            *CNT_R = CNT6 + N_NODE,   *CNT_A = CNT6 + 2*N_NODE;
  int* CUR_E = CNT6 + 3*N_NODE, *CUR_R = CNT6 + 4*N_NODE, *CUR_A = CNT6 + 5*N_NODE;

  const int* cols = adj + N_TRI;

  // ---- init ----
  k_fill<<<192,256,0,stream>>>((float*)CNT6, (long)6*N_NODE, 0.f);

  // ---- CSR builds ----
  k_hist<<<782,256,0,stream>>>(ent_adj, CNT_E);
  k_hist<<<782,256,0,stream>>>(rel_adj, CNT_R);
  k_hist<<<782,256,0,stream>>>(adj,     CNT_A);
  k_scan3<<<3,256,0,stream>>>(CNT_E, RP_E, CNT_R, RP_R, CNT_A, RP_A, N_NODE);
  k_place<<<782,256,0,stream>>>(ent_adj, ent_adj+N_TRI, RP_E, CUR_E, IDX_E, 1);
  k_place<<<782,256,0,stream>>>(rel_adj, rel_adj+N_TRI, RP_R, CUR_R, IDX_R, 1);
  k_place<<<782,256,0,stream>>>(adj,     (const int*)0, RP_A, CUR_A, IDX_A, 0);

  // ---- feature pipeline ----
  k_feat0<<<7500,256,0,stream>>>(RP_E, IDX_E, RP_R, IDX_R, ent_emb, rel_emb, OUT);
  k_trinorm<<<50000,256,0,stream>>>(r_index+N_TRI, r_val, rel_emb, cols, OUT,
                                    TRI, attn_e, attn_r, ATT4, DOTA, DOTB);
  k_gat<<<7500,256,0,stream>>>(RP_A, IDX_A, cols, TRI,
                               ATT4 + 0*N_TRI, ATT4 + 2*N_TRI, DOTA, DOTB,
                               OUT, 0, 128, 384, 512);
  k_tdot<<<50000,256,0,stream>>>(cols, TRI, OUT, 128, 512, DOTA, DOTB);
  k_gat<<<7500,256,0,stream>>>(RP_A, IDX_A, cols, TRI,
                               ATT4 + 1*N_TRI, ATT4 + 3*N_TRI, DOTA, DOTB,
                               OUT, 128, 256, 512, 640);

  // ---- loss prep ----
  k_packE<<<7520,256,0,stream>>>(OUT, EP, ESQ);
  k_packA<<<512,256,0,stream>>>(pairs, EP, OUT, ESQ, AP, ASQ, POS);
  k_fill<<<16,256,0,stream>>>(RS1, (long)NROWA, 0.f);
  k_fill<<<16,256,0,stream>>>(RS2, (long)NROWA, 0.f);
  k_fill<<<16,256,0,stream>>>(RMIN,(long)NROWA, 1e30f);

  // ---- pass 1: GEMM + moments ----
  dim3 gg(NTILE_A, NTILE_E, 1);
  k_gemm<<<gg,256,0,stream>>>(AP, EP, ASQ, ESQ, POS, pairs,
                              RS1, RS2, RMIN, CCv, ALv, REXP, 1);
  k_corr<<<1024,256,0,stream>>>(pairs, AP, EP, ASQ, ESQ, NEGL, NEGR);
  k_stats<<<16,256,0,stream>>>(RS1, RS2, RMIN, NEGL, NEGR, ASQ, POS, pairs,
                               MM, CCv, ALv, REXP);

  // ---- pass 2: GEMM + exp ----
  k_gemm<<<gg,256,0,stream>>>(AP, EP, ASQ, ESQ, POS, pairs,
                              RS1, RS2, RMIN, CCv, ALv, REXP, 2);
  k_final<<<1,256,0,stream>>>(MM, REXP, (float*)d_out);
}

// Round 8
// 1202.120 us; speedup vs baseline: 1.0296x; 1.0296x over previous
//
#include <hip/hip_runtime.h>
#include <hip/hip_bf16.h>
#include <math.h>

#define N_NODE 30000
#define N_TRI  200000
#define DIM    128
#define OUTD   768
#define BATCH  2048
#define NROWA  4096
#define EPAD   30080   // 235*128
#define PADN   80      // EPAD - N_NODE
#define NTILE_E 235
#define NTILE_A 32
#define TILE_ELEMS (128*OUTD)
#define KBLK_ELEMS (128*32)
#define GAMMA_C 3.0f
#define LAMB_C  30.0f
#define TAU_C   10.0f

typedef __attribute__((ext_vector_type(8)))  __bf16 bf16x8;
typedef __attribute__((ext_vector_type(2)))  __bf16 bf16x2;
typedef __attribute__((ext_vector_type(4)))  float f32x4;
typedef __attribute__((ext_vector_type(16))) float f32x16;

__device__ __forceinline__ float waveSum(float v){
#pragma unroll
  for (int m=1;m<64;m<<=1) v += __shfl_xor(v, m, 64);
  return v;
}
__device__ __forceinline__ float waveMax(float v){
#pragma unroll
  for (int m=1;m<64;m<<=1) v = fmaxf(v, __shfl_xor(v, m, 64));
  return v;
}

__device__ __forceinline__ void atomicMinF(float* a, float v){
  if (v >= 0.f) atomicMin((int*)a, __float_as_int(v));
  else          atomicMax((unsigned int*)a, __float_as_uint(v));
}

__device__ __forceinline__ void gl2lds16(const void* g, void* l){
  __builtin_amdgcn_global_load_lds(
      (const __attribute__((address_space(1))) char*)g,
      (__attribute__((address_space(3))) char*)l, 16, 0, 0);
}

__device__ __forceinline__ int swz_off(int r, int q){
  return r*32 + ((q ^ ((r>>1)&3))<<3);
}

// ---------------- fill ----------------
__global__ void k_fill(float* __restrict__ p, long n, float v){
  long i = (long)blockIdx.x*blockDim.x + threadIdx.x;
  long st = (long)gridDim.x*blockDim.x;
  for (; i<n; i+=st) p[i]=v;
}

// ---------------- CSR build ----------------
__global__ __launch_bounds__(256) void k_hist(const int* __restrict__ rows, int* __restrict__ cnt){
  int t = blockIdx.x*256 + threadIdx.x;
  if (t < N_TRI) atomicAdd(&cnt[rows[t]], 1);
}

__global__ __launch_bounds__(256) void k_scan3(
    const int* __restrict__ c0, int* __restrict__ r0,
    const int* __restrict__ c1, int* __restrict__ r1,
    const int* __restrict__ c2, int* __restrict__ r2, int n){
  const int* cnt = blockIdx.x==0 ? c0 : (blockIdx.x==1 ? c1 : c2);
  int* rp        = blockIdx.x==0 ? r0 : (blockIdx.x==1 ? r1 : r2);
  __shared__ int buf[256];
  __shared__ int carry;
  if (threadIdx.x==0) carry = 0;
  __syncthreads();
  for (int base=0; base<n; base+=256){
    int i = base + threadIdx.x;
    int v = (i<n) ? cnt[i] : 0;
    buf[threadIdx.x] = v;
    __syncthreads();
    for (int off=1; off<256; off<<=1){
      int t = (threadIdx.x>=off) ? buf[threadIdx.x-off] : 0;
      __syncthreads();
      buf[threadIdx.x] += t;
      __syncthreads();
    }
    if (i<n) rp[i] = carry + buf[threadIdx.x] - v;
    int tot = buf[255];
    __syncthreads();
    if (threadIdx.x==0) carry += tot;
    __syncthreads();
  }
  if (threadIdx.x==0) rp[n] = carry;
}

__global__ __launch_bounds__(256) void k_place(const int* __restrict__ rows, const int* __restrict__ vals,
                        const int* __restrict__ rowptr, int* __restrict__ cur, int* __restrict__ idx, int mode){
  int t = blockIdx.x*256 + threadIdx.x;
  if (t < N_TRI){
    int r = rows[t];
    int p = atomicAdd(&cur[r], 1);
    idx[rowptr[r] + p] = mode ? vals[t] : t;
  }
}

// ---------------- fused sparse means + tanh -> bf16 features ----------------
__global__ __launch_bounds__(256) void k_feat0(
    const int* __restrict__ rpE, const int* __restrict__ idxE,
    const int* __restrict__ rpR, const int* __restrict__ idxR,
    const float* __restrict__ ent_emb, const float* __restrict__ rel_emb,
    __bf16* __restrict__ outb){
  int wave = threadIdx.x>>6, lane = threadIdx.x&63;
  int i = blockIdx.x*4 + wave;
  if (i >= N_NODE) return;
  int bE = rpE[i], eE = rpE[i+1];
  int bR = rpR[i], eR = rpR[i+1];
  float2 aE = {0.f,0.f}, aR = {0.f,0.f};
  for (int k=bE; k<eE; ++k){
    int c = idxE[k];
    float2 v = *(const float2*)(ent_emb + (size_t)c*DIM + lane*2);
    aE.x += v.x; aE.y += v.y;
  }
  for (int k=bR; k<eR; ++k){
    int c = idxR[k];
    float2 v = *(const float2*)(rel_emb + (size_t)c*DIM + lane*2);
    aR.x += v.x; aR.y += v.y;
  }
  float ie = 1.f/fmaxf((float)(eE-bE), 1.f);
  float ir = 1.f/fmaxf((float)(eR-bR), 1.f);
  bf16x2 oE, oR;
  oE[0] = (__bf16)tanhf(aE.x*ie); oE[1] = (__bf16)tanhf(aE.y*ie);
  oR[0] = (__bf16)tanhf(aR.x*ir); oR[1] = (__bf16)tanhf(aR.y*ir);
  *(bf16x2*)(outb + (size_t)i*OUTD +   0 + lane*2) = oE;
  *(bf16x2*)(outb + (size_t)i*OUTD + 384 + lane*2) = oR;
}

// ---------------- tri_rel direct + norm(bf16) + att logits ----------------
__global__ __launch_bounds__(256) void k_trinorm(
    const int* __restrict__ ridx1, const float* __restrict__ rval,
    const float* __restrict__ rel_emb,
    __bf16* __restrict__ tri, const float* __restrict__ attnE,
    const float* __restrict__ attnR, float* __restrict__ att4){
  __shared__ float ak[4][DIM];
  int tid = threadIdx.x;
  for (int idx=tid; idx<4*DIM; idx+=256){
    int k = idx>>7, d = idx&127;
    ak[k][d] = (k<2) ? attnE[k*DIM + d] : attnR[(k-2)*DIM + d];
  }
  __syncthreads();
  int wave = tid>>6, lane = tid&63;
  int t = blockIdx.x*4 + wave;
  if (t >= N_TRI) return;
  int rr = ridx1[t];
  float rv = rval[t];
  float2 v = *(const float2*)(rel_emb + (size_t)rr*DIM + lane*2);
  v.x *= rv; v.y *= rv;
  float ss = waveSum(v.x*v.x + v.y*v.y);
  float inv = 1.f/fmaxf(sqrtf(ss), 1e-12f);
  v.x *= inv; v.y *= inv;
  bf16x2 b; b[0] = (__bf16)v.x; b[1] = (__bf16)v.y;
  *(bf16x2*)(tri + (size_t)t*DIM + lane*2) = b;
#pragma unroll
  for (int k=0;k<4;k++){
    float p = waveSum(v.x*ak[k][lane*2] + v.y*ak[k][lane*2+1]);
    if (lane==0) att4[(size_t)k*N_TRI + t] = p;
  }
}

// ---------------- fused GAT layer (both branches), bf16 features ----------------
__global__ __launch_bounds__(256) void k_gat(
    const int* __restrict__ rowptr, const int* __restrict__ idx, const int* __restrict__ cols,
    const __bf16* __restrict__ tri,
    const float* __restrict__ attA, const float* __restrict__ attB,
    __bf16* __restrict__ outb, int inA, int outA, int inB, int outB_off){
  int wave = threadIdx.x>>6, lane = threadIdx.x&63;
  int i = blockIdx.x*4 + wave;
  if (i >= N_NODE) return;
  int beg = rowptr[i], end = rowptr[i+1];
  float2 accA = {0.f,0.f}, accB = {0.f,0.f};
  if (end > beg){
    float mA = -1e30f, mB = -1e30f;
    for (int k=beg+lane; k<end; k+=64){
      int t = idx[k];
      mA = fmaxf(mA, attA[t]); mB = fmaxf(mB, attB[t]);
    }
    mA = waveMax(mA); mB = waveMax(mB);
    float zA = 0.f, zB = 0.f;
    for (int k=beg+lane; k<end; k+=64){
      int t = idx[k];
      zA += __expf(attA[t]-mA); zB += __expf(attB[t]-mB);
    }
    zA = waveSum(zA); zB = waveSum(zB);
    float izA = 1.f/zA, izB = 1.f/zB;
    for (int k=beg; k<end; ++k){
      int t = idx[k];
      int c = cols[t];
      bf16x2 ub = *(const bf16x2*)(tri + (size_t)t*DIM + lane*2);
      float ux = (float)ub[0], uy = (float)ub[1];
      bf16x2 fa = *(const bf16x2*)(outb + (size_t)c*OUTD + inA + lane*2);
      bf16x2 fb = *(const bf16x2*)(outb + (size_t)c*OUTD + inB + lane*2);
      float fAx = (float)fa[0], fAy = (float)fa[1];
      float fBx = (float)fb[0], fBy = (float)fb[1];
      float dA = waveSum(fAx*ux + fAy*uy);
      float dB = waveSum(fBx*ux + fBy*uy);
      float wA = __expf(attA[t]-mA)*izA;
      float wB = __expf(attB[t]-mB)*izB;
      float dA2 = 2.f*dA, dB2 = 2.f*dB;
      accA.x = fmaf(wA, fmaf(-dA2, ux, fAx), accA.x);
      accA.y = fmaf(wA, fmaf(-dA2, uy, fAy), accA.y);
      accB.x = fmaf(wB, fmaf(-dB2, ux, fBx), accB.x);
      accB.y = fmaf(wB, fmaf(-dB2, uy, fBy), accB.y);
    }
  }
  bf16x2 oA, oB;
  oA[0] = (__bf16)tanhf(accA.x); oA[1] = (__bf16)tanhf(accA.y);
  oB[0] = (__bf16)tanhf(accB.x); oB[1] = (__bf16)tanhf(accB.y);
  *(bf16x2*)(outb + (size_t)i*OUTD + outA + lane*2) = oA;
  *(bf16x2*)(outb + (size_t)i*OUTD + outB_off + lane*2) = oB;
}

// ---------------- pack E (bf16 -> swizzled tiles + sumsq) ----------------
__global__ __launch_bounds__(256) void k_packE(const __bf16* __restrict__ outb, __bf16* __restrict__ Ep, float* __restrict__ esq){
  int wave = threadIdx.x>>6, lane = threadIdx.x&63;
  int j = blockIdx.x*4 + wave;
  if (j >= EPAD) return;
  int jt = j>>7, r = j&127;
  __bf16* tb = Ep + (size_t)jt*TILE_ELEMS;
  float ss = 0.f;
  for (int c=lane; c<96; c+=64){
    int kb = c>>2, q = c&3;
    bf16x8 o;
    if (j < N_NODE){
      o = *(const bf16x8*)(outb + (size_t)j*OUTD + c*8);
#pragma unroll
      for (int e=0;e<8;e++){ float v = (float)o[e]; ss += v*v; }
    } else {
#pragma unroll
      for (int e=0;e<8;e++) o[e] = (__bf16)0.f;
    }
    *(bf16x8*)(tb + kb*KBLK_ELEMS + swz_off(r, q)) = o;
  }
  ss = waveSum(ss);
  if (lane==0) esq[j] = (j < N_NODE) ? ss : 0.f;
}

__global__ __launch_bounds__(256) void k_packA(const int* __restrict__ pairs, const __bf16* __restrict__ Ep,
    const __bf16* __restrict__ outb, const float* __restrict__ esq,
    __bf16* __restrict__ Ap, float* __restrict__ asq, float* __restrict__ pos){
  int wave = threadIdx.x>>6, lane = threadIdx.x&63;
  int p = blockIdx.x*4 + wave;
  if (p >= BATCH) return;
  int l = pairs[2*p], r = pairs[2*p+1];
  float ss = 0.f;
#pragma unroll
  for (int c=0;c<6;c++){
    int d = c*128 + lane*2;
    bf16x2 a = *(const bf16x2*)(outb + (size_t)l*OUTD + d);
    bf16x2 b = *(const bf16x2*)(outb + (size_t)r*OUTD + d);
    float dx = (float)a[0]-(float)b[0], dy = (float)a[1]-(float)b[1];
    ss += dx*dx + dy*dy;
  }
  ss = waveSum(ss);
  if (lane==0){ pos[p] = ss; asq[p] = esq[l]; asq[p+BATCH] = esq[r]; }
  int lt = l>>7, lr = l&127;
  int rt2 = r>>7, rr = r&127;
  int p0t = p>>7, p0r = p&127;
  int p1t = (p+BATCH)>>7, p1r = (p+BATCH)&127;
  for (int c=lane; c<96; c+=64){
    int kb = c>>2, q = c&3;
    bf16x8 vl = *(const bf16x8*)(Ep + (size_t)lt*TILE_ELEMS + kb*KBLK_ELEMS + swz_off(lr, q));
    *(bf16x8*)(Ap + (size_t)p0t*TILE_ELEMS + kb*KBLK_ELEMS + swz_off(p0r, q)) = vl;
    bf16x8 vr = *(const bf16x8*)(Ep + (size_t)rt2*TILE_ELEMS + kb*KBLK_ELEMS + swz_off(rr, q));
    *(bf16x8*)(Ap + (size_t)p1t*TILE_ELEMS + kb*KBLK_ELEMS + swz_off(p1r, q)) = vr;
  }
}

// ---------------- GEMM (32x32x16 MFMA, BK=64): pass1 = moments; pass2 = exp ----------------
__global__ __launch_bounds__(256) void k_gemm(
    const __bf16* __restrict__ Ap, const __bf16* __restrict__ Ep,
    const float* __restrict__ asq, const float* __restrict__ esq,
    const float* __restrict__ pos, const int* __restrict__ pairs,
    float* __restrict__ rs1, float* __restrict__ rs2, float* __restrict__ rmin,
    const float* __restrict__ CC, const float* __restrict__ AL,
    float* __restrict__ rexp, int pass)
{
  __shared__ __bf16 sA[2*KBLK_ELEMS];   // 16 KB
  __shared__ __bf16 sB[2*KBLK_ELEMS];   // 16 KB
  __shared__ float red[768];
  int tid = threadIdx.x;

  int wave = tid>>6, lane = tid&63;
  int l31 = lane&31, h = lane>>5;
  int bi = blockIdx.x, bj = blockIdx.y;
  int wi = wave>>1, wj = wave&1;

  const __bf16* Asrc = Ap + (size_t)bi*TILE_ELEMS;
  const __bf16* Bsrc = Ep + (size_t)bj*TILE_ELEMS;

  // fragment LDS offsets: frag row-block ri/cj (32 rows), k-step s (16k): q = s*2 + h
  int a_off[2][2], b_off[2][2];
#pragma unroll
  for (int ri=0; ri<2; ++ri){
    int row = wi*64 + ri*32 + l31;
#pragma unroll
    for (int s=0; s<2; ++s){ int q = s*2 + h; a_off[ri][s] = row*32 + ((q ^ ((row>>1)&3))<<3); }
  }
#pragma unroll
  for (int cj=0; cj<2; ++cj){
    int row = wj*64 + cj*32 + l31;
#pragma unroll
    for (int s=0; s<2; ++s){ int q = s*2 + h; b_off[cj][s] = row*32 + ((q ^ ((row>>1)&3))<<3); }
  }

  const __bf16* gsrc = (wave<2 ? Asrc : Bsrc);
  __bf16* ldsb = (wave<2 ? sA : sB);
  int half = (wave&1)*KBLK_ELEMS;

  f32x16 acc[2][2];
#pragma unroll
  for (int ri=0; ri<2; ++ri)
#pragma unroll
    for (int cj=0; cj<2; ++cj)
#pragma unroll
      for (int e=0; e<16; ++e) acc[ri][cj][e] = 0.f;

  for (int kb2=0; kb2<12; ++kb2){
    __syncthreads();
    const __bf16* g = gsrc + kb2*(2*KBLK_ELEMS) + half + lane*8;
#pragma unroll
    for (int s=0; s<8; ++s)
      gl2lds16(g + s*512, ldsb + half + s*512);
    __syncthreads();
#pragma unroll
    for (int ks=0; ks<2; ++ks){
      int o = ks*KBLK_ELEMS;
#pragma unroll
      for (int s=0; s<2; ++s){
        bf16x8 a0 = *(const bf16x8*)(sA + o + a_off[0][s]);
        bf16x8 a1 = *(const bf16x8*)(sA + o + a_off[1][s]);
        bf16x8 b0 = *(const bf16x8*)(sB + o + b_off[0][s]);
        bf16x8 b1 = *(const bf16x8*)(sB + o + b_off[1][s]);
        acc[0][0] = __builtin_amdgcn_mfma_f32_32x32x16_bf16(a0, b0, acc[0][0], 0,0,0);
        acc[0][1] = __builtin_amdgcn_mfma_f32_32x32x16_bf16(a0, b1, acc[0][1], 0,0,0);
        acc[1][0] = __builtin_amdgcn_mfma_f32_32x32x16_bf16(a1, b0, acc[1][0], 0,0,0);
        acc[1][1] = __builtin_amdgcn_mfma_f32_32x32x16_bf16(a1, b1, acc[1][1], 0,0,0);
      }
    }
  }

  // ---- epilogue: C/D map col=lane&31, row=(reg&3)+8*(reg>>2)+4*h ----
  int jbase = bj*128 + wj*64;
  int jc[2] = { jbase + l31, jbase + 32 + l31 };
  bool val[2] = { jc[0] < N_NODE, jc[1] < N_NODE };
  float esqv[2] = { esq[jc[0]], esq[jc[1]] };

  if (pass == 1){
#pragma unroll
    for (int ri=0; ri<2; ++ri){
#pragma unroll
      for (int reg=0; reg<16; ++reg){
        int il = wi*64 + ri*32 + (reg&3) + 8*(reg>>2) + 4*h;
        int i  = bi*128 + il;
        int p  = i & (BATCH-1);
        int li = pairs[2*p], rx = pairs[2*p+1];
        float av = asq[i];
        float s=0.f, q=0.f, mn=1e30f;
#pragma unroll
        for (int cj=0; cj<2; ++cj){
          float neg = (av + esqv[cj]) - 2.f*acc[ri][cj][reg];
          s += neg;
          q = fmaf(neg, neg, q);
          bool bad = (jc[cj]==li) | (jc[cj]==rx) | (!val[cj]);
          mn = fminf(mn, bad ? 1e30f : neg);
        }
#pragma unroll
        for (int m=1;m<32;m<<=1){
          s += __shfl_xor(s,m,64); q += __shfl_xor(q,m,64);
          mn = fminf(mn, __shfl_xor(mn,m,64));
        }
        if (l31 == 0){
          red[il*2+wj] = s; red[256 + il*2+wj] = q; red[512 + il*2+wj] = mn;
        }
      }
    }
    __syncthreads();
    if (tid < 128){
      int i = bi*128 + tid;
      atomicAdd(rs1+i, red[tid*2] + red[tid*2+1]);
      atomicAdd(rs2+i, red[256 + tid*2] + red[256 + tid*2+1]);
      atomicMinF(rmin+i, fminf(red[512 + tid*2], red[512 + tid*2+1]));
    }
  } else {
#pragma unroll
    for (int ri=0; ri<2; ++ri){
#pragma unroll
      for (int reg=0; reg<16; ++reg){
        int il = wi*64 + ri*32 + (reg&3) + 8*(reg>>2) + 4*h;
        int i  = bi*128 + il;
        int p  = i & (BATCH-1);
        int li = pairs[2*p], rx = pairs[2*p+1];
        float av = asq[i];
        float C = CC[i], A = AL[i];
        float s = 0.f;
#pragma unroll
        for (int cj=0; cj<2; ++cj){
          float neg = (av + esqv[cj]) - 2.f*acc[ri][cj][reg];
          bool bad = (jc[cj]==li) | (jc[cj]==rx) | (!val[cj]);
          s += bad ? 0.f : __expf(fmaf(-A, neg, C));
        }
#pragma unroll
        for (int m=1;m<32;m<<=1) s += __shfl_xor(s,m,64);
        if (l31 == 0) red[il*2+wj] = s;
      }
    }
    __syncthreads();
    if (tid < 128){
      int i = bi*128 + tid;
      atomicAdd(rexp+i, red[tid*2] + red[tid*2+1]);
    }
  }
}

// ---------------- per-row special-column dots ----------------
__global__ __launch_bounds__(256) void k_corr(
    const int* __restrict__ pairs, const __bf16* __restrict__ Ap, const __bf16* __restrict__ Ep,
    const float* __restrict__ asq, const float* __restrict__ esq,
    float* __restrict__ negl, float* __restrict__ negr)
{
  int wave = threadIdx.x>>6, lane = threadIdx.x&63;
  int i = blockIdx.x*4 + wave;
  if (i >= NROWA) return;
  int p = i & (BATCH-1);
  int li = pairs[2*p], ri = pairs[2*p+1];
  const __bf16* Ar = Ap + (size_t)(i>>7)*TILE_ELEMS;  int ra = i&127;
  const __bf16* E1 = Ep + (size_t)(li>>7)*TILE_ELEMS; int r1 = li&127;
  const __bf16* E2 = Ep + (size_t)(ri>>7)*TILE_ELEMS; int r2 = ri&127;
  float d1=0.f, d2=0.f;
  for (int c=lane; c<96; c+=64){
    int kb = c>>2, q = c&3;
    bf16x8 a  = *(const bf16x8*)(Ar + kb*KBLK_ELEMS + swz_off(ra, q));
    bf16x8 e1 = *(const bf16x8*)(E1 + kb*KBLK_ELEMS + swz_off(r1, q));
    bf16x8 e2 = *(const bf16x8*)(E2 + kb*KBLK_ELEMS + swz_off(r2, q));
#pragma unroll
    for (int e=0;e<8;e++){
      d1 = fmaf((float)a[e], (float)e1[e], d1);
      d2 = fmaf((float)a[e], (float)e2[e], d2);
    }
  }
  d1 = waveSum(d1); d2 = waveSum(d2);
  if (lane==0){
    float av = asq[i];
    negl[i] = av + esq[li] - 2.f*d1;
    negr[i] = av + esq[ri] - 2.f*d2;
  }
}

// ---------------- stats ----------------
__global__ __launch_bounds__(256) void k_stats(
    const float* __restrict__ rs1, const float* __restrict__ rs2, const float* __restrict__ rmin,
    const float* __restrict__ negl, const float* __restrict__ negr,
    const float* __restrict__ asq, const float* __restrict__ pos, const int* __restrict__ pairs,
    float* __restrict__ MM, float* __restrict__ CC, float* __restrict__ AL, float* __restrict__ rexp)
{
  int i = blockIdx.x*256 + threadIdx.x;
  if (i >= NROWA) return;
  int p = i & (BATCH-1);
  int li = pairs[2*p], ri = pairs[2*p+1];
  float K = pos[p] + GAMMA_C;
  float av = asq[i];
  float S1 = rs1[i] - (float)PADN*av;
  float S2 = rs2[i] - (float)PADN*av*av;
  float nl = negl[i], nr = negr[i];
  float Sx, Sxx, mx;
  const float invN = 1.f/(float)N_NODE;
  if (li != ri){
    Sx  = -(S1 - nl - nr) - 2.f*K;
    Sxx = (S2 - nl*nl - nr*nr) + 2.f*K*K;
    mx  = fmaxf(K - rmin[i], 0.f);
    float mu = K + Sx*invN;
    float m2 = Sx*invN;
    float var = Sxx*invN - m2*m2;
    float sd = sqrtf(fmaxf(var, 1e-30f));
    float M = LAMB_C*(mx-mu)/sd + TAU_C;
    MM[i] = M; CC[i] = LAMB_C*(K-mu)/sd + TAU_C - M; AL[i] = LAMB_C/sd;
    rexp[i] = 2.f*__expf(LAMB_C*(0.f-mu)/sd + TAU_C - M);
  } else {
    float lossm = nl - K;
    float x = lossm - K;
    Sx  = -(S1 - nl) + x;
    Sxx = (S2 - nl*nl) + x*x;
    mx  = fmaxf(K - rmin[i], lossm);
    float mu = K + Sx*invN;
    float m2 = Sx*invN;
    float var = Sxx*invN - m2*m2;
    float sd = sqrtf(fmaxf(var, 1e-30f));
    float M = LAMB_C*(mx-mu)/sd + TAU_C;
    MM[i] = M; CC[i] = LAMB_C*(K-mu)/sd + TAU_C - M; AL[i] = LAMB_C/sd;
    rexp[i] = __expf(LAMB_C*(lossm-mu)/sd + TAU_C - M);
  }
}

__global__ __launch_bounds__(256) void k_final(const float* __restrict__ mm, const float* __restrict__ rexp, float* __restrict__ out){
  __shared__ float red[256];
  float s = 0.f;
  for (int i=threadIdx.x; i<NROWA; i+=256) s += mm[i] + logf(rexp[i]);
  red[threadIdx.x] = s; __syncthreads();
  for (int st=128; st>0; st>>=1){ if (threadIdx.x<st) red[threadIdx.x]+=red[threadIdx.x+st]; __syncthreads(); }
  if (threadIdx.x==0) out[0] = red[0]*(1.f/BATCH);
}

extern "C" void kernel_launch(void* const* d_in, const int* in_sizes, int n_in,
                              void* d_out, int out_size, void* d_ws, size_t ws_size,
                              hipStream_t stream) {
  const int*   pairs   = (const int*)d_in[0];
  const int*   ent_adj = (const int*)d_in[1];
  const int*   rel_adj = (const int*)d_in[2];
  const int*   adj     = (const int*)d_in[3];
  const int*   r_index = (const int*)d_in[4];
  const float* r_val   = (const float*)d_in[5];
  const float* ent_emb = (const float*)d_in[7];
  const float* rel_emb = (const float*)d_in[8];
  const float* attn_e  = (const float*)d_in[9];
  const float* attn_r  = (const float*)d_in[10];

  char* base = (char*)d_ws;
  size_t off = 0;
  auto take = [&](size_t bytes)->char*{
    char* p = base + off;
    off = (off + bytes + 511) & ~(size_t)511;
    return p;
  };
  // persistent GEMM-phase region (~53.5 MB)
  __bf16* EP    = (__bf16*)take((size_t)NTILE_E*TILE_ELEMS*2);
  __bf16* AP    = (__bf16*)take((size_t)NTILE_A*TILE_ELEMS*2);
  float*  ESQ   = (float*)take((size_t)EPAD*4);
  float*  ASQ   = (float*)take((size_t)NROWA*4);
  float*  POS   = (float*)take((size_t)BATCH*4);
  float*  RS1   = (float*)take((size_t)NROWA*4);
  float*  RS2   = (float*)take((size_t)NROWA*4);
  float*  RMIN  = (float*)take((size_t)NROWA*4);
  float*  NEGL  = (float*)take((size_t)NROWA*4);
  float*  NEGR  = (float*)take((size_t)NROWA*4);
  float*  MM    = (float*)take((size_t)NROWA*4);
  float*  CCv   = (float*)take((size_t)NROWA*4);
  float*  ALv   = (float*)take((size_t)NROWA*4);
  float*  REXP  = (float*)take((size_t)NROWA*4);

  // graph-phase region (~105 MB)
  __bf16* OUTB = (__bf16*)take((size_t)N_NODE*OUTD*2);     // 46.1 MB bf16 features
  __bf16* TRI  = (__bf16*)take((size_t)N_TRI*DIM*2);       // 51.2 MB
  float*  ATT4 = (float*)take((size_t)4*N_TRI*4);          // 3.2 MB
  int* RP_E  = (int*)take((size_t)(N_NODE+1)*4);
  int* RP_R  = (int*)take((size_t)(N_NODE+1)*4);
  int* RP_A  = (int*)take((size_t)(N_NODE+1)*4);
  int* IDX_E = (int*)take((size_t)N_TRI*4);
  int* IDX_R = (int*)take((size_t)N_TRI*4);
  int* IDX_A = (int*)take((size_t)N_TRI*4);
  int* CNT6  = (int*)take((size_t)6*N_NODE*4);
  int* CNT_E = CNT6,            *CNT_R = CNT6 + N_NODE,   *CNT_A = CNT6 + 2*N_NODE;
  int* CUR_E = CNT6 + 3*N_NODE, *CUR_R = CNT6 + 4*N_NODE, *CUR_A = CNT6 + 5*N_NODE;

  const int* cols = adj + N_TRI;

  // ---- init ----
  k_fill<<<192,256,0,stream>>>((float*)CNT6, (long)6*N_NODE, 0.f);

  // ---- CSR builds ----
  k_hist<<<782,256,0,stream>>>(ent_adj, CNT_E);
  k_hist<<<782,256,0,stream>>>(rel_adj, CNT_R);
  k_hist<<<782,256,0,stream>>>(adj,     CNT_A);
  k_scan3<<<3,256,0,stream>>>(CNT_E, RP_E, CNT_R, RP_R, CNT_A, RP_A, N_NODE);
  k_place<<<782,256,0,stream>>>(ent_adj, ent_adj+N_TRI, RP_E, CUR_E, IDX_E, 1);
  k_place<<<782,256,0,stream>>>(rel_adj, rel_adj+N_TRI, RP_R, CUR_R, IDX_R, 1);
  k_place<<<782,256,0,stream>>>(adj,     (const int*)0, RP_A, CUR_A, IDX_A, 0);

  // ---- feature pipeline (bf16 features) ----
  k_feat0<<<7500,256,0,stream>>>(RP_E, IDX_E, RP_R, IDX_R, ent_emb, rel_emb, OUTB);
  k_trinorm<<<50000,256,0,stream>>>(r_index+N_TRI, r_val, rel_emb, TRI, attn_e, attn_r, ATT4);
  k_gat<<<7500,256,0,stream>>>(RP_A, IDX_A, cols, TRI,
                               ATT4 + 0*N_TRI, ATT4 + 2*N_TRI, OUTB, 0, 128, 384, 512);
  k_gat<<<7500,256,0,stream>>>(RP_A, IDX_A, cols, TRI,
                               ATT4 + 1*N_TRI, ATT4 + 3*N_TRI, OUTB, 128, 256, 512, 640);

  // ---- loss prep ----
  k_packE<<<7520,256,0,stream>>>(OUTB, EP, ESQ);
  k_packA<<<512,256,0,stream>>>(pairs, EP, OUTB, ESQ, AP, ASQ, POS);
  k_fill<<<16,256,0,stream>>>(RS1, (long)NROWA, 0.f);
  k_fill<<<16,256,0,stream>>>(RS2, (long)NROWA, 0.f);
  k_fill<<<16,256,0,stream>>>(RMIN,(long)NROWA, 1e30f);

  // ---- pass 1: GEMM + moments ----
  dim3 gg(NTILE_A, NTILE_E, 1);
  k_gemm<<<gg,256,0,stream>>>(AP, EP, ASQ, ESQ, POS, pairs,
                              RS1, RS2, RMIN, CCv, ALv, REXP, 1);
  k_corr<<<1024,256,0,stream>>>(pairs, AP, EP, ASQ, ESQ, NEGL, NEGR);
  k_stats<<<16,256,0,stream>>>(RS1, RS2, RMIN, NEGL, NEGR, ASQ, POS, pairs,
                               MM, CCv, ALv, REXP);

  // ---- pass 2: GEMM + exp ----
  k_gemm<<<gg,256,0,stream>>>(AP, EP, ASQ, ESQ, POS, pairs,
                              RS1, RS2, RMIN, CCv, ALv, REXP, 2);
  k_final<<<1,256,0,stream>>>(MM, REXP, (float*)d_out);
}

// Round 9
// 1146.374 us; speedup vs baseline: 1.0797x; 1.0486x over previous
//
#include <hip/hip_runtime.h>
#include <hip/hip_bf16.h>
#include <math.h>

#define N_NODE 30000
#define N_TRI  200000
#define DIM    128
#define OUTD   768
#define BATCH  2048
#define NROWA  4096
#define EPAD   30080   // 235*128
#define PADN   80      // EPAD - N_NODE
#define NTILE_E 235
#define NTILE_A 32
#define TILE_ELEMS (128*OUTD)
#define KBLK_ELEMS (128*32)
#define GAMMA_C 3.0f
#define LAMB_C  30.0f
#define TAU_C   10.0f

typedef __attribute__((ext_vector_type(8)))  __bf16 bf16x8;
typedef __attribute__((ext_vector_type(2)))  __bf16 bf16x2;
typedef __attribute__((ext_vector_type(4)))  float f32x4;

__device__ __forceinline__ float waveSum(float v){
#pragma unroll
  for (int m=1;m<64;m<<=1) v += __shfl_xor(v, m, 64);
  return v;
}
__device__ __forceinline__ float waveMax(float v){
#pragma unroll
  for (int m=1;m<64;m<<=1) v = fmaxf(v, __shfl_xor(v, m, 64));
  return v;
}

__device__ __forceinline__ void atomicMinF(float* a, float v){
  if (v >= 0.f) atomicMin((int*)a, __float_as_int(v));
  else          atomicMax((unsigned int*)a, __float_as_uint(v));
}

__device__ __forceinline__ void gl2lds16(const void* g, void* l){
  __builtin_amdgcn_global_load_lds(
      (const __attribute__((address_space(1))) char*)g,
      (__attribute__((address_space(3))) char*)l, 16, 0, 0);
}

__device__ __forceinline__ int swz_off(int r, int q){
  return r*32 + ((q ^ ((r>>1)&3))<<3);
}

// ---------------- fill ----------------
__global__ void k_fill(float* __restrict__ p, long n, float v){
  long i = (long)blockIdx.x*blockDim.x + threadIdx.x;
  long st = (long)gridDim.x*blockDim.x;
  for (; i<n; i+=st) p[i]=v;
}

// ---------------- CSR build ----------------
__global__ __launch_bounds__(256) void k_hist(const int* __restrict__ rows, int* __restrict__ cnt){
  int t = blockIdx.x*256 + threadIdx.x;
  if (t < N_TRI) atomicAdd(&cnt[rows[t]], 1);
}

__global__ __launch_bounds__(256) void k_scan3(
    const int* __restrict__ c0, int* __restrict__ r0,
    const int* __restrict__ c1, int* __restrict__ r1,
    const int* __restrict__ c2, int* __restrict__ r2, int n){
  const int* cnt = blockIdx.x==0 ? c0 : (blockIdx.x==1 ? c1 : c2);
  int* rp        = blockIdx.x==0 ? r0 : (blockIdx.x==1 ? r1 : r2);
  __shared__ int buf[256];
  __shared__ int carry;
  if (threadIdx.x==0) carry = 0;
  __syncthreads();
  for (int base=0; base<n; base+=256){
    int i = base + threadIdx.x;
    int v = (i<n) ? cnt[i] : 0;
    buf[threadIdx.x] = v;
    __syncthreads();
    for (int off=1; off<256; off<<=1){
      int t = (threadIdx.x>=off) ? buf[threadIdx.x-off] : 0;
      __syncthreads();
      buf[threadIdx.x] += t;
      __syncthreads();
    }
    if (i<n) rp[i] = carry + buf[threadIdx.x] - v;
    int tot = buf[255];
    __syncthreads();
    if (threadIdx.x==0) carry += tot;
    __syncthreads();
  }
  if (threadIdx.x==0) rp[n] = carry;
}

__global__ __launch_bounds__(256) void k_place(const int* __restrict__ rows, const int* __restrict__ vals,
                        const int* __restrict__ rowptr, int* __restrict__ cur, int* __restrict__ idx, int mode){
  int t = blockIdx.x*256 + threadIdx.x;
  if (t < N_TRI){
    int r = rows[t];
    int p = atomicAdd(&cur[r], 1);
    idx[rowptr[r] + p] = mode ? vals[t] : t;
  }
}

// ---------------- fused sparse means + tanh -> bf16 features ----------------
__global__ __launch_bounds__(256) void k_feat0(
    const int* __restrict__ rpE, const int* __restrict__ idxE,
    const int* __restrict__ rpR, const int* __restrict__ idxR,
    const float* __restrict__ ent_emb, const float* __restrict__ rel_emb,
    __bf16* __restrict__ outb){
  int wave = threadIdx.x>>6, lane = threadIdx.x&63;
  int i = blockIdx.x*4 + wave;
  if (i >= N_NODE) return;
  int bE = rpE[i], eE = rpE[i+1];
  int bR = rpR[i], eR = rpR[i+1];
  float2 aE = {0.f,0.f}, aR = {0.f,0.f};
  for (int k=bE; k<eE; ++k){
    int c = idxE[k];
    float2 v = *(const float2*)(ent_emb + (size_t)c*DIM + lane*2);
    aE.x += v.x; aE.y += v.y;
  }
  for (int k=bR; k<eR; ++k){
    int c = idxR[k];
    float2 v = *(const float2*)(rel_emb + (size_t)c*DIM + lane*2);
    aR.x += v.x; aR.y += v.y;
  }
  float ie = 1.f/fmaxf((float)(eE-bE), 1.f);
  float ir = 1.f/fmaxf((float)(eR-bR), 1.f);
  bf16x2 oE, oR;
  oE[0] = (__bf16)tanhf(aE.x*ie); oE[1] = (__bf16)tanhf(aE.y*ie);
  oR[0] = (__bf16)tanhf(aR.x*ir); oR[1] = (__bf16)tanhf(aR.y*ir);
  *(bf16x2*)(outb + (size_t)i*OUTD +   0 + lane*2) = oE;
  *(bf16x2*)(outb + (size_t)i*OUTD + 384 + lane*2) = oR;
}

// ---------------- tri_rel direct + norm(bf16) + att logits ----------------
__global__ __launch_bounds__(256) void k_trinorm(
    const int* __restrict__ ridx1, const float* __restrict__ rval,
    const float* __restrict__ rel_emb,
    __bf16* __restrict__ tri, const float* __restrict__ attnE,
    const float* __restrict__ attnR, float* __restrict__ att4){
  __shared__ float ak[4][DIM];
  int tid = threadIdx.x;
  for (int idx=tid; idx<4*DIM; idx+=256){
    int k = idx>>7, d = idx&127;
    ak[k][d] = (k<2) ? attnE[k*DIM + d] : attnR[(k-2)*DIM + d];
  }
  __syncthreads();
  int wave = tid>>6, lane = tid&63;
  int t = blockIdx.x*4 + wave;
  if (t >= N_TRI) return;
  int rr = ridx1[t];
  float rv = rval[t];
  float2 v = *(const float2*)(rel_emb + (size_t)rr*DIM + lane*2);
  v.x *= rv; v.y *= rv;
  float ss = waveSum(v.x*v.x + v.y*v.y);
  float inv = 1.f/fmaxf(sqrtf(ss), 1e-12f);
  v.x *= inv; v.y *= inv;
  bf16x2 b; b[0] = (__bf16)v.x; b[1] = (__bf16)v.y;
  *(bf16x2*)(tri + (size_t)t*DIM + lane*2) = b;
#pragma unroll
  for (int k=0;k<4;k++){
    float p = waveSum(v.x*ak[k][lane*2] + v.y*ak[k][lane*2+1]);
    if (lane==0) att4[(size_t)k*N_TRI + t] = p;
  }
}

// ---------------- fused GAT layer (both branches), bf16 features ----------------
__global__ __launch_bounds__(256) void k_gat(
    const int* __restrict__ rowptr, const int* __restrict__ idx, const int* __restrict__ cols,
    const __bf16* __restrict__ tri,
    const float* __restrict__ attA, const float* __restrict__ attB,
    __bf16* __restrict__ outb, int inA, int outA, int inB, int outB_off){
  int wave = threadIdx.x>>6, lane = threadIdx.x&63;
  int i = blockIdx.x*4 + wave;
  if (i >= N_NODE) return;
  int beg = rowptr[i], end = rowptr[i+1];
  float2 accA = {0.f,0.f}, accB = {0.f,0.f};
  if (end > beg){
    float mA = -1e30f, mB = -1e30f;
    for (int k=beg+lane; k<end; k+=64){
      int t = idx[k];
      mA = fmaxf(mA, attA[t]); mB = fmaxf(mB, attB[t]);
    }
    mA = waveMax(mA); mB = waveMax(mB);
    float zA = 0.f, zB = 0.f;
    for (int k=beg+lane; k<end; k+=64){
      int t = idx[k];
      zA += __expf(attA[t]-mA); zB += __expf(attB[t]-mB);
    }
    zA = waveSum(zA); zB = waveSum(zB);
    float izA = 1.f/zA, izB = 1.f/zB;
    for (int k=beg; k<end; ++k){
      int t = idx[k];
      int c = cols[t];
      bf16x2 ub = *(const bf16x2*)(tri + (size_t)t*DIM + lane*2);
      float ux = (float)ub[0], uy = (float)ub[1];
      bf16x2 fa = *(const bf16x2*)(outb + (size_t)c*OUTD + inA + lane*2);
      bf16x2 fb = *(const bf16x2*)(outb + (size_t)c*OUTD + inB + lane*2);
      float fAx = (float)fa[0], fAy = (float)fa[1];
      float fBx = (float)fb[0], fBy = (float)fb[1];
      float dA = waveSum(fAx*ux + fAy*uy);
      float dB = waveSum(fBx*ux + fBy*uy);
      float wA = __expf(attA[t]-mA)*izA;
      float wB = __expf(attB[t]-mB)*izB;
      float dA2 = 2.f*dA, dB2 = 2.f*dB;
      accA.x = fmaf(wA, fmaf(-dA2, ux, fAx), accA.x);
      accA.y = fmaf(wA, fmaf(-dA2, uy, fAy), accA.y);
      accB.x = fmaf(wB, fmaf(-dB2, ux, fBx), accB.x);
      accB.y = fmaf(wB, fmaf(-dB2, uy, fBy), accB.y);
    }
  }
  bf16x2 oA, oB;
  oA[0] = (__bf16)tanhf(accA.x); oA[1] = (__bf16)tanhf(accA.y);
  oB[0] = (__bf16)tanhf(accB.x); oB[1] = (__bf16)tanhf(accB.y);
  *(bf16x2*)(outb + (size_t)i*OUTD + outA + lane*2) = oA;
  *(bf16x2*)(outb + (size_t)i*OUTD + outB_off + lane*2) = oB;
}

// ---------------- pack E (bf16 -> swizzled tiles + sumsq) ----------------
__global__ __launch_bounds__(256) void k_packE(const __bf16* __restrict__ outb, __bf16* __restrict__ Ep, float* __restrict__ esq){
  int wave = threadIdx.x>>6, lane = threadIdx.x&63;
  int j = blockIdx.x*4 + wave;
  if (j >= EPAD) return;
  int jt = j>>7, r = j&127;
  __bf16* tb = Ep + (size_t)jt*TILE_ELEMS;
  float ss = 0.f;
  for (int c=lane; c<96; c+=64){
    int kb = c>>2, q = c&3;
    bf16x8 o;
    if (j < N_NODE){
      o = *(const bf16x8*)(outb + (size_t)j*OUTD + c*8);
#pragma unroll
      for (int e=0;e<8;e++){ float v = (float)o[e]; ss += v*v; }
    } else {
#pragma unroll
      for (int e=0;e<8;e++) o[e] = (__bf16)0.f;
    }
    *(bf16x8*)(tb + kb*KBLK_ELEMS + swz_off(r, q)) = o;
  }
  ss = waveSum(ss);
  if (lane==0) esq[j] = (j < N_NODE) ? ss : 0.f;
}

__global__ __launch_bounds__(256) void k_packA(const int* __restrict__ pairs, const __bf16* __restrict__ Ep,
    const __bf16* __restrict__ outb, const float* __restrict__ esq,
    __bf16* __restrict__ Ap, float* __restrict__ asq, float* __restrict__ pos){
  int wave = threadIdx.x>>6, lane = threadIdx.x&63;
  int p = blockIdx.x*4 + wave;
  if (p >= BATCH) return;
  int l = pairs[2*p], r = pairs[2*p+1];
  float ss = 0.f;
#pragma unroll
  for (int c=0;c<6;c++){
    int d = c*128 + lane*2;
    bf16x2 a = *(const bf16x2*)(outb + (size_t)l*OUTD + d);
    bf16x2 b = *(const bf16x2*)(outb + (size_t)r*OUTD + d);
    float dx = (float)a[0]-(float)b[0], dy = (float)a[1]-(float)b[1];
    ss += dx*dx + dy*dy;
  }
  ss = waveSum(ss);
  if (lane==0){ pos[p] = ss; asq[p] = esq[l]; asq[p+BATCH] = esq[r]; }
  int lt = l>>7, lr = l&127;
  int rt2 = r>>7, rr = r&127;
  int p0t = p>>7, p0r = p&127;
  int p1t = (p+BATCH)>>7, p1r = (p+BATCH)&127;
  for (int c=lane; c<96; c+=64){
    int kb = c>>2, q = c&3;
    bf16x8 vl = *(const bf16x8*)(Ep + (size_t)lt*TILE_ELEMS + kb*KBLK_ELEMS + swz_off(lr, q));
    *(bf16x8*)(Ap + (size_t)p0t*TILE_ELEMS + kb*KBLK_ELEMS + swz_off(p0r, q)) = vl;
    bf16x8 vr = *(const bf16x8*)(Ep + (size_t)rt2*TILE_ELEMS + kb*KBLK_ELEMS + swz_off(rr, q));
    *(bf16x8*)(Ap + (size_t)p1t*TILE_ELEMS + kb*KBLK_ELEMS + swz_off(p1r, q)) = vr;
  }
}

// ---------------- GEMM (16x16x32 MFMA, BK=64): pass1 = moments; pass2 = exp ----------------
__global__ __launch_bounds__(256) void k_gemm(
    const __bf16* __restrict__ Ap, const __bf16* __restrict__ Ep,
    const float* __restrict__ asq, const float* __restrict__ esq,
    const float* __restrict__ pos, const int* __restrict__ pairs,
    float* __restrict__ rs1, float* __restrict__ rs2, float* __restrict__ rmin,
    const float* __restrict__ CC, const float* __restrict__ AL,
    float* __restrict__ rexp, int pass)
{
  __shared__ __bf16 sA[2*KBLK_ELEMS];   // 16 KB
  __shared__ __bf16 sB[2*KBLK_ELEMS];   // 16 KB
  __shared__ float red[768];
  int tid = threadIdx.x;

  int wave = tid>>6, lane = tid&63, quad = lane>>4, l16 = lane&15;
  int bi = blockIdx.x, bj = blockIdx.y;
  int wi = wave>>1, wj = wave&1;

  const __bf16* Asrc = Ap + (size_t)bi*TILE_ELEMS;
  const __bf16* Bsrc = Ep + (size_t)bj*TILE_ELEMS;

  int a_off[4], b_off[4];
#pragma unroll
  for (int rt=0; rt<4; ++rt){ int row = wi*64 + rt*16 + l16; a_off[rt] = swz_off(row, quad); }
#pragma unroll
  for (int ct=0; ct<4; ++ct){ int row = wj*64 + ct*16 + l16; b_off[ct] = swz_off(row, quad); }

  const __bf16* gsrc = (wave<2 ? Asrc : Bsrc);
  __bf16* ldsb = (wave<2 ? sA : sB);
  int half = (wave&1)*KBLK_ELEMS;   // each wave stages one 4096-elem k-block

  const f32x4 zf = {0.f,0.f,0.f,0.f};
  f32x4 acc[4][4];
#pragma unroll
  for (int rt=0; rt<4; ++rt)
#pragma unroll
    for (int ct=0; ct<4; ++ct) acc[rt][ct] = zf;

  for (int kb2=0; kb2<12; ++kb2){
    __syncthreads();
    const __bf16* g = gsrc + kb2*(2*KBLK_ELEMS) + half + lane*8;
#pragma unroll
    for (int s=0; s<8; ++s)
      gl2lds16(g + s*512, ldsb + half + s*512);
    __syncthreads();
#pragma unroll
    for (int ks=0; ks<2; ++ks){
      int o = ks*KBLK_ELEMS;
      bf16x8 af[4], bf[4];
#pragma unroll
      for (int rt=0; rt<4; ++rt) af[rt] = *(const bf16x8*)(sA + o + a_off[rt]);
#pragma unroll
      for (int ct=0; ct<4; ++ct) bf[ct] = *(const bf16x8*)(sB + o + b_off[ct]);
#pragma unroll
      for (int rt=0; rt<4; ++rt)
#pragma unroll
        for (int ct=0; ct<4; ++ct)
          acc[rt][ct] = __builtin_amdgcn_mfma_f32_16x16x32_bf16(af[rt], bf[ct], acc[rt][ct], 0,0,0);
    }
  }

  // ---- epilogue ----
  int jbase = bj*128 + wj*64;
  float esqv[4]; bool val[4]; int jcol[4];
#pragma unroll
  for (int ct=0; ct<4; ++ct){
    jcol[ct] = jbase + ct*16 + l16;
    val[ct] = jcol[ct] < N_NODE;
    esqv[ct] = esq[jcol[ct]];
  }

  if (pass == 1){
#pragma unroll
    for (int rt=0; rt<4; ++rt){
#pragma unroll
      for (int reg=0; reg<4; ++reg){
        int il = wi*64 + rt*16 + quad*4 + reg;
        int i  = bi*128 + il;
        int p  = i & (BATCH-1);
        int li = pairs[2*p], ri = pairs[2*p+1];
        float av = asq[i];
        float s=0.f, q=0.f, mn=1e30f;
#pragma unroll
        for (int ct=0; ct<4; ++ct){
          float neg = (av + esqv[ct]) - 2.f*acc[rt][ct][reg];
          s += neg;
          q = fmaf(neg, neg, q);
          bool bad = (jcol[ct]==li) | (jcol[ct]==ri) | (!val[ct]);
          mn = fminf(mn, bad ? 1e30f : neg);
        }
#pragma unroll
        for (int m=1;m<16;m<<=1){
          s += __shfl_xor(s,m,64); q += __shfl_xor(q,m,64);
          mn = fminf(mn, __shfl_xor(mn,m,64));
        }
        if (l16 == 0){
          red[il*2+wj] = s; red[256 + il*2+wj] = q; red[512 + il*2+wj] = mn;
        }
      }
    }
    __syncthreads();
    if (tid < 128){
      int i = bi*128 + tid;
      atomicAdd(rs1+i, red[tid*2] + red[tid*2+1]);
      atomicAdd(rs2+i, red[256 + tid*2] + red[256 + tid*2+1]);
      atomicMinF(rmin+i, fminf(red[512 + tid*2], red[512 + tid*2+1]));
    }
  } else {
#pragma unroll
    for (int rt=0; rt<4; ++rt){
#pragma unroll
      for (int reg=0; reg<4; ++reg){
        int il = wi*64 + rt*16 + quad*4 + reg;
        int i  = bi*128 + il;
        int p  = i & (BATCH-1);
        int li = pairs[2*p], ri = pairs[2*p+1];
        float av = asq[i];
        float C = CC[i], A = AL[i];
        float s = 0.f;
#pragma unroll
        for (int ct=0; ct<4; ++ct){
          float neg = (av + esqv[ct]) - 2.f*acc[rt][ct][reg];
          bool bad = (jcol[ct]==li) | (jcol[ct]==ri) | (!val[ct]);
          s += bad ? 0.f : __expf(fmaf(-A, neg, C));
        }
#pragma unroll
        for (int m=1;m<16;m<<=1) s += __shfl_xor(s,m,64);
        if (l16 == 0) red[il*2+wj] = s;
      }
    }
    __syncthreads();
    if (tid < 128){
      int i = bi*128 + tid;
      atomicAdd(rexp+i, red[tid*2] + red[tid*2+1]);
    }
  }
}

// ---------------- per-row special-column dots ----------------
__global__ __launch_bounds__(256) void k_corr(
    const int* __restrict__ pairs, const __bf16* __restrict__ Ap, const __bf16* __restrict__ Ep,
    const float* __restrict__ asq, const float* __restrict__ esq,
    float* __restrict__ negl, float* __restrict__ negr)
{
  int wave = threadIdx.x>>6, lane = threadIdx.x&63;
  int i = blockIdx.x*4 + wave;
  if (i >= NROWA) return;
  int p = i & (BATCH-1);
  int li = pairs[2*p], ri = pairs[2*p+1];
  const __bf16* Ar = Ap + (size_t)(i>>7)*TILE_ELEMS;  int ra = i&127;
  const __bf16* E1 = Ep + (size_t)(li>>7)*TILE_ELEMS; int r1 = li&127;
  const __bf16* E2 = Ep + (size_t)(ri>>7)*TILE_ELEMS; int r2 = ri&127;
  float d1=0.f, d2=0.f;
  for (int c=lane; c<96; c+=64){
    int kb = c>>2, q = c&3;
    bf16x8 a  = *(const bf16x8*)(Ar + kb*KBLK_ELEMS + swz_off(ra, q));
    bf16x8 e1 = *(const bf16x8*)(E1 + kb*KBLK_ELEMS + swz_off(r1, q));
    bf16x8 e2 = *(const bf16x8*)(E2 + kb*KBLK_ELEMS + swz_off(r2, q));
#pragma unroll
    for (int e=0;e<8;e++){
      d1 = fmaf((float)a[e], (float)e1[e], d1);
      d2 = fmaf((float)a[e], (float)e2[e], d2);
    }
  }
  d1 = waveSum(d1); d2 = waveSum(d2);
  if (lane==0){
    float av = asq[i];
    negl[i] = av + esq[li] - 2.f*d1;
    negr[i] = av + esq[ri] - 2.f*d2;
  }
}

// ---------------- stats ----------------
__global__ __launch_bounds__(256) void k_stats(
    const float* __restrict__ rs1, const float* __restrict__ rs2, const float* __restrict__ rmin,
    const float* __restrict__ negl, const float* __restrict__ negr,
    const float* __restrict__ asq, const float* __restrict__ pos, const int* __restrict__ pairs,
    float* __restrict__ MM, float* __restrict__ CC, float* __restrict__ AL, float* __restrict__ rexp)
{
  int i = blockIdx.x*256 + threadIdx.x;
  if (i >= NROWA) return;
  int p = i & (BATCH-1);
  int li = pairs[2*p], ri = pairs[2*p+1];
  float K = pos[p] + GAMMA_C;
  float av = asq[i];
  float S1 = rs1[i] - (float)PADN*av;
  float S2 = rs2[i] - (float)PADN*av*av;
  float nl = negl[i], nr = negr[i];
  float Sx, Sxx, mx;
  const float invN = 1.f/(float)N_NODE;
  if (li != ri){
    Sx  = -(S1 - nl - nr) - 2.f*K;
    Sxx = (S2 - nl*nl - nr*nr) + 2.f*K*K;
    mx  = fmaxf(K - rmin[i], 0.f);
    float mu = K + Sx*invN;
    float m2 = Sx*invN;
    float var = Sxx*invN - m2*m2;
    float sd = sqrtf(fmaxf(var, 1e-30f));
    float M = LAMB_C*(mx-mu)/sd + TAU_C;
    MM[i] = M; CC[i] = LAMB_C*(K-mu)/sd + TAU_C - M; AL[i] = LAMB_C/sd;
    rexp[i] = 2.f*__expf(LAMB_C*(0.f-mu)/sd + TAU_C - M);
  } else {
    float lossm = nl - K;
    float x = lossm - K;
    Sx  = -(S1 - nl) + x;
    Sxx = (S2 - nl*nl) + x*x;
    mx  = fmaxf(K - rmin[i], lossm);
    float mu = K + Sx*invN;
    float m2 = Sx*invN;
    float var = Sxx*invN - m2*m2;
    float sd = sqrtf(fmaxf(var, 1e-30f));
    float M = LAMB_C*(mx-mu)/sd + TAU_C;
    MM[i] = M; CC[i] = LAMB_C*(K-mu)/sd + TAU_C - M; AL[i] = LAMB_C/sd;
    rexp[i] = __expf(LAMB_C*(lossm-mu)/sd + TAU_C - M);
  }
}

__global__ __launch_bounds__(256) void k_final(const float* __restrict__ mm, const float* __restrict__ rexp, float* __restrict__ out){
  __shared__ float red[256];
  float s = 0.f;
  for (int i=threadIdx.x; i<NROWA; i+=256) s += mm[i] + logf(rexp[i]);
  red[threadIdx.x] = s; __syncthreads();
  for (int st=128; st>0; st>>=1){ if (threadIdx.x<st) red[threadIdx.x]+=red[threadIdx.x+st]; __syncthreads(); }
  if (threadIdx.x==0) out[0] = red[0]*(1.f/BATCH);
}

extern "C" void kernel_launch(void* const* d_in, const int* in_sizes, int n_in,
                              void* d_out, int out_size, void* d_ws, size_t ws_size,
                              hipStream_t stream) {
  const int*   pairs   = (const int*)d_in[0];
  const int*   ent_adj = (const int*)d_in[1];
  const int*   rel_adj = (const int*)d_in[2];
  const int*   adj     = (const int*)d_in[3];
  const int*   r_index = (const int*)d_in[4];
  const float* r_val   = (const float*)d_in[5];
  const float* ent_emb = (const float*)d_in[7];
  const float* rel_emb = (const float*)d_in[8];
  const float* attn_e  = (const float*)d_in[9];
  const float* attn_r  = (const float*)d_in[10];

  char* base = (char*)d_ws;
  size_t off = 0;
  auto take = [&](size_t bytes)->char*{
    char* p = base + off;
    off = (off + bytes + 511) & ~(size_t)511;
    return p;
  };
  // persistent GEMM-phase region (~53.5 MB)
  __bf16* EP    = (__bf16*)take((size_t)NTILE_E*TILE_ELEMS*2);
  __bf16* AP    = (__bf16*)take((size_t)NTILE_A*TILE_ELEMS*2);
  float*  ESQ   = (float*)take((size_t)EPAD*4);
  float*  ASQ   = (float*)take((size_t)NROWA*4);
  float*  POS   = (float*)take((size_t)BATCH*4);
  float*  RS1   = (float*)take((size_t)NROWA*4);
  float*  RS2   = (float*)take((size_t)NROWA*4);
  float*  RMIN  = (float*)take((size_t)NROWA*4);
  float*  NEGL  = (float*)take((size_t)NROWA*4);
  float*  NEGR  = (float*)take((size_t)NROWA*4);
  float*  MM    = (float*)take((size_t)NROWA*4);
  float*  CCv   = (float*)take((size_t)NROWA*4);
  float*  ALv   = (float*)take((size_t)NROWA*4);
  float*  REXP  = (float*)take((size_t)NROWA*4);

  // graph-phase region (~105 MB)
  __bf16* OUTB = (__bf16*)take((size_t)N_NODE*OUTD*2);     // 46.1 MB bf16 features
  __bf16* TRI  = (__bf16*)take((size_t)N_TRI*DIM*2);       // 51.2 MB
  float*  ATT4 = (float*)take((size_t)4*N_TRI*4);          // 3.2 MB
  int* RP_E  = (int*)take((size_t)(N_NODE+1)*4);
  int* RP_R  = (int*)take((size_t)(N_NODE+1)*4);
  int* RP_A  = (int*)take((size_t)(N_NODE+1)*4);
  int* IDX_E = (int*)take((size_t)N_TRI*4);
  int* IDX_R = (int*)take((size_t)N_TRI*4);
  int* IDX_A = (int*)take((size_t)N_TRI*4);
  int* CNT6  = (int*)take((size_t)6*N_NODE*4);
  int* CNT_E = CNT6,            *CNT_R = CNT6 + N_NODE,   *CNT_A = CNT6 + 2*N_NODE;
  int* CUR_E = CNT6 + 3*N_NODE, *CUR_R = CNT6 + 4*N_NODE, *CUR_A = CNT6 + 5*N_NODE;

  const int* cols = adj + N_TRI;

  // ---- init ----
  k_fill<<<192,256,0,stream>>>((float*)CNT6, (long)6*N_NODE, 0.f);

  // ---- CSR builds ----
  k_hist<<<782,256,0,stream>>>(ent_adj, CNT_E);
  k_hist<<<782,256,0,stream>>>(rel_adj, CNT_R);
  k_hist<<<782,256,0,stream>>>(adj,     CNT_A);
  k_scan3<<<3,256,0,stream>>>(CNT_E, RP_E, CNT_R, RP_R, CNT_A, RP_A, N_NODE);
  k_place<<<782,256,0,stream>>>(ent_adj, ent_adj+N_TRI, RP_E, CUR_E, IDX_E, 1);
  k_place<<<782,256,0,stream>>>(rel_adj, rel_adj+N_TRI, RP_R, CUR_R, IDX_R, 1);
  k_place<<<782,256,0,stream>>>(adj,     (const int*)0, RP_A, CUR_A, IDX_A, 0);

  // ---- feature pipeline (bf16 features) ----
  k_feat0<<<7500,256,0,stream>>>(RP_E, IDX_E, RP_R, IDX_R, ent_emb, rel_emb, OUTB);
  k_trinorm<<<50000,256,0,stream>>>(r_index+N_TRI, r_val, rel_emb, TRI, attn_e, attn_r, ATT4);
  k_gat<<<7500,256,0,stream>>>(RP_A, IDX_A, cols, TRI,
                               ATT4 + 0*N_TRI, ATT4 + 2*N_TRI, OUTB, 0, 128, 384, 512);
  k_gat<<<7500,256,0,stream>>>(RP_A, IDX_A, cols, TRI,
                               ATT4 + 1*N_TRI, ATT4 + 3*N_TRI, OUTB, 128, 256, 512, 640);

  // ---- loss prep ----
  k_packE<<<7520,256,0,stream>>>(OUTB, EP, ESQ);
  k_packA<<<512,256,0,stream>>>(pairs, EP, OUTB, ESQ, AP, ASQ, POS);
  k_fill<<<16,256,0,stream>>>(RS1, (long)NROWA, 0.f);
  k_fill<<<16,256,0,stream>>>(RS2, (long)NROWA, 0.f);
  k_fill<<<16,256,0,stream>>>(RMIN,(long)NROWA, 1e30f);

  // ---- pass 1: GEMM + moments ----
  dim3 gg(NTILE_A, NTILE_E, 1);
  k_gemm<<<gg,256,0,stream>>>(AP, EP, ASQ, ESQ, POS, pairs,
                              RS1, RS2, RMIN, CCv, ALv, REXP, 1);
  k_corr<<<1024,256,0,stream>>>(pairs, AP, EP, ASQ, ESQ, NEGL, NEGR);
  k_stats<<<16,256,0,stream>>>(RS1, RS2, RMIN, NEGL, NEGR, ASQ, POS, pairs,
                               MM, CCv, ALv, REXP);

  // ---- pass 2: GEMM + exp ----
  k_gemm<<<gg,256,0,stream>>>(AP, EP, ASQ, ESQ, POS, pairs,
                              RS1, RS2, RMIN, CCv, ALv, REXP, 2);
  k_final<<<1,256,0,stream>>>(MM, REXP, (float*)d_out);
}

// Round 10
// 962.677 us; speedup vs baseline: 1.2857x; 1.1908x over previous
//
#include <hip/hip_runtime.h>
#include <hip/hip_bf16.h>
#include <math.h>

#define N_NODE 30000
#define N_TRI  200000
#define DIM    128
#define OUTD   768
#define BATCH  2048
#define NROWA  4096
#define EPAD   30080   // 235*128
#define PADN   80      // EPAD - N_NODE
#define NTILE_E 235
#define NTILE_A 32
#define TILE_ELEMS (128*OUTD)
#define KBLK_ELEMS (128*32)
#define GAMMA_C 3.0f
#define LAMB_C  30.0f
#define TAU_C   10.0f

typedef __attribute__((ext_vector_type(8)))  __bf16 bf16x8;
typedef __attribute__((ext_vector_type(4)))  __bf16 bf16x4;
typedef __attribute__((ext_vector_type(2)))  __bf16 bf16x2;
typedef __attribute__((ext_vector_type(8)))  _Float16 half8;
typedef __attribute__((ext_vector_type(4)))  float f32x4;

__device__ __forceinline__ float waveSum(float v){
#pragma unroll
  for (int m=1;m<64;m<<=1) v += __shfl_xor(v, m, 64);
  return v;
}

__device__ __forceinline__ void atomicMinF(float* a, float v){
  if (v >= 0.f) atomicMin((int*)a, __float_as_int(v));
  else          atomicMax((unsigned int*)a, __float_as_uint(v));
}

__device__ __forceinline__ void gl2lds16(const void* g, void* l){
  __builtin_amdgcn_global_load_lds(
      (const __attribute__((address_space(1))) char*)g,
      (__attribute__((address_space(3))) char*)l, 16, 0, 0);
}

__device__ __forceinline__ int swz_off(int r, int q){
  return r*32 + ((q ^ ((r>>1)&3))<<3);
}

// ---------------- fill ----------------
__global__ void k_fill(float* __restrict__ p, long n, float v){
  long i = (long)blockIdx.x*blockDim.x + threadIdx.x;
  long st = (long)gridDim.x*blockDim.x;
  for (; i<n; i+=st) p[i]=v;
}

// ---------------- CSR build ----------------
__global__ __launch_bounds__(256) void k_hist(const int* __restrict__ rows, int* __restrict__ cnt){
  int t = blockIdx.x*256 + threadIdx.x;
  if (t < N_TRI) atomicAdd(&cnt[rows[t]], 1);
}

__global__ __launch_bounds__(256) void k_scan3(
    const int* __restrict__ c0, int* __restrict__ r0,
    const int* __restrict__ c1, int* __restrict__ r1,
    const int* __restrict__ c2, int* __restrict__ r2, int n){
  const int* cnt = blockIdx.x==0 ? c0 : (blockIdx.x==1 ? c1 : c2);
  int* rp        = blockIdx.x==0 ? r0 : (blockIdx.x==1 ? r1 : r2);
  __shared__ int buf[256];
  __shared__ int carry;
  if (threadIdx.x==0) carry = 0;
  __syncthreads();
  for (int base=0; base<n; base+=256){
    int i = base + threadIdx.x;
    int v = (i<n) ? cnt[i] : 0;
    buf[threadIdx.x] = v;
    __syncthreads();
    for (int off=1; off<256; off<<=1){
      int t = (threadIdx.x>=off) ? buf[threadIdx.x-off] : 0;
      __syncthreads();
      buf[threadIdx.x] += t;
      __syncthreads();
    }
    if (i<n) rp[i] = carry + buf[threadIdx.x] - v;
    int tot = buf[255];
    __syncthreads();
    if (threadIdx.x==0) carry += tot;
    __syncthreads();
  }
  if (threadIdx.x==0) rp[n] = carry;
}

__global__ __launch_bounds__(256) void k_place(const int* __restrict__ rows, const int* __restrict__ vals,
                        const int* __restrict__ rowptr, int* __restrict__ cur, int* __restrict__ idx, int mode){
  int t = blockIdx.x*256 + threadIdx.x;
  if (t < N_TRI){
    int r = rows[t];
    int p = atomicAdd(&cur[r], 1);
    idx[rowptr[r] + p] = mode ? vals[t] : t;
  }
}

// ---------------- fused sparse means + tanh -> interleaved bf16 features ----------------
// interleaved layout blocks: [e0 r0 e1 r1 e2 r2], each 128 wide
__global__ __launch_bounds__(256) void k_feat0(
    const int* __restrict__ rpE, const int* __restrict__ idxE,
    const int* __restrict__ rpR, const int* __restrict__ idxR,
    const float* __restrict__ ent_emb, const float* __restrict__ rel_emb,
    __bf16* __restrict__ outb){
  int wave = threadIdx.x>>6, lane = threadIdx.x&63;
  int i = blockIdx.x*4 + wave;
  if (i >= N_NODE) return;
  int bE = rpE[i], eE = rpE[i+1];
  int bR = rpR[i], eR = rpR[i+1];
  float2 aE = {0.f,0.f}, aR = {0.f,0.f};
  for (int k=bE; k<eE; ++k){
    int c = idxE[k];
    float2 v = *(const float2*)(ent_emb + (size_t)c*DIM + lane*2);
    aE.x += v.x; aE.y += v.y;
  }
  for (int k=bR; k<eR; ++k){
    int c = idxR[k];
    float2 v = *(const float2*)(rel_emb + (size_t)c*DIM + lane*2);
    aR.x += v.x; aR.y += v.y;
  }
  float ie = 1.f/fmaxf((float)(eE-bE), 1.f);
  float ir = 1.f/fmaxf((float)(eR-bR), 1.f);
  bf16x2 oE, oR;
  oE[0] = (__bf16)tanhf(aE.x*ie); oE[1] = (__bf16)tanhf(aE.y*ie);
  oR[0] = (__bf16)tanhf(aR.x*ir); oR[1] = (__bf16)tanhf(aR.y*ir);
  *(bf16x2*)(outb + (size_t)i*OUTD +   0 + lane*2) = oE;   // e0
  *(bf16x2*)(outb + (size_t)i*OUTD + 128 + lane*2) = oR;   // r0
}

// ---------------- tri_rel direct + norm(bf16) + att logits ----------------
__global__ __launch_bounds__(256) void k_trinorm(
    const int* __restrict__ ridx1, const float* __restrict__ rval,
    const float* __restrict__ rel_emb,
    __bf16* __restrict__ tri, const float* __restrict__ attnE,
    const float* __restrict__ attnR, float* __restrict__ att4){
  __shared__ float ak[4][DIM];
  int tid = threadIdx.x;
  for (int idx=tid; idx<4*DIM; idx+=256){
    int k = idx>>7, d = idx&127;
    ak[k][d] = (k<2) ? attnE[k*DIM + d] : attnR[(k-2)*DIM + d];
  }
  __syncthreads();
  int wave = tid>>6, lane = tid&63;
  int t = blockIdx.x*4 + wave;
  if (t >= N_TRI) return;
  int rr = ridx1[t];
  float rv = rval[t];
  float2 v = *(const float2*)(rel_emb + (size_t)rr*DIM + lane*2);
  v.x *= rv; v.y *= rv;
  float ss = waveSum(v.x*v.x + v.y*v.y);
  float inv = 1.f/fmaxf(sqrtf(ss), 1e-12f);
  v.x *= inv; v.y *= inv;
  bf16x2 b; b[0] = (__bf16)v.x; b[1] = (__bf16)v.y;
  *(bf16x2*)(tri + (size_t)t*DIM + lane*2) = b;
#pragma unroll
  for (int k=0;k<4;k++){
    float p = waveSum(v.x*ak[k][lane*2] + v.y*ak[k][lane*2+1]);
    if (lane==0) att4[(size_t)k*N_TRI + t] = p;
  }
}

// ---------------- fused GAT layer: half-wave per branch, contiguous 256-dim block ----------------
// lanes 0-31: e-branch (att = attE), lanes 32-63: r-branch (att = attR)
__global__ __launch_bounds__(256) void k_gat(
    const int* __restrict__ rowptr, const int* __restrict__ idx, const int* __restrict__ cols,
    const __bf16* __restrict__ tri,
    const float* __restrict__ attE, const float* __restrict__ attR,
    __bf16* __restrict__ outb, int inOff, int outOff){
  int wave = threadIdx.x>>6, lane = threadIdx.x&63;
  int i = blockIdx.x*4 + wave;
  if (i >= N_NODE) return;
  int l31 = lane&31;
  const float* att = (lane < 32) ? attE : attR;
  int beg = rowptr[i], end = rowptr[i+1];
  float a0=0.f, a1=0.f, a2=0.f, a3=0.f;
  if (end > beg){
    float m = -1e30f;
    for (int k=beg+l31; k<end; k+=32) m = fmaxf(m, att[idx[k]]);
#pragma unroll
    for (int mm=1; mm<32; mm<<=1) m = fmaxf(m, __shfl_xor(m, mm, 64));
    float z = 0.f;
    for (int k=beg+l31; k<end; k+=32) z += __expf(att[idx[k]]-m);
#pragma unroll
    for (int mm=1; mm<32; mm<<=1) z += __shfl_xor(z, mm, 64);
    float iz = 1.f/z;
    for (int k=beg; k<end; ++k){
      int t = idx[k];
      int c = cols[t];
      bf16x4 u4 = *(const bf16x4*)(tri + (size_t)t*DIM + l31*4);
      bf16x4 f4 = *(const bf16x4*)(outb + (size_t)c*OUTD + inOff + lane*4);
      float u0=(float)u4[0], u1=(float)u4[1], u2=(float)u4[2], u3=(float)u4[3];
      float f0=(float)f4[0], f1=(float)f4[1], f2=(float)f4[2], f3=(float)f4[3];
      float d = f0*u0 + f1*u1 + f2*u2 + f3*u3;
#pragma unroll
      for (int mm=1; mm<32; mm<<=1) d += __shfl_xor(d, mm, 64);
      float w = __expf(att[t]-m)*iz;
      float d2 = 2.f*d;
      a0 = fmaf(w, fmaf(-d2, u0, f0), a0);
      a1 = fmaf(w, fmaf(-d2, u1, f1), a1);
      a2 = fmaf(w, fmaf(-d2, u2, f2), a2);
      a3 = fmaf(w, fmaf(-d2, u3, f3), a3);
    }
  }
  bf16x4 o;
  o[0] = (__bf16)tanhf(a0); o[1] = (__bf16)tanhf(a1);
  o[2] = (__bf16)tanhf(a2); o[3] = (__bf16)tanhf(a3);
  *(bf16x4*)(outb + (size_t)i*OUTD + outOff + lane*4) = o;
}

// ---------------- pack E (interleaved bf16 -> canonical swizzled tiles + sumsq) ----------------
// canonical block cb=c>>4 maps to interleaved block perm[cb]
__global__ __launch_bounds__(256) void k_packE(const __bf16* __restrict__ outb, __bf16* __restrict__ Ep, float* __restrict__ esq){
  const int perm[6] = {0,2,4,1,3,5};   // canonical [e0 e1 e2 r0 r1 r2] -> interleaved idx
  int wave = threadIdx.x>>6, lane = threadIdx.x&63;
  int j = blockIdx.x*4 + wave;
  if (j >= EPAD) return;
  int jt = j>>7, r = j&127;
  __bf16* tb = Ep + (size_t)jt*TILE_ELEMS;
  float ss = 0.f;
  for (int c=lane; c<96; c+=64){
    int kb = c>>2, q = c&3;
    bf16x8 o;
    if (j < N_NODE){
      int ib = perm[c>>4], wb = c&15;
      o = *(const bf16x8*)(outb + (size_t)j*OUTD + ib*128 + wb*8);
#pragma unroll
      for (int e=0;e<8;e++){ float v = (float)o[e]; ss += v*v; }
    } else {
#pragma unroll
      for (int e=0;e<8;e++) o[e] = (__bf16)0.f;
    }
    *(bf16x8*)(tb + kb*KBLK_ELEMS + swz_off(r, q)) = o;
  }
  ss = waveSum(ss);
  if (lane==0) esq[j] = (j < N_NODE) ? ss : 0.f;
}

__global__ __launch_bounds__(256) void k_packA(const int* __restrict__ pairs, const __bf16* __restrict__ Ep,
    const __bf16* __restrict__ outb, const float* __restrict__ esq,
    __bf16* __restrict__ Ap, float* __restrict__ asq, float* __restrict__ pos){
  int wave = threadIdx.x>>6, lane = threadIdx.x&63;
  int p = blockIdx.x*4 + wave;
  if (p >= BATCH) return;
  int l = pairs[2*p], r = pairs[2*p+1];
  float ss = 0.f;
#pragma unroll
  for (int c=0;c<6;c++){    // order-invariant over interleaved layout
    int d = c*128 + lane*2;
    bf16x2 a = *(const bf16x2*)(outb + (size_t)l*OUTD + d);
    bf16x2 b = *(const bf16x2*)(outb + (size_t)r*OUTD + d);
    float dx = (float)a[0]-(float)b[0], dy = (float)a[1]-(float)b[1];
    ss += dx*dx + dy*dy;
  }
  ss = waveSum(ss);
  if (lane==0){ pos[p] = ss; asq[p] = esq[l]; asq[p+BATCH] = esq[r]; }
  int lt = l>>7, lr = l&127;
  int rt2 = r>>7, rr = r&127;
  int p0t = p>>7, p0r = p&127;
  int p1t = (p+BATCH)>>7, p1r = (p+BATCH)&127;
  for (int c=lane; c<96; c+=64){
    int kb = c>>2, q = c&3;
    bf16x8 vl = *(const bf16x8*)(Ep + (size_t)lt*TILE_ELEMS + kb*KBLK_ELEMS + swz_off(lr, q));
    *(bf16x8*)(Ap + (size_t)p0t*TILE_ELEMS + kb*KBLK_ELEMS + swz_off(p0r, q)) = vl;
    bf16x8 vr = *(const bf16x8*)(Ep + (size_t)rt2*TILE_ELEMS + kb*KBLK_ELEMS + swz_off(rr, q));
    *(bf16x8*)(Ap + (size_t)p1t*TILE_ELEMS + kb*KBLK_ELEMS + swz_off(p1r, q)) = vr;
  }
}

// ---------------- GEMM (16x16x32, BK=64): pass1 = moments (+partial neg16); pass2 = exp ----------------
__global__ __launch_bounds__(256) void k_gemm(
    const __bf16* __restrict__ Ap, const __bf16* __restrict__ Ep,
    const float* __restrict__ asq, const float* __restrict__ esq,
    const float* __restrict__ pos, const int* __restrict__ pairs,
    float* __restrict__ rs1, float* __restrict__ rs2, float* __restrict__ rmin,
    const float* __restrict__ CC, const float* __restrict__ AL,
    float* __restrict__ rexp, _Float16* __restrict__ neg16, int njstore, int bjOff, int pass)
{
  __shared__ __bf16 sA[2*KBLK_ELEMS];   // 16 KB
  __shared__ __bf16 sB[2*KBLK_ELEMS];   // 16 KB
  __shared__ float red[768];
  int tid = threadIdx.x;

  int wave = tid>>6, lane = tid&63, quad = lane>>4, l16 = lane&15;
  int bi = blockIdx.x, bj = blockIdx.y + bjOff;
  int wi = wave>>1, wj = wave&1;

  const __bf16* Asrc = Ap + (size_t)bi*TILE_ELEMS;
  const __bf16* Bsrc = Ep + (size_t)bj*TILE_ELEMS;

  int a_off[4], b_off[4];
#pragma unroll
  for (int rt=0; rt<4; ++rt){ int row = wi*64 + rt*16 + l16; a_off[rt] = swz_off(row, quad); }
#pragma unroll
  for (int ct=0; ct<4; ++ct){ int row = wj*64 + ct*16 + l16; b_off[ct] = swz_off(row, quad); }

  const __bf16* gsrc = (wave<2 ? Asrc : Bsrc);
  __bf16* ldsb = (wave<2 ? sA : sB);
  int half = (wave&1)*KBLK_ELEMS;

  const f32x4 zf = {0.f,0.f,0.f,0.f};
  f32x4 acc[4][4];
#pragma unroll
  for (int rt=0; rt<4; ++rt)
#pragma unroll
    for (int ct=0; ct<4; ++ct) acc[rt][ct] = zf;

  for (int kb2=0; kb2<12; ++kb2){
    __syncthreads();
    const __bf16* g = gsrc + kb2*(2*KBLK_ELEMS) + half + lane*8;
#pragma unroll
    for (int s=0; s<8; ++s)
      gl2lds16(g + s*512, ldsb + half + s*512);
    __syncthreads();
#pragma unroll
    for (int ks=0; ks<2; ++ks){
      int o = ks*KBLK_ELEMS;
      bf16x8 af[4], bf[4];
#pragma unroll
      for (int rt=0; rt<4; ++rt) af[rt] = *(const bf16x8*)(sA + o + a_off[rt]);
#pragma unroll
      for (int ct=0; ct<4; ++ct) bf[ct] = *(const bf16x8*)(sB + o + b_off[ct]);
#pragma unroll
      for (int rt=0; rt<4; ++rt)
#pragma unroll
        for (int ct=0; ct<4; ++ct)
          acc[rt][ct] = __builtin_amdgcn_mfma_f32_16x16x32_bf16(af[rt], bf[ct], acc[rt][ct], 0,0,0);
    }
  }

  // ---- epilogue ----
  int jbase = bj*128 + wj*64;
  float esqv[4]; bool val[4]; int jcol[4];
#pragma unroll
  for (int ct=0; ct<4; ++ct){
    jcol[ct] = jbase + ct*16 + l16;
    val[ct] = jcol[ct] < N_NODE;
    esqv[ct] = esq[jcol[ct]];
  }

  if (pass == 1){
    bool doStore = (bj < njstore);
    size_t tBase = ((size_t)bj*NTILE_A + bi)*16384;
#pragma unroll
    for (int rt=0; rt<4; ++rt){
      _Float16 h16[16];
#pragma unroll
      for (int reg=0; reg<4; ++reg){
        int il = wi*64 + rt*16 + quad*4 + reg;
        int i  = bi*128 + il;
        int p  = i & (BATCH-1);
        int li = pairs[2*p], ri = pairs[2*p+1];
        float av = asq[i];
        float s=0.f, q=0.f, mn=1e30f;
#pragma unroll
        for (int ct=0; ct<4; ++ct){
          float neg = (av + esqv[ct]) - 2.f*acc[rt][ct][reg];
          s += neg;
          q = fmaf(neg, neg, q);
          bool bad = (jcol[ct]==li) | (jcol[ct]==ri) | (!val[ct]);
          mn = fminf(mn, bad ? 1e30f : neg);
          h16[reg*4+ct] = (_Float16)neg;
        }
#pragma unroll
        for (int m=1;m<16;m<<=1){
          s += __shfl_xor(s,m,64); q += __shfl_xor(q,m,64);
          mn = fminf(mn, __shfl_xor(mn,m,64));
        }
        if (l16 == 0){
          red[il*2+wj] = s; red[256 + il*2+wj] = q; red[512 + il*2+wj] = mn;
        }
      }
      if (doStore){
        _Float16* dst = neg16 + tBase + ((size_t)(wave*4 + rt))*1024 + lane*16;
        *(half8*)(dst)     = *(half8*)&h16[0];
        *(half8*)(dst + 8) = *(half8*)&h16[8];
      }
    }
    __syncthreads();
    if (tid < 128){
      int i = bi*128 + tid;
      atomicAdd(rs1+i, red[tid*2] + red[tid*2+1]);
      atomicAdd(rs2+i, red[256 + tid*2] + red[256 + tid*2+1]);
      atomicMinF(rmin+i, fminf(red[512 + tid*2], red[512 + tid*2+1]));
    }
  } else {
#pragma unroll
    for (int rt=0; rt<4; ++rt){
#pragma unroll
      for (int reg=0; reg<4; ++reg){
        int il = wi*64 + rt*16 + quad*4 + reg;
        int i  = bi*128 + il;
        int p  = i & (BATCH-1);
        int li = pairs[2*p], ri = pairs[2*p+1];
        float av = asq[i];
        float C = CC[i], A = AL[i];
        float s = 0.f;
#pragma unroll
        for (int ct=0; ct<4; ++ct){
          float neg = (av + esqv[ct]) - 2.f*acc[rt][ct][reg];
          bool bad = (jcol[ct]==li) | (jcol[ct]==ri) | (!val[ct]);
          s += bad ? 0.f : __expf(fmaf(-A, neg, C));
        }
#pragma unroll
        for (int m=1;m<16;m<<=1) s += __shfl_xor(s,m,64);
        if (l16 == 0) red[il*2+wj] = s;
      }
    }
    __syncthreads();
    if (tid < 128){
      int i = bi*128 + tid;
      atomicAdd(rexp+i, red[tid*2] + red[tid*2+1]);
    }
  }
}

// ---------------- streaming pass 2 over stored fp16 neg ----------------
__global__ __launch_bounds__(256) void k_p2s(
    const _Float16* __restrict__ neg16, const float* __restrict__ CC, const float* __restrict__ AL,
    const int* __restrict__ pairs, float* __restrict__ rexp)
{
  __shared__ float red[256];
  int tid = threadIdx.x;
  int wave = tid>>6, lane = tid&63, quad = lane>>4, l16 = lane&15;
  int bi = blockIdx.x, bj = blockIdx.y;
  int wi = wave>>1, wj = wave&1;
  int jbase = bj*128 + wj*64;
  bool val[4]; int jcol[4];
#pragma unroll
  for (int ct=0; ct<4; ++ct){
    jcol[ct] = jbase + ct*16 + l16;
    val[ct] = jcol[ct] < N_NODE;
  }
  size_t tBase = ((size_t)bj*NTILE_A + bi)*16384;
#pragma unroll
  for (int rt=0; rt<4; ++rt){
    const _Float16* src = neg16 + tBase + ((size_t)(wave*4 + rt))*1024 + lane*16;
    half8 v0 = *(const half8*)(src);
    half8 v1 = *(const half8*)(src + 8);
    _Float16 h16[16];
    *(half8*)&h16[0] = v0; *(half8*)&h16[8] = v1;
#pragma unroll
    for (int reg=0; reg<4; ++reg){
      int il = wi*64 + rt*16 + quad*4 + reg;
      int i  = bi*128 + il;
      int p  = i & (BATCH-1);
      int li = pairs[2*p], ri = pairs[2*p+1];
      float C = CC[i], A = AL[i];
      float s = 0.f;
#pragma unroll
      for (int ct=0; ct<4; ++ct){
        float neg = (float)h16[reg*4+ct];
        bool bad = (jcol[ct]==li) | (jcol[ct]==ri) | (!val[ct]);
        s += bad ? 0.f : __expf(fmaf(-A, neg, C));
      }
#pragma unroll
      for (int m=1;m<16;m<<=1) s += __shfl_xor(s,m,64);
      if (l16 == 0) red[il*2+wj] = s;
    }
  }
  __syncthreads();
  if (tid < 128){
    int i = bi*128 + tid;
    atomicAdd(rexp+i, red[tid*2] + red[tid*2+1]);
  }
}

// ---------------- per-row special-column dots ----------------
__global__ __launch_bounds__(256) void k_corr(
    const int* __restrict__ pairs, const __bf16* __restrict__ Ap, const __bf16* __restrict__ Ep,
    const float* __restrict__ asq, const float* __restrict__ esq,
    float* __restrict__ negl, float* __restrict__ negr)
{
  int wave = threadIdx.x>>6, lane = threadIdx.x&63;
  int i = blockIdx.x*4 + wave;
  if (i >= NROWA) return;
  int p = i & (BATCH-1);
  int li = pairs[2*p], ri = pairs[2*p+1];
  const __bf16* Ar = Ap + (size_t)(i>>7)*TILE_ELEMS;  int ra = i&127;
  const __bf16* E1 = Ep + (size_t)(li>>7)*TILE_ELEMS; int r1 = li&127;
  const __bf16* E2 = Ep + (size_t)(ri>>7)*TILE_ELEMS; int r2 = ri&127;
  float d1=0.f, d2=0.f;
  for (int c=lane; c<96; c+=64){
    int kb = c>>2, q = c&3;
    bf16x8 a  = *(const bf16x8*)(Ar + kb*KBLK_ELEMS + swz_off(ra, q));
    bf16x8 e1 = *(const bf16x8*)(E1 + kb*KBLK_ELEMS + swz_off(r1, q));
    bf16x8 e2 = *(const bf16x8*)(E2 + kb*KBLK_ELEMS + swz_off(r2, q));
#pragma unroll
    for (int e=0;e<8;e++){
      d1 = fmaf((float)a[e], (float)e1[e], d1);
      d2 = fmaf((float)a[e], (float)e2[e], d2);
    }
  }
  d1 = waveSum(d1); d2 = waveSum(d2);
  if (lane==0){
    float av = asq[i];
    negl[i] = av + esq[li] - 2.f*d1;
    negr[i] = av + esq[ri] - 2.f*d2;
  }
}

// ---------------- stats ----------------
__global__ __launch_bounds__(256) void k_stats(
    const float* __restrict__ rs1, const float* __restrict__ rs2, const float* __restrict__ rmin,
    const float* __restrict__ negl, const float* __restrict__ negr,
    const float* __restrict__ asq, const float* __restrict__ pos, const int* __restrict__ pairs,
    float* __restrict__ MM, float* __restrict__ CC, float* __restrict__ AL, float* __restrict__ rexp)
{
  int i = blockIdx.x*256 + threadIdx.x;
  if (i >= NROWA) return;
  int p = i & (BATCH-1);
  int li = pairs[2*p], ri = pairs[2*p+1];
  float K = pos[p] + GAMMA_C;
  float av = asq[i];
  float S1 = rs1[i] - (float)PADN*av;
  float S2 = rs2[i] - (float)PADN*av*av;
  float nl = negl[i], nr = negr[i];
  float Sx, Sxx, mx;
  const float invN = 1.f/(float)N_NODE;
  if (li != ri){
    Sx  = -(S1 - nl - nr) - 2.f*K;
    Sxx = (S2 - nl*nl - nr*nr) + 2.f*K*K;
    mx  = fmaxf(K - rmin[i], 0.f);
    float mu = K + Sx*invN;
    float m2 = Sx*invN;
    float var = Sxx*invN - m2*m2;
    float sd = sqrtf(fmaxf(var, 1e-30f));
    float M = LAMB_C*(mx-mu)/sd + TAU_C;
    MM[i] = M; CC[i] = LAMB_C*(K-mu)/sd + TAU_C - M; AL[i] = LAMB_C/sd;
    rexp[i] = 2.f*__expf(LAMB_C*(0.f-mu)/sd + TAU_C - M);
  } else {
    float lossm = nl - K;
    float x = lossm - K;
    Sx  = -(S1 - nl) + x;
    Sxx = (S2 - nl*nl) + x*x;
    mx  = fmaxf(K - rmin[i], lossm);
    float mu = K + Sx*invN;
    float m2 = Sx*invN;
    float var = Sxx*invN - m2*m2;
    float sd = sqrtf(fmaxf(var, 1e-30f));
    float M = LAMB_C*(mx-mu)/sd + TAU_C;
    MM[i] = M; CC[i] = LAMB_C*(K-mu)/sd + TAU_C - M; AL[i] = LAMB_C/sd;
    rexp[i] = __expf(LAMB_C*(lossm-mu)/sd + TAU_C - M);
  }
}

__global__ __launch_bounds__(256) void k_final(const float* __restrict__ mm, const float* __restrict__ rexp, float* __restrict__ out){
  __shared__ float red[256];
  float s = 0.f;
  for (int i=threadIdx.x; i<NROWA; i+=256) s += mm[i] + logf(rexp[i]);
  red[threadIdx.x] = s; __syncthreads();
  for (int st=128; st>0; st>>=1){ if (threadIdx.x<st) red[threadIdx.x]+=red[threadIdx.x+st]; __syncthreads(); }
  if (threadIdx.x==0) out[0] = red[0]*(1.f/BATCH);
}

extern "C" void kernel_launch(void* const* d_in, const int* in_sizes, int n_in,
                              void* d_out, int out_size, void* d_ws, size_t ws_size,
                              hipStream_t stream) {
  const int*   pairs   = (const int*)d_in[0];
  const int*   ent_adj = (const int*)d_in[1];
  const int*   rel_adj = (const int*)d_in[2];
  const int*   adj     = (const int*)d_in[3];
  const int*   r_index = (const int*)d_in[4];
  const float* r_val   = (const float*)d_in[5];
  const float* ent_emb = (const float*)d_in[7];
  const float* rel_emb = (const float*)d_in[8];
  const float* attn_e  = (const float*)d_in[9];
  const float* attn_r  = (const float*)d_in[10];

  char* base = (char*)d_ws;
  size_t off = 0;
  auto take = [&](size_t bytes)->char*{
    char* p = base + off;
    off = (off + bytes + 511) & ~(size_t)511;
    return p;
  };
  // persistent GEMM-phase region (~53.5 MB)
  __bf16* EP    = (__bf16*)take((size_t)NTILE_E*TILE_ELEMS*2);
  __bf16* AP    = (__bf16*)take((size_t)NTILE_A*TILE_ELEMS*2);
  float*  ESQ   = (float*)take((size_t)EPAD*4);
  float*  ASQ   = (float*)take((size_t)NROWA*4);
  float*  POS   = (float*)take((size_t)BATCH*4);
  float*  RS1   = (float*)take((size_t)NROWA*4);
  float*  RS2   = (float*)take((size_t)NROWA*4);
  float*  RMIN  = (float*)take((size_t)NROWA*4);
  float*  NEGL  = (float*)take((size_t)NROWA*4);
  float*  NEGR  = (float*)take((size_t)NROWA*4);
  float*  MM    = (float*)take((size_t)NROWA*4);
  float*  CCv   = (float*)take((size_t)NROWA*4);
  float*  ALv   = (float*)take((size_t)NROWA*4);
  float*  REXP  = (float*)take((size_t)NROWA*4);

  // graph-phase region (dead by GEMM time) — overlapped by NEG16
  size_t offG = off;
  __bf16* OUTB = (__bf16*)take((size_t)N_NODE*OUTD*2);     // 46.1 MB, interleaved layout
  __bf16* TRI  = (__bf16*)take((size_t)N_TRI*DIM*2);       // 51.2 MB
  float*  ATT4 = (float*)take((size_t)4*N_TRI*4);          // 3.2 MB
  int* RP_E  = (int*)take((size_t)(N_NODE+1)*4);
  int* RP_R  = (int*)take((size_t)(N_NODE+1)*4);
  int* RP_A  = (int*)take((size_t)(N_NODE+1)*4);
  int* IDX_E = (int*)take((size_t)N_TRI*4);
  int* IDX_R = (int*)take((size_t)N_TRI*4);
  int* IDX_A = (int*)take((size_t)N_TRI*4);
  int* CNT6  = (int*)take((size_t)6*N_NODE*4);
  int* CNT_E = CNT6,            *CNT_R = CNT6 + N_NODE,   *CNT_A = CNT6 + 2*N_NODE;
  int* CUR_E = CNT6 + 3*N_NODE, *CUR_R = CNT6 + 4*N_NODE, *CUR_A = CNT6 + 5*N_NODE;

  // NEG16 overlays the graph region; njstore j-tile-columns fit (1 MB per bj)
  _Float16* NEG16 = (_Float16*)(base + offG);
  long perBj = (long)NTILE_A * 16384 * 2;   // 1 MiB
  long njs = (ws_size > offG) ? (long)((ws_size - offG) / perBj) : 0;
  if (njs > NTILE_E) njs = NTILE_E;
  int njstore = (int)njs;
  int rem = NTILE_E - njstore;

  const int* cols = adj + N_TRI;

  // ---- init ----
  k_fill<<<192,256,0,stream>>>((float*)CNT6, (long)6*N_NODE, 0.f);

  // ---- CSR builds ----
  k_hist<<<782,256,0,stream>>>(ent_adj, CNT_E);
  k_hist<<<782,256,0,stream>>>(rel_adj, CNT_R);
  k_hist<<<782,256,0,stream>>>(adj,     CNT_A);
  k_scan3<<<3,256,0,stream>>>(CNT_E, RP_E, CNT_R, RP_R, CNT_A, RP_A, N_NODE);
  k_place<<<782,256,0,stream>>>(ent_adj, ent_adj+N_TRI, RP_E, CUR_E, IDX_E, 1);
  k_place<<<782,256,0,stream>>>(rel_adj, rel_adj+N_TRI, RP_R, CUR_R, IDX_R, 1);
  k_place<<<782,256,0,stream>>>(adj,     (const int*)0, RP_A, CUR_A, IDX_A, 0);

  // ---- feature pipeline (interleaved bf16 features) ----
  k_feat0<<<7500,256,0,stream>>>(RP_E, IDX_E, RP_R, IDX_R, ent_emb, rel_emb, OUTB);
  k_trinorm<<<50000,256,0,stream>>>(r_index+N_TRI, r_val, rel_emb, TRI, attn_e, attn_r, ATT4);
  k_gat<<<7500,256,0,stream>>>(RP_A, IDX_A, cols, TRI,
                               ATT4 + 0*N_TRI, ATT4 + 2*N_TRI, OUTB, 0, 256);
  k_gat<<<7500,256,0,stream>>>(RP_A, IDX_A, cols, TRI,
                               ATT4 + 1*N_TRI, ATT4 + 3*N_TRI, OUTB, 256, 512);

  // ---- loss prep ----
  k_packE<<<7520,256,0,stream>>>(OUTB, EP, ESQ);
  k_packA<<<512,256,0,stream>>>(pairs, EP, OUTB, ESQ, AP, ASQ, POS);
  k_fill<<<16,256,0,stream>>>(RS1, (long)NROWA, 0.f);
  k_fill<<<16,256,0,stream>>>(RS2, (long)NROWA, 0.f);
  k_fill<<<16,256,0,stream>>>(RMIN,(long)NROWA, 1e30f);

  // ---- pass 1: GEMM + moments (+neg16 store for bj < njstore) ----
  dim3 gg(NTILE_A, NTILE_E, 1);
  k_gemm<<<gg,256,0,stream>>>(AP, EP, ASQ, ESQ, POS, pairs,
                              RS1, RS2, RMIN, CCv, ALv, REXP, NEG16, njstore, 0, 1);
  k_corr<<<1024,256,0,stream>>>(pairs, AP, EP, ASQ, ESQ, NEGL, NEGR);
  k_stats<<<16,256,0,stream>>>(RS1, RS2, RMIN, NEGL, NEGR, ASQ, POS, pairs,
                               MM, CCv, ALv, REXP);

  // ---- pass 2: streamed exp over stored tiles + recompute for the rest ----
  if (njstore > 0){
    dim3 gs(NTILE_A, njstore, 1);
    k_p2s<<<gs,256,0,stream>>>(NEG16, CCv, ALv, pairs, REXP);
  }
  if (rem > 0){
    dim3 gr(NTILE_A, rem, 1);
    k_gemm<<<gr,256,0,stream>>>(AP, EP, ASQ, ESQ, POS, pairs,
                                RS1, RS2, RMIN, CCv, ALv, REXP, NEG16, njstore, njstore, 2);
  }
  k_final<<<1,256,0,stream>>>(MM, REXP, (float*)d_out);
}

// Round 11
// 922.126 us; speedup vs baseline: 1.3423x; 1.0440x over previous
//
#include <hip/hip_runtime.h>
#include <hip/hip_bf16.h>
#include <math.h>

#define N_NODE 30000
#define N_TRI  200000
#define DIM    128
#define OUTD   768
#define BATCH  2048
#define NROWA  4096
#define EPAD   30080   // 235*128
#define PADN   80      // EPAD - N_NODE
#define NTILE_E 235
#define NTILE_A 32
#define TILE_ELEMS (128*OUTD)
#define KBLK_ELEMS (128*32)
#define GAMMA_C 3.0f
#define LAMB_C  30.0f
#define TAU_C   10.0f

typedef __attribute__((ext_vector_type(8)))  __bf16 bf16x8;
typedef __attribute__((ext_vector_type(4)))  __bf16 bf16x4;
typedef __attribute__((ext_vector_type(2)))  __bf16 bf16x2;
typedef __attribute__((ext_vector_type(8)))  _Float16 half8;
typedef __attribute__((ext_vector_type(4)))  float f32x4;

__device__ __forceinline__ float waveSum(float v){
#pragma unroll
  for (int m=1;m<64;m<<=1) v += __shfl_xor(v, m, 64);
  return v;
}

__device__ __forceinline__ void atomicMinF(float* a, float v){
  if (v >= 0.f) atomicMin((int*)a, __float_as_int(v));
  else          atomicMax((unsigned int*)a, __float_as_uint(v));
}

__device__ __forceinline__ void gl2lds16(const void* g, void* l){
  __builtin_amdgcn_global_load_lds(
      (const __attribute__((address_space(1))) char*)g,
      (__attribute__((address_space(3))) char*)l, 16, 0, 0);
}

__device__ __forceinline__ int swz_off(int r, int q){
  return r*32 + ((q ^ ((r>>1)&3))<<3);
}

// ---------------- fill ----------------
__global__ void k_fill(float* __restrict__ p, long n, float v){
  long i = (long)blockIdx.x*blockDim.x + threadIdx.x;
  long st = (long)gridDim.x*blockDim.x;
  for (; i<n; i+=st) p[i]=v;
}

// ---------------- CSR build ----------------
__global__ __launch_bounds__(256) void k_hist(const int* __restrict__ rows, int* __restrict__ cnt){
  int t = blockIdx.x*256 + threadIdx.x;
  if (t < N_TRI) atomicAdd(&cnt[rows[t]], 1);
}

__global__ __launch_bounds__(256) void k_scan3(
    const int* __restrict__ c0, int* __restrict__ r0,
    const int* __restrict__ c1, int* __restrict__ r1,
    const int* __restrict__ c2, int* __restrict__ r2, int n){
  const int* cnt = blockIdx.x==0 ? c0 : (blockIdx.x==1 ? c1 : c2);
  int* rp        = blockIdx.x==0 ? r0 : (blockIdx.x==1 ? r1 : r2);
  __shared__ int buf[256];
  __shared__ int carry;
  if (threadIdx.x==0) carry = 0;
  __syncthreads();
  for (int base=0; base<n; base+=256){
    int i = base + threadIdx.x;
    int v = (i<n) ? cnt[i] : 0;
    buf[threadIdx.x] = v;
    __syncthreads();
    for (int off=1; off<256; off<<=1){
      int t = (threadIdx.x>=off) ? buf[threadIdx.x-off] : 0;
      __syncthreads();
      buf[threadIdx.x] += t;
      __syncthreads();
    }
    if (i<n) rp[i] = carry + buf[threadIdx.x] - v;
    int tot = buf[255];
    __syncthreads();
    if (threadIdx.x==0) carry += tot;
    __syncthreads();
  }
  if (threadIdx.x==0) rp[n] = carry;
}

__global__ __launch_bounds__(256) void k_place(const int* __restrict__ rows, const int* __restrict__ vals,
                        const int* __restrict__ rowptr, int* __restrict__ cur, int* __restrict__ idx, int mode){
  int t = blockIdx.x*256 + threadIdx.x;
  if (t < N_TRI){
    int r = rows[t];
    int p = atomicAdd(&cur[r], 1);
    idx[rowptr[r] + p] = mode ? vals[t] : t;
  }
}

// ---------------- fused sparse means + tanh -> interleaved bf16 features ----------------
__global__ __launch_bounds__(256) void k_feat0(
    const int* __restrict__ rpE, const int* __restrict__ idxE,
    const int* __restrict__ rpR, const int* __restrict__ idxR,
    const float* __restrict__ ent_emb, const float* __restrict__ rel_emb,
    __bf16* __restrict__ outb){
  int wave = threadIdx.x>>6, lane = threadIdx.x&63;
  int i = blockIdx.x*4 + wave;
  if (i >= N_NODE) return;
  int bE = rpE[i], eE = rpE[i+1];
  int bR = rpR[i], eR = rpR[i+1];
  float2 aE = {0.f,0.f}, aR = {0.f,0.f};
  for (int k=bE; k<eE; ++k){
    int c = idxE[k];
    float2 v = *(const float2*)(ent_emb + (size_t)c*DIM + lane*2);
    aE.x += v.x; aE.y += v.y;
  }
  for (int k=bR; k<eR; ++k){
    int c = idxR[k];
    float2 v = *(const float2*)(rel_emb + (size_t)c*DIM + lane*2);
    aR.x += v.x; aR.y += v.y;
  }
  float ie = 1.f/fmaxf((float)(eE-bE), 1.f);
  float ir = 1.f/fmaxf((float)(eR-bR), 1.f);
  bf16x2 oE, oR;
  oE[0] = (__bf16)tanhf(aE.x*ie); oE[1] = (__bf16)tanhf(aE.y*ie);
  oR[0] = (__bf16)tanhf(aR.x*ir); oR[1] = (__bf16)tanhf(aR.y*ir);
  *(bf16x2*)(outb + (size_t)i*OUTD +   0 + lane*2) = oE;   // e0
  *(bf16x2*)(outb + (size_t)i*OUTD + 128 + lane*2) = oR;   // r0
}

// ---------------- tri_rel direct + norm(bf16) + att logits ----------------
__global__ __launch_bounds__(256) void k_trinorm(
    const int* __restrict__ ridx1, const float* __restrict__ rval,
    const float* __restrict__ rel_emb,
    __bf16* __restrict__ tri, const float* __restrict__ attnE,
    const float* __restrict__ attnR, float* __restrict__ att4){
  __shared__ float ak[4][DIM];
  int tid = threadIdx.x;
  for (int idx=tid; idx<4*DIM; idx+=256){
    int k = idx>>7, d = idx&127;
    ak[k][d] = (k<2) ? attnE[k*DIM + d] : attnR[(k-2)*DIM + d];
  }
  __syncthreads();
  int wave = tid>>6, lane = tid&63;
  int t = blockIdx.x*4 + wave;
  if (t >= N_TRI) return;
  int rr = ridx1[t];
  float rv = rval[t];
  float2 v = *(const float2*)(rel_emb + (size_t)rr*DIM + lane*2);
  v.x *= rv; v.y *= rv;
  float ss = waveSum(v.x*v.x + v.y*v.y);
  float inv = 1.f/fmaxf(sqrtf(ss), 1e-12f);
  v.x *= inv; v.y *= inv;
  bf16x2 b; b[0] = (__bf16)v.x; b[1] = (__bf16)v.y;
  *(bf16x2*)(tri + (size_t)t*DIM + lane*2) = b;
#pragma unroll
  for (int k=0;k<4;k++){
    float p = waveSum(v.x*ak[k][lane*2] + v.y*ak[k][lane*2+1]);
    if (lane==0) att4[(size_t)k*N_TRI + t] = p;
  }
}

// ---------------- fused GAT layer: half-wave per branch, 2-edge software pipeline ----------------
__global__ __launch_bounds__(256) void k_gat(
    const int* __restrict__ rowptr, const int* __restrict__ idx, const int* __restrict__ cols,
    const __bf16* __restrict__ tri,
    const float* __restrict__ attE, const float* __restrict__ attR,
    __bf16* __restrict__ outb, int inOff, int outOff){
  int wave = threadIdx.x>>6, lane = threadIdx.x&63;
  int i = blockIdx.x*4 + wave;
  if (i >= N_NODE) return;
  int l31 = lane&31;
  const float* att = (lane < 32) ? attE : attR;
  int beg = rowptr[i], end = rowptr[i+1];
  float a0=0.f, a1=0.f, a2=0.f, a3=0.f;
  if (end > beg){
    float m = -1e30f;
    for (int k=beg+l31; k<end; k+=32) m = fmaxf(m, att[idx[k]]);
#pragma unroll
    for (int mm=1; mm<32; mm<<=1) m = fmaxf(m, __shfl_xor(m, mm, 64));
    float z = 0.f;
    for (int k=beg+l31; k<end; k+=32) z += __expf(att[idx[k]]-m);
#pragma unroll
    for (int mm=1; mm<32; mm<<=1) z += __shfl_xor(z, mm, 64);
    float iz = 1.f/z;
    // software-pipelined edge loop
    int t0 = idx[beg];
    int c0 = cols[t0];
    bf16x4 u4 = *(const bf16x4*)(tri + (size_t)t0*DIM + l31*4);
    bf16x4 f4 = *(const bf16x4*)(outb + (size_t)c0*OUTD + inOff + lane*4);
    float atv = att[t0];
    for (int k=beg; k<end; ++k){
      bf16x4 u4c = u4, f4c = f4;
      float atc = atv;
      if (k+1 < end){
        int t1 = idx[k+1];
        int c1 = cols[t1];
        u4 = *(const bf16x4*)(tri + (size_t)t1*DIM + l31*4);
        f4 = *(const bf16x4*)(outb + (size_t)c1*OUTD + inOff + lane*4);
        atv = att[t1];
      }
      float u0=(float)u4c[0], u1=(float)u4c[1], u2=(float)u4c[2], u3=(float)u4c[3];
      float f0=(float)f4c[0], f1=(float)f4c[1], f2=(float)f4c[2], f3=(float)f4c[3];
      float d = f0*u0 + f1*u1 + f2*u2 + f3*u3;
#pragma unroll
      for (int mm=1; mm<32; mm<<=1) d += __shfl_xor(d, mm, 64);
      float w = __expf(atc-m)*iz;
      float d2 = 2.f*d;
      a0 = fmaf(w, fmaf(-d2, u0, f0), a0);
      a1 = fmaf(w, fmaf(-d2, u1, f1), a1);
      a2 = fmaf(w, fmaf(-d2, u2, f2), a2);
      a3 = fmaf(w, fmaf(-d2, u3, f3), a3);
    }
  }
  bf16x4 o;
  o[0] = (__bf16)tanhf(a0); o[1] = (__bf16)tanhf(a1);
  o[2] = (__bf16)tanhf(a2); o[3] = (__bf16)tanhf(a3);
  *(bf16x4*)(outb + (size_t)i*OUTD + outOff + lane*4) = o;
}

// ---------------- pack E (interleaved bf16 -> canonical swizzled tiles + sumsq) ----------------
__global__ __launch_bounds__(256) void k_packE(const __bf16* __restrict__ outb, __bf16* __restrict__ Ep, float* __restrict__ esq){
  const int perm[6] = {0,2,4,1,3,5};
  int wave = threadIdx.x>>6, lane = threadIdx.x&63;
  int j = blockIdx.x*4 + wave;
  if (j >= EPAD) return;
  int jt = j>>7, r = j&127;
  __bf16* tb = Ep + (size_t)jt*TILE_ELEMS;
  float ss = 0.f;
  for (int c=lane; c<96; c+=64){
    int kb = c>>2, q = c&3;
    bf16x8 o;
    if (j < N_NODE){
      int ib = perm[c>>4], wb = c&15;
      o = *(const bf16x8*)(outb + (size_t)j*OUTD + ib*128 + wb*8);
#pragma unroll
      for (int e=0;e<8;e++){ float v = (float)o[e]; ss += v*v; }
    } else {
#pragma unroll
      for (int e=0;e<8;e++) o[e] = (__bf16)0.f;
    }
    *(bf16x8*)(tb + kb*KBLK_ELEMS + swz_off(r, q)) = o;
  }
  ss = waveSum(ss);
  if (lane==0) esq[j] = (j < N_NODE) ? ss : 0.f;
}

__global__ __launch_bounds__(256) void k_packA(const int* __restrict__ pairs, const __bf16* __restrict__ Ep,
    const __bf16* __restrict__ outb, const float* __restrict__ esq,
    __bf16* __restrict__ Ap, float* __restrict__ asq, float* __restrict__ pos){
  int wave = threadIdx.x>>6, lane = threadIdx.x&63;
  int p = blockIdx.x*4 + wave;
  if (p >= BATCH) return;
  int l = pairs[2*p], r = pairs[2*p+1];
  float ss = 0.f;
#pragma unroll
  for (int c=0;c<6;c++){
    int d = c*128 + lane*2;
    bf16x2 a = *(const bf16x2*)(outb + (size_t)l*OUTD + d);
    bf16x2 b = *(const bf16x2*)(outb + (size_t)r*OUTD + d);
    float dx = (float)a[0]-(float)b[0], dy = (float)a[1]-(float)b[1];
    ss += dx*dx + dy*dy;
  }
  ss = waveSum(ss);
  if (lane==0){ pos[p] = ss; asq[p] = esq[l]; asq[p+BATCH] = esq[r]; }
  int lt = l>>7, lr = l&127;
  int rt2 = r>>7, rr = r&127;
  int p0t = p>>7, p0r = p&127;
  int p1t = (p+BATCH)>>7, p1r = (p+BATCH)&127;
  for (int c=lane; c<96; c+=64){
    int kb = c>>2, q = c&3;
    bf16x8 vl = *(const bf16x8*)(Ep + (size_t)lt*TILE_ELEMS + kb*KBLK_ELEMS + swz_off(lr, q));
    *(bf16x8*)(Ap + (size_t)p0t*TILE_ELEMS + kb*KBLK_ELEMS + swz_off(p0r, q)) = vl;
    bf16x8 vr = *(const bf16x8*)(Ep + (size_t)rt2*TILE_ELEMS + kb*KBLK_ELEMS + swz_off(rr, q));
    *(bf16x8*)(Ap + (size_t)p1t*TILE_ELEMS + kb*KBLK_ELEMS + swz_off(p1r, q)) = vr;
  }
}

// ---------------- GEMM (16x16x32, BK=64) ----------------
// pass1, bj<njstore : store neg16 only (epilogue-lite; moments come from k_mom)
// pass1, bj>=njstore: full moment epilogue
// pass2             : exp epilogue (recompute path for rem tiles)
__global__ __launch_bounds__(256) void k_gemm(
    const __bf16* __restrict__ Ap, const __bf16* __restrict__ Ep,
    const float* __restrict__ asq, const float* __restrict__ esq,
    const float* __restrict__ pos, const int* __restrict__ pairs,
    float* __restrict__ rs1, float* __restrict__ rs2, float* __restrict__ rmin,
    const float* __restrict__ CC, const float* __restrict__ AL,
    float* __restrict__ rexp, _Float16* __restrict__ neg16, int njstore, int bjOff, int pass)
{
  __shared__ __bf16 sA[2*KBLK_ELEMS];   // 16 KB
  __shared__ __bf16 sB[2*KBLK_ELEMS];   // 16 KB
  __shared__ float red[768];
  int tid = threadIdx.x;

  int wave = tid>>6, lane = tid&63, quad = lane>>4, l16 = lane&15;
  int bi = blockIdx.x, bj = blockIdx.y + bjOff;
  int wi = wave>>1, wj = wave&1;

  const __bf16* Asrc = Ap + (size_t)bi*TILE_ELEMS;
  const __bf16* Bsrc = Ep + (size_t)bj*TILE_ELEMS;

  int a_off[4], b_off[4];
#pragma unroll
  for (int rt=0; rt<4; ++rt){ int row = wi*64 + rt*16 + l16; a_off[rt] = swz_off(row, quad); }
#pragma unroll
  for (int ct=0; ct<4; ++ct){ int row = wj*64 + ct*16 + l16; b_off[ct] = swz_off(row, quad); }

  const __bf16* gsrc = (wave<2 ? Asrc : Bsrc);
  __bf16* ldsb = (wave<2 ? sA : sB);
  int half = (wave&1)*KBLK_ELEMS;

  const f32x4 zf = {0.f,0.f,0.f,0.f};
  f32x4 acc[4][4];
#pragma unroll
  for (int rt=0; rt<4; ++rt)
#pragma unroll
    for (int ct=0; ct<4; ++ct) acc[rt][ct] = zf;

  for (int kb2=0; kb2<12; ++kb2){
    __syncthreads();
    const __bf16* g = gsrc + kb2*(2*KBLK_ELEMS) + half + lane*8;
#pragma unroll
    for (int s=0; s<8; ++s)
      gl2lds16(g + s*512, ldsb + half + s*512);
    __syncthreads();
#pragma unroll
    for (int ks=0; ks<2; ++ks){
      int o = ks*KBLK_ELEMS;
      bf16x8 af[4], bf[4];
#pragma unroll
      for (int rt=0; rt<4; ++rt) af[rt] = *(const bf16x8*)(sA + o + a_off[rt]);
#pragma unroll
      for (int ct=0; ct<4; ++ct) bf[ct] = *(const bf16x8*)(sB + o + b_off[ct]);
#pragma unroll
      for (int rt=0; rt<4; ++rt)
#pragma unroll
        for (int ct=0; ct<4; ++ct)
          acc[rt][ct] = __builtin_amdgcn_mfma_f32_16x16x32_bf16(af[rt], bf[ct], acc[rt][ct], 0,0,0);
    }
  }

  // ---- epilogue ----
  int jbase = bj*128 + wj*64;
  float esqv[4]; bool val[4]; int jcol[4];
#pragma unroll
  for (int ct=0; ct<4; ++ct){
    jcol[ct] = jbase + ct*16 + l16;
    val[ct] = jcol[ct] < N_NODE;
    esqv[ct] = esq[jcol[ct]];
  }

  if (pass == 1){
    bool doStore = (bj < njstore);
    if (doStore){
      // epilogue-lite: convert + store only; moments computed by k_mom streamer
      size_t tBase = ((size_t)bj*NTILE_A + bi)*16384;
#pragma unroll
      for (int rt=0; rt<4; ++rt){
        _Float16 h16[16];
#pragma unroll
        for (int reg=0; reg<4; ++reg){
          int il = wi*64 + rt*16 + quad*4 + reg;
          int i  = bi*128 + il;
          float av = asq[i];
#pragma unroll
          for (int ct=0; ct<4; ++ct){
            float neg = (av + esqv[ct]) - 2.f*acc[rt][ct][reg];
            h16[reg*4+ct] = (_Float16)neg;
          }
        }
        _Float16* dst = neg16 + tBase + ((size_t)(wave*4 + rt))*1024 + lane*16;
        *(half8*)(dst)     = *(half8*)&h16[0];
        *(half8*)(dst + 8) = *(half8*)&h16[8];
      }
    } else {
#pragma unroll
      for (int rt=0; rt<4; ++rt){
#pragma unroll
        for (int reg=0; reg<4; ++reg){
          int il = wi*64 + rt*16 + quad*4 + reg;
          int i  = bi*128 + il;
          int p  = i & (BATCH-1);
          int li = pairs[2*p], ri = pairs[2*p+1];
          float av = asq[i];
          float s=0.f, q=0.f, mn=1e30f;
#pragma unroll
          for (int ct=0; ct<4; ++ct){
            float neg = (av + esqv[ct]) - 2.f*acc[rt][ct][reg];
            s += neg;
            q = fmaf(neg, neg, q);
            bool bad = (jcol[ct]==li) | (jcol[ct]==ri) | (!val[ct]);
            mn = fminf(mn, bad ? 1e30f : neg);
          }
#pragma unroll
          for (int m=1;m<16;m<<=1){
            s += __shfl_xor(s,m,64); q += __shfl_xor(q,m,64);
            mn = fminf(mn, __shfl_xor(mn,m,64));
          }
          if (l16 == 0){
            red[il*2+wj] = s; red[256 + il*2+wj] = q; red[512 + il*2+wj] = mn;
          }
        }
      }
      __syncthreads();
      if (tid < 128){
        int i = bi*128 + tid;
        atomicAdd(rs1+i, red[tid*2] + red[tid*2+1]);
        atomicAdd(rs2+i, red[256 + tid*2] + red[256 + tid*2+1]);
        atomicMinF(rmin+i, fminf(red[512 + tid*2], red[512 + tid*2+1]));
      }
    }
  } else {
#pragma unroll
    for (int rt=0; rt<4; ++rt){
#pragma unroll
      for (int reg=0; reg<4; ++reg){
        int il = wi*64 + rt*16 + quad*4 + reg;
        int i  = bi*128 + il;
        int p  = i & (BATCH-1);
        int li = pairs[2*p], ri = pairs[2*p+1];
        float av = asq[i];
        float C = CC[i], A = AL[i];
        float s = 0.f;
#pragma unroll
        for (int ct=0; ct<4; ++ct){
          float neg = (av + esqv[ct]) - 2.f*acc[rt][ct][reg];
          bool bad = (jcol[ct]==li) | (jcol[ct]==ri) | (!val[ct]);
          s += bad ? 0.f : __expf(fmaf(-A, neg, C));
        }
#pragma unroll
        for (int m=1;m<16;m<<=1) s += __shfl_xor(s,m,64);
        if (l16 == 0) red[il*2+wj] = s;
      }
    }
    __syncthreads();
    if (tid < 128){
      int i = bi*128 + tid;
      atomicAdd(rexp+i, red[tid*2] + red[tid*2+1]);
    }
  }
}

// ---------------- moments streamer over stored fp16 neg ----------------
__global__ __launch_bounds__(256) void k_mom(
    const _Float16* __restrict__ neg16, const int* __restrict__ pairs,
    float* __restrict__ rs1, float* __restrict__ rs2, float* __restrict__ rmin)
{
  __shared__ float red[768];
  int tid = threadIdx.x;
  int wave = tid>>6, lane = tid&63, quad = lane>>4, l16 = lane&15;
  int bi = blockIdx.x, bj = blockIdx.y;
  int wi = wave>>1, wj = wave&1;
  int jbase = bj*128 + wj*64;
  bool val[4]; int jcol[4];
#pragma unroll
  for (int ct=0; ct<4; ++ct){
    jcol[ct] = jbase + ct*16 + l16;
    val[ct] = jcol[ct] < N_NODE;
  }
  size_t tBase = ((size_t)bj*NTILE_A + bi)*16384;
#pragma unroll
  for (int rt=0; rt<4; ++rt){
    const _Float16* src = neg16 + tBase + ((size_t)(wave*4 + rt))*1024 + lane*16;
    half8 v0 = *(const half8*)(src);
    half8 v1 = *(const half8*)(src + 8);
    _Float16 h16[16];
    *(half8*)&h16[0] = v0; *(half8*)&h16[8] = v1;
#pragma unroll
    for (int reg=0; reg<4; ++reg){
      int il = wi*64 + rt*16 + quad*4 + reg;
      int i  = bi*128 + il;
      int p  = i & (BATCH-1);
      int li = pairs[2*p], ri = pairs[2*p+1];
      float s=0.f, q=0.f, mn=1e30f;
#pragma unroll
      for (int ct=0; ct<4; ++ct){
        float neg = (float)h16[reg*4+ct];
        s += neg;
        q = fmaf(neg, neg, q);
        bool bad = (jcol[ct]==li) | (jcol[ct]==ri) | (!val[ct]);
        mn = fminf(mn, bad ? 1e30f : neg);
      }
#pragma unroll
      for (int m=1;m<16;m<<=1){
        s += __shfl_xor(s,m,64); q += __shfl_xor(q,m,64);
        mn = fminf(mn, __shfl_xor(mn,m,64));
      }
      if (l16 == 0){
        red[il*2+wj] = s; red[256 + il*2+wj] = q; red[512 + il*2+wj] = mn;
      }
    }
  }
  __syncthreads();
  if (tid < 128){
    int i = bi*128 + tid;
    atomicAdd(rs1+i, red[tid*2] + red[tid*2+1]);
    atomicAdd(rs2+i, red[256 + tid*2] + red[256 + tid*2+1]);
    atomicMinF(rmin+i, fminf(red[512 + tid*2], red[512 + tid*2+1]));
  }
}

// ---------------- streaming pass 2 (exp) over stored fp16 neg ----------------
__global__ __launch_bounds__(256) void k_p2s(
    const _Float16* __restrict__ neg16, const float* __restrict__ CC, const float* __restrict__ AL,
    const int* __restrict__ pairs, float* __restrict__ rexp)
{
  __shared__ float red[256];
  int tid = threadIdx.x;
  int wave = tid>>6, lane = tid&63, quad = lane>>4, l16 = lane&15;
  int bi = blockIdx.x, bj = blockIdx.y;
  int wi = wave>>1, wj = wave&1;
  int jbase = bj*128 + wj*64;
  bool val[4]; int jcol[4];
#pragma unroll
  for (int ct=0; ct<4; ++ct){
    jcol[ct] = jbase + ct*16 + l16;
    val[ct] = jcol[ct] < N_NODE;
  }
  size_t tBase = ((size_t)bj*NTILE_A + bi)*16384;
#pragma unroll
  for (int rt=0; rt<4; ++rt){
    const _Float16* src = neg16 + tBase + ((size_t)(wave*4 + rt))*1024 + lane*16;
    half8 v0 = *(const half8*)(src);
    half8 v1 = *(const half8*)(src + 8);
    _Float16 h16[16];
    *(half8*)&h16[0] = v0; *(half8*)&h16[8] = v1;
#pragma unroll
    for (int reg=0; reg<4; ++reg){
      int il = wi*64 + rt*16 + quad*4 + reg;
      int i  = bi*128 + il;
      int p  = i & (BATCH-1);
      int li = pairs[2*p], ri = pairs[2*p+1];
      float C = CC[i], A = AL[i];
      float s = 0.f;
#pragma unroll
      for (int ct=0; ct<4; ++ct){
        float neg = (float)h16[reg*4+ct];
        bool bad = (jcol[ct]==li) | (jcol[ct]==ri) | (!val[ct]);
        s += bad ? 0.f : __expf(fmaf(-A, neg, C));
      }
#pragma unroll
      for (int m=1;m<16;m<<=1) s += __shfl_xor(s,m,64);
      if (l16 == 0) red[il*2+wj] = s;
    }
  }
  __syncthreads();
  if (tid < 128){
    int i = bi*128 + tid;
    atomicAdd(rexp+i, red[tid*2] + red[tid*2+1]);
  }
}

// ---------------- per-row special-column dots ----------------
__global__ __launch_bounds__(256) void k_corr(
    const int* __restrict__ pairs, const __bf16* __restrict__ Ap, const __bf16* __restrict__ Ep,
    const float* __restrict__ asq, const float* __restrict__ esq,
    float* __restrict__ negl, float* __restrict__ negr)
{
  int wave = threadIdx.x>>6, lane = threadIdx.x&63;
  int i = blockIdx.x*4 + wave;
  if (i >= NROWA) return;
  int p = i & (BATCH-1);
  int li = pairs[2*p], ri = pairs[2*p+1];
  const __bf16* Ar = Ap + (size_t)(i>>7)*TILE_ELEMS;  int ra = i&127;
  const __bf16* E1 = Ep + (size_t)(li>>7)*TILE_ELEMS; int r1 = li&127;
  const __bf16* E2 = Ep + (size_t)(ri>>7)*TILE_ELEMS; int r2 = ri&127;
  float d1=0.f, d2=0.f;
  for (int c=lane; c<96; c+=64){
    int kb = c>>2, q = c&3;
    bf16x8 a  = *(const bf16x8*)(Ar + kb*KBLK_ELEMS + swz_off(ra, q));
    bf16x8 e1 = *(const bf16x8*)(E1 + kb*KBLK_ELEMS + swz_off(r1, q));
    bf16x8 e2 = *(const bf16x8*)(E2 + kb*KBLK_ELEMS + swz_off(r2, q));
#pragma unroll
    for (int e=0;e<8;e++){
      d1 = fmaf((float)a[e], (float)e1[e], d1);
      d2 = fmaf((float)a[e], (float)e2[e], d2);
    }
  }
  d1 = waveSum(d1); d2 = waveSum(d2);
  if (lane==0){
    float av = asq[i];
    negl[i] = av + esq[li] - 2.f*d1;
    negr[i] = av + esq[ri] - 2.f*d2;
  }
}

// ---------------- stats ----------------
__global__ __launch_bounds__(256) void k_stats(
    const float* __restrict__ rs1, const float* __restrict__ rs2, const float* __restrict__ rmin,
    const float* __restrict__ negl, const float* __restrict__ negr,
    const float* __restrict__ asq, const float* __restrict__ pos, const int* __restrict__ pairs,
    float* __restrict__ MM, float* __restrict__ CC, float* __restrict__ AL, float* __restrict__ rexp)
{
  int i = blockIdx.x*256 + threadIdx.x;
  if (i >= NROWA) return;
  int p = i & (BATCH-1);
  int li = pairs[2*p], ri = pairs[2*p+1];
  float K = pos[p] + GAMMA_C;
  float av = asq[i];
  float S1 = rs1[i] - (float)PADN*av;
  float S2 = rs2[i] - (float)PADN*av*av;
  float nl = negl[i], nr = negr[i];
  float Sx, Sxx, mx;
  const float invN = 1.f/(float)N_NODE;
  if (li != ri){
    Sx  = -(S1 - nl - nr) - 2.f*K;
    Sxx = (S2 - nl*nl - nr*nr) + 2.f*K*K;
    mx  = fmaxf(K - rmin[i], 0.f);
    float mu = K + Sx*invN;
    float m2 = Sx*invN;
    float var = Sxx*invN - m2*m2;
    float sd = sqrtf(fmaxf(var, 1e-30f));
    float M = LAMB_C*(mx-mu)/sd + TAU_C;
    MM[i] = M; CC[i] = LAMB_C*(K-mu)/sd + TAU_C - M; AL[i] = LAMB_C/sd;
    rexp[i] = 2.f*__expf(LAMB_C*(0.f-mu)/sd + TAU_C - M);
  } else {
    float lossm = nl - K;
    float x = lossm - K;
    Sx  = -(S1 - nl) + x;
    Sxx = (S2 - nl*nl) + x*x;
    mx  = fmaxf(K - rmin[i], lossm);
    float mu = K + Sx*invN;
    float m2 = Sx*invN;
    float var = Sxx*invN - m2*m2;
    float sd = sqrtf(fmaxf(var, 1e-30f));
    float M = LAMB_C*(mx-mu)/sd + TAU_C;
    MM[i] = M; CC[i] = LAMB_C*(K-mu)/sd + TAU_C - M; AL[i] = LAMB_C/sd;
    rexp[i] = __expf(LAMB_C*(lossm-mu)/sd + TAU_C - M);
  }
}

__global__ __launch_bounds__(256) void k_final(const float* __restrict__ mm, const float* __restrict__ rexp, float* __restrict__ out){
  __shared__ float red[256];
  float s = 0.f;
  for (int i=threadIdx.x; i<NROWA; i+=256) s += mm[i] + logf(rexp[i]);
  red[threadIdx.x] = s; __syncthreads();
  for (int st=128; st>0; st>>=1){ if (threadIdx.x<st) red[threadIdx.x]+=red[threadIdx.x+st]; __syncthreads(); }
  if (threadIdx.x==0) out[0] = red[0]*(1.f/BATCH);
}

extern "C" void kernel_launch(void* const* d_in, const int* in_sizes, int n_in,
                              void* d_out, int out_size, void* d_ws, size_t ws_size,
                              hipStream_t stream) {
  const int*   pairs   = (const int*)d_in[0];
  const int*   ent_adj = (const int*)d_in[1];
  const int*   rel_adj = (const int*)d_in[2];
  const int*   adj     = (const int*)d_in[3];
  const int*   r_index = (const int*)d_in[4];
  const float* r_val   = (const float*)d_in[5];
  const float* ent_emb = (const float*)d_in[7];
  const float* rel_emb = (const float*)d_in[8];
  const float* attn_e  = (const float*)d_in[9];
  const float* attn_r  = (const float*)d_in[10];

  char* base = (char*)d_ws;
  size_t off = 0;
  auto take = [&](size_t bytes)->char*{
    char* p = base + off;
    off = (off + bytes + 511) & ~(size_t)511;
    return p;
  };
  // persistent GEMM-phase region (~53.5 MB)
  __bf16* EP    = (__bf16*)take((size_t)NTILE_E*TILE_ELEMS*2);
  __bf16* AP    = (__bf16*)take((size_t)NTILE_A*TILE_ELEMS*2);
  float*  ESQ   = (float*)take((size_t)EPAD*4);
  float*  ASQ   = (float*)take((size_t)NROWA*4);
  float*  POS   = (float*)take((size_t)BATCH*4);
  float*  RS1   = (float*)take((size_t)NROWA*4);
  float*  RS2   = (float*)take((size_t)NROWA*4);
  float*  RMIN  = (float*)take((size_t)NROWA*4);
  float*  NEGL  = (float*)take((size_t)NROWA*4);
  float*  NEGR  = (float*)take((size_t)NROWA*4);
  float*  MM    = (float*)take((size_t)NROWA*4);
  float*  CCv   = (float*)take((size_t)NROWA*4);
  float*  ALv   = (float*)take((size_t)NROWA*4);
  float*  REXP  = (float*)take((size_t)NROWA*4);

  // graph-phase region (dead by GEMM time) — overlapped by NEG16
  size_t offG = off;
  __bf16* OUTB = (__bf16*)take((size_t)N_NODE*OUTD*2);     // 46.1 MB, interleaved layout
  __bf16* TRI  = (__bf16*)take((size_t)N_TRI*DIM*2);       // 51.2 MB
  float*  ATT4 = (float*)take((size_t)4*N_TRI*4);          // 3.2 MB
  int* RP_E  = (int*)take((size_t)(N_NODE+1)*4);
  int* RP_R  = (int*)take((size_t)(N_NODE+1)*4);
  int* RP_A  = (int*)take((size_t)(N_NODE+1)*4);
  int* IDX_E = (int*)take((size_t)N_TRI*4);
  int* IDX_R = (int*)take((size_t)N_TRI*4);
  int* IDX_A = (int*)take((size_t)N_TRI*4);
  int* CNT6  = (int*)take((size_t)6*N_NODE*4);
  int* CNT_E = CNT6,            *CNT_R = CNT6 + N_NODE,   *CNT_A = CNT6 + 2*N_NODE;
  int* CUR_E = CNT6 + 3*N_NODE, *CUR_R = CNT6 + 4*N_NODE, *CUR_A = CNT6 + 5*N_NODE;

  // NEG16 overlays the graph region; njstore j-tile-columns fit (1 MB per bj)
  _Float16* NEG16 = (_Float16*)(base + offG);
  long perBj = (long)NTILE_A * 16384 * 2;   // 1 MiB
  long njs = (ws_size > offG) ? (long)((ws_size - offG) / perBj) : 0;
  if (njs > NTILE_E) njs = NTILE_E;
  int njstore = (int)njs;
  int rem = NTILE_E - njstore;

  const int* cols = adj + N_TRI;

  // ---- init ----
  k_fill<<<192,256,0,stream>>>((float*)CNT6, (long)6*N_NODE, 0.f);

  // ---- CSR builds ----
  k_hist<<<782,256,0,stream>>>(ent_adj, CNT_E);
  k_hist<<<782,256,0,stream>>>(rel_adj, CNT_R);
  k_hist<<<782,256,0,stream>>>(adj,     CNT_A);
  k_scan3<<<3,256,0,stream>>>(CNT_E, RP_E, CNT_R, RP_R, CNT_A, RP_A, N_NODE);
  k_place<<<782,256,0,stream>>>(ent_adj, ent_adj+N_TRI, RP_E, CUR_E, IDX_E, 1);
  k_place<<<782,256,0,stream>>>(rel_adj, rel_adj+N_TRI, RP_R, CUR_R, IDX_R, 1);
  k_place<<<782,256,0,stream>>>(adj,     (const int*)0, RP_A, CUR_A, IDX_A, 0);

  // ---- feature pipeline (interleaved bf16 features) ----
  k_feat0<<<7500,256,0,stream>>>(RP_E, IDX_E, RP_R, IDX_R, ent_emb, rel_emb, OUTB);
  k_trinorm<<<50000,256,0,stream>>>(r_index+N_TRI, r_val, rel_emb, TRI, attn_e, attn_r, ATT4);
  k_gat<<<7500,256,0,stream>>>(RP_A, IDX_A, cols, TRI,
                               ATT4 + 0*N_TRI, ATT4 + 2*N_TRI, OUTB, 0, 256);
  k_gat<<<7500,256,0,stream>>>(RP_A, IDX_A, cols, TRI,
                               ATT4 + 1*N_TRI, ATT4 + 3*N_TRI, OUTB, 256, 512);

  // ---- loss prep ----
  k_packE<<<7520,256,0,stream>>>(OUTB, EP, ESQ);
  k_packA<<<512,256,0,stream>>>(pairs, EP, OUTB, ESQ, AP, ASQ, POS);
  k_fill<<<16,256,0,stream>>>(RS1, (long)NROWA, 0.f);
  k_fill<<<16,256,0,stream>>>(RS2, (long)NROWA, 0.f);
  k_fill<<<16,256,0,stream>>>(RMIN,(long)NROWA, 1e30f);

  // ---- pass 1: GEMM (epilogue-lite for stored tiles) ----
  dim3 gg(NTILE_A, NTILE_E, 1);
  k_gemm<<<gg,256,0,stream>>>(AP, EP, ASQ, ESQ, POS, pairs,
                              RS1, RS2, RMIN, CCv, ALv, REXP, NEG16, njstore, 0, 1);
  // ---- moments from stored tiles ----
  if (njstore > 0){
    dim3 gm(NTILE_A, njstore, 1);
    k_mom<<<gm,256,0,stream>>>(NEG16, pairs, RS1, RS2, RMIN);
  }
  k_corr<<<1024,256,0,stream>>>(pairs, AP, EP, ASQ, ESQ, NEGL, NEGR);
  k_stats<<<16,256,0,stream>>>(RS1, RS2, RMIN, NEGL, NEGR, ASQ, POS, pairs,
                               MM, CCv, ALv, REXP);

  // ---- pass 2: streamed exp over stored tiles + recompute for the rest ----
  if (njstore > 0){
    dim3 gs(NTILE_A, njstore, 1);
    k_p2s<<<gs,256,0,stream>>>(NEG16, CCv, ALv, pairs, REXP);
  }
  if (rem > 0){
    dim3 gr(NTILE_A, rem, 1);
    k_gemm<<<gr,256,0,stream>>>(AP, EP, ASQ, ESQ, POS, pairs,
                                RS1, RS2, RMIN, CCv, ALv, REXP, NEG16, njstore, njstore, 2);
  }
  k_final<<<1,256,0,stream>>>(MM, REXP, (float*)d_out);
}

// Round 12
// 866.629 us; speedup vs baseline: 1.4282x; 1.0640x over previous
//
#include <hip/hip_runtime.h>
#include <hip/hip_bf16.h>
#include <math.h>

#define N_NODE 30000
#define N_TRI  200000
#define DIM    128
#define OUTD   768
#define BATCH  2048
#define NROWA  4096
#define EPAD   30080   // 235*128
#define PADN   80      // EPAD - N_NODE
#define NTILE_E 235
#define NTILE_A 32
#define NCHB   16      // bi-tiles per loss chunk (2 chunks)
#define TILE_ELEMS (128*OUTD)
#define KBLK_ELEMS (128*32)
#define GAMMA_C 3.0f
#define LAMB_C  30.0f
#define TAU_C   10.0f

typedef __attribute__((ext_vector_type(8)))  __bf16 bf16x8;
typedef __attribute__((ext_vector_type(4)))  __bf16 bf16x4;
typedef __attribute__((ext_vector_type(2)))  __bf16 bf16x2;
typedef __attribute__((ext_vector_type(8)))  _Float16 half8;
typedef __attribute__((ext_vector_type(4)))  float f32x4;

__device__ __forceinline__ float waveSum(float v){
#pragma unroll
  for (int m=1;m<64;m<<=1) v += __shfl_xor(v, m, 64);
  return v;
}

__device__ __forceinline__ void atomicMinF(float* a, float v){
  if (v >= 0.f) atomicMin((int*)a, __float_as_int(v));
  else          atomicMax((unsigned int*)a, __float_as_uint(v));
}

__device__ __forceinline__ void gl2lds16(const void* g, void* l){
  __builtin_amdgcn_global_load_lds(
      (const __attribute__((address_space(1))) char*)g,
      (__attribute__((address_space(3))) char*)l, 16, 0, 0);
}

__device__ __forceinline__ int swz_off(int r, int q){
  return r*32 + ((q ^ ((r>>1)&3))<<3);
}

// ---------------- fill ----------------
__global__ void k_fill(float* __restrict__ p, long n, float v){
  long i = (long)blockIdx.x*blockDim.x + threadIdx.x;
  long st = (long)gridDim.x*blockDim.x;
  for (; i<n; i+=st) p[i]=v;
}

// ---------------- CSR build ----------------
__global__ __launch_bounds__(256) void k_hist(const int* __restrict__ rows, int* __restrict__ cnt){
  int t = blockIdx.x*256 + threadIdx.x;
  if (t < N_TRI) atomicAdd(&cnt[rows[t]], 1);
}

__global__ __launch_bounds__(256) void k_scan3(
    const int* __restrict__ c0, int* __restrict__ r0,
    const int* __restrict__ c1, int* __restrict__ r1,
    const int* __restrict__ c2, int* __restrict__ r2, int n){
  const int* cnt = blockIdx.x==0 ? c0 : (blockIdx.x==1 ? c1 : c2);
  int* rp        = blockIdx.x==0 ? r0 : (blockIdx.x==1 ? r1 : r2);
  __shared__ int buf[256];
  __shared__ int carry;
  if (threadIdx.x==0) carry = 0;
  __syncthreads();
  for (int base=0; base<n; base+=256){
    int i = base + threadIdx.x;
    int v = (i<n) ? cnt[i] : 0;
    buf[threadIdx.x] = v;
    __syncthreads();
    for (int off=1; off<256; off<<=1){
      int t = (threadIdx.x>=off) ? buf[threadIdx.x-off] : 0;
      __syncthreads();
      buf[threadIdx.x] += t;
      __syncthreads();
    }
    if (i<n) rp[i] = carry + buf[threadIdx.x] - v;
    int tot = buf[255];
    __syncthreads();
    if (threadIdx.x==0) carry += tot;
    __syncthreads();
  }
  if (threadIdx.x==0) rp[n] = carry;
}

__global__ __launch_bounds__(256) void k_place(const int* __restrict__ rows, const int* __restrict__ vals,
                        const int* __restrict__ rowptr, int* __restrict__ cur, int* __restrict__ idx, int mode){
  int t = blockIdx.x*256 + threadIdx.x;
  if (t < N_TRI){
    int r = rows[t];
    int p = atomicAdd(&cur[r], 1);
    idx[rowptr[r] + p] = mode ? vals[t] : t;
  }
}

// ---------------- fused sparse means + tanh -> interleaved bf16 features ----------------
__global__ __launch_bounds__(256) void k_feat0(
    const int* __restrict__ rpE, const int* __restrict__ idxE,
    const int* __restrict__ rpR, const int* __restrict__ idxR,
    const float* __restrict__ ent_emb, const float* __restrict__ rel_emb,
    __bf16* __restrict__ outb){
  int wave = threadIdx.x>>6, lane = threadIdx.x&63;
  int i = blockIdx.x*4 + wave;
  if (i >= N_NODE) return;
  int bE = rpE[i], eE = rpE[i+1];
  int bR = rpR[i], eR = rpR[i+1];
  float2 aE = {0.f,0.f}, aR = {0.f,0.f};
  for (int k=bE; k<eE; ++k){
    int c = idxE[k];
    float2 v = *(const float2*)(ent_emb + (size_t)c*DIM + lane*2);
    aE.x += v.x; aE.y += v.y;
  }
  for (int k=bR; k<eR; ++k){
    int c = idxR[k];
    float2 v = *(const float2*)(rel_emb + (size_t)c*DIM + lane*2);
    aR.x += v.x; aR.y += v.y;
  }
  float ie = 1.f/fmaxf((float)(eE-bE), 1.f);
  float ir = 1.f/fmaxf((float)(eR-bR), 1.f);
  bf16x2 oE, oR;
  oE[0] = (__bf16)tanhf(aE.x*ie); oE[1] = (__bf16)tanhf(aE.y*ie);
  oR[0] = (__bf16)tanhf(aR.x*ir); oR[1] = (__bf16)tanhf(aR.y*ir);
  *(bf16x2*)(outb + (size_t)i*OUTD +   0 + lane*2) = oE;   // e0
  *(bf16x2*)(outb + (size_t)i*OUTD + 128 + lane*2) = oR;   // r0
}

// ---------------- tri_rel direct + norm(bf16) + att logits ----------------
__global__ __launch_bounds__(256) void k_trinorm(
    const int* __restrict__ ridx1, const float* __restrict__ rval,
    const float* __restrict__ rel_emb,
    __bf16* __restrict__ tri, const float* __restrict__ attnE,
    const float* __restrict__ attnR, float* __restrict__ att4){
  __shared__ float ak[4][DIM];
  int tid = threadIdx.x;
  for (int idx=tid; idx<4*DIM; idx+=256){
    int k = idx>>7, d = idx&127;
    ak[k][d] = (k<2) ? attnE[k*DIM + d] : attnR[(k-2)*DIM + d];
  }
  __syncthreads();
  int wave = tid>>6, lane = tid&63;
  int t = blockIdx.x*4 + wave;
  if (t >= N_TRI) return;
  int rr = ridx1[t];
  float rv = rval[t];
  float2 v = *(const float2*)(rel_emb + (size_t)rr*DIM + lane*2);
  v.x *= rv; v.y *= rv;
  float ss = waveSum(v.x*v.x + v.y*v.y);
  float inv = 1.f/fmaxf(sqrtf(ss), 1e-12f);
  v.x *= inv; v.y *= inv;
  bf16x2 b; b[0] = (__bf16)v.x; b[1] = (__bf16)v.y;
  *(bf16x2*)(tri + (size_t)t*DIM + lane*2) = b;
#pragma unroll
  for (int k=0;k<4;k++){
    float p = waveSum(v.x*ak[k][lane*2] + v.y*ak[k][lane*2+1]);
    if (lane==0) att4[(size_t)k*N_TRI + t] = p;
  }
}

// ---------------- fused GAT layer: half-wave per branch, 2-edge software pipeline ----------------
__global__ __launch_bounds__(256) void k_gat(
    const int* __restrict__ rowptr, const int* __restrict__ idx, const int* __restrict__ cols,
    const __bf16* __restrict__ tri,
    const float* __restrict__ attE, const float* __restrict__ attR,
    __bf16* __restrict__ outb, int inOff, int outOff){
  int wave = threadIdx.x>>6, lane = threadIdx.x&63;
  int i = blockIdx.x*4 + wave;
  if (i >= N_NODE) return;
  int l31 = lane&31;
  const float* att = (lane < 32) ? attE : attR;
  int beg = rowptr[i], end = rowptr[i+1];
  float a0=0.f, a1=0.f, a2=0.f, a3=0.f;
  if (end > beg){
    float m = -1e30f;
    for (int k=beg+l31; k<end; k+=32) m = fmaxf(m, att[idx[k]]);
#pragma unroll
    for (int mm=1; mm<32; mm<<=1) m = fmaxf(m, __shfl_xor(m, mm, 64));
    float z = 0.f;
    for (int k=beg+l31; k<end; k+=32) z += __expf(att[idx[k]]-m);
#pragma unroll
    for (int mm=1; mm<32; mm<<=1) z += __shfl_xor(z, mm, 64);
    float iz = 1.f/z;
    int t0 = idx[beg];
    int c0 = cols[t0];
    bf16x4 u4 = *(const bf16x4*)(tri + (size_t)t0*DIM + l31*4);
    bf16x4 f4 = *(const bf16x4*)(outb + (size_t)c0*OUTD + inOff + lane*4);
    float atv = att[t0];
    for (int k=beg; k<end; ++k){
      bf16x4 u4c = u4, f4c = f4;
      float atc = atv;
      if (k+1 < end){
        int t1 = idx[k+1];
        int c1 = cols[t1];
        u4 = *(const bf16x4*)(tri + (size_t)t1*DIM + l31*4);
        f4 = *(const bf16x4*)(outb + (size_t)c1*OUTD + inOff + lane*4);
        atv = att[t1];
      }
      float u0=(float)u4c[0], u1=(float)u4c[1], u2=(float)u4c[2], u3=(float)u4c[3];
      float f0=(float)f4c[0], f1=(float)f4c[1], f2=(float)f4c[2], f3=(float)f4c[3];
      float d = f0*u0 + f1*u1 + f2*u2 + f3*u3;
#pragma unroll
      for (int mm=1; mm<32; mm<<=1) d += __shfl_xor(d, mm, 64);
      float w = __expf(atc-m)*iz;
      float d2 = 2.f*d;
      a0 = fmaf(w, fmaf(-d2, u0, f0), a0);
      a1 = fmaf(w, fmaf(-d2, u1, f1), a1);
      a2 = fmaf(w, fmaf(-d2, u2, f2), a2);
      a3 = fmaf(w, fmaf(-d2, u3, f3), a3);
    }
  }
  bf16x4 o;
  o[0] = (__bf16)tanhf(a0); o[1] = (__bf16)tanhf(a1);
  o[2] = (__bf16)tanhf(a2); o[3] = (__bf16)tanhf(a3);
  *(bf16x4*)(outb + (size_t)i*OUTD + outOff + lane*4) = o;
}

// ---------------- pack E (interleaved bf16 -> canonical swizzled tiles + sumsq) ----------------
__global__ __launch_bounds__(256) void k_packE(const __bf16* __restrict__ outb, __bf16* __restrict__ Ep, float* __restrict__ esq){
  const int perm[6] = {0,2,4,1,3,5};
  int wave = threadIdx.x>>6, lane = threadIdx.x&63;
  int j = blockIdx.x*4 + wave;
  if (j >= EPAD) return;
  int jt = j>>7, r = j&127;
  __bf16* tb = Ep + (size_t)jt*TILE_ELEMS;
  float ss = 0.f;
  for (int c=lane; c<96; c+=64){
    int kb = c>>2, q = c&3;
    bf16x8 o;
    if (j < N_NODE){
      int ib = perm[c>>4], wb = c&15;
      o = *(const bf16x8*)(outb + (size_t)j*OUTD + ib*128 + wb*8);
#pragma unroll
      for (int e=0;e<8;e++){ float v = (float)o[e]; ss += v*v; }
    } else {
#pragma unroll
      for (int e=0;e<8;e++) o[e] = (__bf16)0.f;
    }
    *(bf16x8*)(tb + kb*KBLK_ELEMS + swz_off(r, q)) = o;
  }
  ss = waveSum(ss);
  if (lane==0) esq[j] = (j < N_NODE) ? ss : 0.f;
}

__global__ __launch_bounds__(256) void k_packA(const int* __restrict__ pairs, const __bf16* __restrict__ Ep,
    const __bf16* __restrict__ outb, const float* __restrict__ esq,
    __bf16* __restrict__ Ap, float* __restrict__ asq, float* __restrict__ pos){
  int wave = threadIdx.x>>6, lane = threadIdx.x&63;
  int p = blockIdx.x*4 + wave;
  if (p >= BATCH) return;
  int l = pairs[2*p], r = pairs[2*p+1];
  float ss = 0.f;
#pragma unroll
  for (int c=0;c<6;c++){
    int d = c*128 + lane*2;
    bf16x2 a = *(const bf16x2*)(outb + (size_t)l*OUTD + d);
    bf16x2 b = *(const bf16x2*)(outb + (size_t)r*OUTD + d);
    float dx = (float)a[0]-(float)b[0], dy = (float)a[1]-(float)b[1];
    ss += dx*dx + dy*dy;
  }
  ss = waveSum(ss);
  if (lane==0){ pos[p] = ss; asq[p] = esq[l]; asq[p+BATCH] = esq[r]; }
  int lt = l>>7, lr = l&127;
  int rt2 = r>>7, rr = r&127;
  int p0t = p>>7, p0r = p&127;
  int p1t = (p+BATCH)>>7, p1r = (p+BATCH)&127;
  for (int c=lane; c<96; c+=64){
    int kb = c>>2, q = c&3;
    bf16x8 vl = *(const bf16x8*)(Ep + (size_t)lt*TILE_ELEMS + kb*KBLK_ELEMS + swz_off(lr, q));
    *(bf16x8*)(Ap + (size_t)p0t*TILE_ELEMS + kb*KBLK_ELEMS + swz_off(p0r, q)) = vl;
    bf16x8 vr = *(const bf16x8*)(Ep + (size_t)rt2*TILE_ELEMS + kb*KBLK_ELEMS + swz_off(rr, q));
    *(bf16x8*)(Ap + (size_t)p1t*TILE_ELEMS + kb*KBLK_ELEMS + swz_off(p1r, q)) = vr;
  }
}

// ---------------- GEMM (16x16x32, BK=64): epilogue-lite, always stores neg16 ----------------
__global__ __launch_bounds__(256) void k_gemm(
    const __bf16* __restrict__ Ap, const __bf16* __restrict__ Ep,
    const float* __restrict__ asq, const float* __restrict__ esq,
    _Float16* __restrict__ neg16, int biOff)
{
  __shared__ __bf16 sA[2*KBLK_ELEMS];   // 16 KB
  __shared__ __bf16 sB[2*KBLK_ELEMS];   // 16 KB
  int tid = threadIdx.x;

  int wave = tid>>6, lane = tid&63, quad = lane>>4, l16 = lane&15;
  int biL = blockIdx.x, bj = blockIdx.y;
  int bi = biOff + biL;
  int wi = wave>>1, wj = wave&1;

  const __bf16* Asrc = Ap + (size_t)bi*TILE_ELEMS;
  const __bf16* Bsrc = Ep + (size_t)bj*TILE_ELEMS;

  int a_off[4], b_off[4];
#pragma unroll
  for (int rt=0; rt<4; ++rt){ int row = wi*64 + rt*16 + l16; a_off[rt] = swz_off(row, quad); }
#pragma unroll
  for (int ct=0; ct<4; ++ct){ int row = wj*64 + ct*16 + l16; b_off[ct] = swz_off(row, quad); }

  const __bf16* gsrc = (wave<2 ? Asrc : Bsrc);
  __bf16* ldsb = (wave<2 ? sA : sB);
  int half = (wave&1)*KBLK_ELEMS;

  const f32x4 zf = {0.f,0.f,0.f,0.f};
  f32x4 acc[4][4];
#pragma unroll
  for (int rt=0; rt<4; ++rt)
#pragma unroll
    for (int ct=0; ct<4; ++ct) acc[rt][ct] = zf;

  for (int kb2=0; kb2<12; ++kb2){
    __syncthreads();
    const __bf16* g = gsrc + kb2*(2*KBLK_ELEMS) + half + lane*8;
#pragma unroll
    for (int s=0; s<8; ++s)
      gl2lds16(g + s*512, ldsb + half + s*512);
    __syncthreads();
#pragma unroll
    for (int ks=0; ks<2; ++ks){
      int o = ks*KBLK_ELEMS;
      bf16x8 af[4], bf[4];
#pragma unroll
      for (int rt=0; rt<4; ++rt) af[rt] = *(const bf16x8*)(sA + o + a_off[rt]);
#pragma unroll
      for (int ct=0; ct<4; ++ct) bf[ct] = *(const bf16x8*)(sB + o + b_off[ct]);
#pragma unroll
      for (int rt=0; rt<4; ++rt)
#pragma unroll
        for (int ct=0; ct<4; ++ct)
          acc[rt][ct] = __builtin_amdgcn_mfma_f32_16x16x32_bf16(af[rt], bf[ct], acc[rt][ct], 0,0,0);
    }
  }

  // ---- epilogue-lite: convert + coalesced store ----
  int jbase = bj*128 + wj*64;
  float esqv[4];
#pragma unroll
  for (int ct=0; ct<4; ++ct) esqv[ct] = esq[jbase + ct*16 + l16];

  size_t tBase = ((size_t)bj*NCHB + biL)*16384;
#pragma unroll
  for (int rt=0; rt<4; ++rt){
    _Float16 h16[16];
#pragma unroll
    for (int reg=0; reg<4; ++reg){
      int il = wi*64 + rt*16 + quad*4 + reg;
      int i  = bi*128 + il;
      float av = asq[i];
#pragma unroll
      for (int ct=0; ct<4; ++ct){
        float neg = (av + esqv[ct]) - 2.f*acc[rt][ct][reg];
        h16[reg*4+ct] = (_Float16)neg;
      }
    }
    _Float16* dst = neg16 + tBase + ((size_t)(wave*4 + rt))*1024 + lane*16;
    *(half8*)(dst)     = *(half8*)&h16[0];
    *(half8*)(dst + 8) = *(half8*)&h16[8];
  }
}

// ---------------- moments streamer over stored fp16 neg ----------------
__global__ __launch_bounds__(256) void k_mom(
    const _Float16* __restrict__ neg16, const int* __restrict__ pairs,
    float* __restrict__ rs1, float* __restrict__ rs2, float* __restrict__ rmin, int biOff)
{
  __shared__ float red[768];
  int tid = threadIdx.x;
  int wave = tid>>6, lane = tid&63, quad = lane>>4, l16 = lane&15;
  int biL = blockIdx.x, bj = blockIdx.y;
  int bi = biOff + biL;
  int wi = wave>>1, wj = wave&1;
  int jbase = bj*128 + wj*64;
  bool val[4]; int jcol[4];
#pragma unroll
  for (int ct=0; ct<4; ++ct){
    jcol[ct] = jbase + ct*16 + l16;
    val[ct] = jcol[ct] < N_NODE;
  }
  size_t tBase = ((size_t)bj*NCHB + biL)*16384;
#pragma unroll
  for (int rt=0; rt<4; ++rt){
    const _Float16* src = neg16 + tBase + ((size_t)(wave*4 + rt))*1024 + lane*16;
    half8 v0 = *(const half8*)(src);
    half8 v1 = *(const half8*)(src + 8);
    _Float16 h16[16];
    *(half8*)&h16[0] = v0; *(half8*)&h16[8] = v1;
#pragma unroll
    for (int reg=0; reg<4; ++reg){
      int il = wi*64 + rt*16 + quad*4 + reg;
      int i  = bi*128 + il;
      int p  = i & (BATCH-1);
      int li = pairs[2*p], ri = pairs[2*p+1];
      float s=0.f, q=0.f, mn=1e30f;
#pragma unroll
      for (int ct=0; ct<4; ++ct){
        float neg = (float)h16[reg*4+ct];
        s += neg;
        q = fmaf(neg, neg, q);
        bool bad = (jcol[ct]==li) | (jcol[ct]==ri) | (!val[ct]);
        mn = fminf(mn, bad ? 1e30f : neg);
      }
#pragma unroll
      for (int m=1;m<16;m<<=1){
        s += __shfl_xor(s,m,64); q += __shfl_xor(q,m,64);
        mn = fminf(mn, __shfl_xor(mn,m,64));
      }
      if (l16 == 0){
        red[il*2+wj] = s; red[256 + il*2+wj] = q; red[512 + il*2+wj] = mn;
      }
    }
  }
  __syncthreads();
  if (tid < 128){
    int i = bi*128 + tid;
    atomicAdd(rs1+i, red[tid*2] + red[tid*2+1]);
    atomicAdd(rs2+i, red[256 + tid*2] + red[256 + tid*2+1]);
    atomicMinF(rmin+i, fminf(red[512 + tid*2], red[512 + tid*2+1]));
  }
}

// ---------------- streaming pass 2 (exp) over stored fp16 neg ----------------
__global__ __launch_bounds__(256) void k_p2s(
    const _Float16* __restrict__ neg16, const float* __restrict__ CC, const float* __restrict__ AL,
    const int* __restrict__ pairs, float* __restrict__ rexp, int biOff)
{
  __shared__ float red[256];
  int tid = threadIdx.x;
  int wave = tid>>6, lane = tid&63, quad = lane>>4, l16 = lane&15;
  int biL = blockIdx.x, bj = blockIdx.y;
  int bi = biOff + biL;
  int wi = wave>>1, wj = wave&1;
  int jbase = bj*128 + wj*64;
  bool val[4]; int jcol[4];
#pragma unroll
  for (int ct=0; ct<4; ++ct){
    jcol[ct] = jbase + ct*16 + l16;
    val[ct] = jcol[ct] < N_NODE;
  }
  size_t tBase = ((size_t)bj*NCHB + biL)*16384;
#pragma unroll
  for (int rt=0; rt<4; ++rt){
    const _Float16* src = neg16 + tBase + ((size_t)(wave*4 + rt))*1024 + lane*16;
    half8 v0 = *(const half8*)(src);
    half8 v1 = *(const half8*)(src + 8);
    _Float16 h16[16];
    *(half8*)&h16[0] = v0; *(half8*)&h16[8] = v1;
#pragma unroll
    for (int reg=0; reg<4; ++reg){
      int il = wi*64 + rt*16 + quad*4 + reg;
      int i  = bi*128 + il;
      int p  = i & (BATCH-1);
      int li = pairs[2*p], ri = pairs[2*p+1];
      float C = CC[i], A = AL[i];
      float s = 0.f;
#pragma unroll
      for (int ct=0; ct<4; ++ct){
        float neg = (float)h16[reg*4+ct];
        bool bad = (jcol[ct]==li) | (jcol[ct]==ri) | (!val[ct]);
        s += bad ? 0.f : __expf(fmaf(-A, neg, C));
      }
#pragma unroll
      for (int m=1;m<16;m<<=1) s += __shfl_xor(s,m,64);
      if (l16 == 0) red[il*2+wj] = s;
    }
  }
  __syncthreads();
  if (tid < 128){
    int i = bi*128 + tid;
    atomicAdd(rexp+i, red[tid*2] + red[tid*2+1]);
  }
}

// ---------------- per-row special-column dots ----------------
__global__ __launch_bounds__(256) void k_corr(
    const int* __restrict__ pairs, const __bf16* __restrict__ Ap, const __bf16* __restrict__ Ep,
    const float* __restrict__ asq, const float* __restrict__ esq,
    float* __restrict__ negl, float* __restrict__ negr, int iOff)
{
  int wave = threadIdx.x>>6, lane = threadIdx.x&63;
  int i = iOff + blockIdx.x*4 + wave;
  int p = i & (BATCH-1);
  int li = pairs[2*p], ri = pairs[2*p+1];
  const __bf16* Ar = Ap + (size_t)(i>>7)*TILE_ELEMS;  int ra = i&127;
  const __bf16* E1 = Ep + (size_t)(li>>7)*TILE_ELEMS; int r1 = li&127;
  const __bf16* E2 = Ep + (size_t)(ri>>7)*TILE_ELEMS; int r2 = ri&127;
  float d1=0.f, d2=0.f;
  for (int c=lane; c<96; c+=64){
    int kb = c>>2, q = c&3;
    bf16x8 a  = *(const bf16x8*)(Ar + kb*KBLK_ELEMS + swz_off(ra, q));
    bf16x8 e1 = *(const bf16x8*)(E1 + kb*KBLK_ELEMS + swz_off(r1, q));
    bf16x8 e2 = *(const bf16x8*)(E2 + kb*KBLK_ELEMS + swz_off(r2, q));
#pragma unroll
    for (int e=0;e<8;e++){
      d1 = fmaf((float)a[e], (float)e1[e], d1);
      d2 = fmaf((float)a[e], (float)e2[e], d2);
    }
  }
  d1 = waveSum(d1); d2 = waveSum(d2);
  if (lane==0){
    float av = asq[i];
    negl[i] = av + esq[li] - 2.f*d1;
    negr[i] = av + esq[ri] - 2.f*d2;
  }
}

// ---------------- stats ----------------
__global__ __launch_bounds__(256) void k_stats(
    const float* __restrict__ rs1, const float* __restrict__ rs2, const float* __restrict__ rmin,
    const float* __restrict__ negl, const float* __restrict__ negr,
    const float* __restrict__ asq, const float* __restrict__ pos, const int* __restrict__ pairs,
    float* __restrict__ MM, float* __restrict__ CC, float* __restrict__ AL, float* __restrict__ rexp, int iOff)
{
  int i = iOff + blockIdx.x*256 + threadIdx.x;
  int p = i & (BATCH-1);
  int li = pairs[2*p], ri = pairs[2*p+1];
  float K = pos[p] + GAMMA_C;
  float av = asq[i];
  float S1 = rs1[i] - (float)PADN*av;
  float S2 = rs2[i] - (float)PADN*av*av;
  float nl = negl[i], nr = negr[i];
  float Sx, Sxx, mx;
  const float invN = 1.f/(float)N_NODE;
  if (li != ri){
    Sx  = -(S1 - nl - nr) - 2.f*K;
    Sxx = (S2 - nl*nl - nr*nr) + 2.f*K*K;
    mx  = fmaxf(K - rmin[i], 0.f);
    float mu = K + Sx*invN;
    float m2 = Sx*invN;
    float var = Sxx*invN - m2*m2;
    float sd = sqrtf(fmaxf(var, 1e-30f));
    float M = LAMB_C*(mx-mu)/sd + TAU_C;
    MM[i] = M; CC[i] = LAMB_C*(K-mu)/sd + TAU_C - M; AL[i] = LAMB_C/sd;
    rexp[i] = 2.f*__expf(LAMB_C*(0.f-mu)/sd + TAU_C - M);
  } else {
    float lossm = nl - K;
    float x = lossm - K;
    Sx  = -(S1 - nl) + x;
    Sxx = (S2 - nl*nl) + x*x;
    mx  = fmaxf(K - rmin[i], lossm);
    float mu = K + Sx*invN;
    float m2 = Sx*invN;
    float var = Sxx*invN - m2*m2;
    float sd = sqrtf(fmaxf(var, 1e-30f));
    float M = LAMB_C*(mx-mu)/sd + TAU_C;
    MM[i] = M; CC[i] = LAMB_C*(K-mu)/sd + TAU_C - M; AL[i] = LAMB_C/sd;
    rexp[i] = __expf(LAMB_C*(lossm-mu)/sd + TAU_C - M);
  }
}

__global__ __launch_bounds__(256) void k_final(const float* __restrict__ mm, const float* __restrict__ rexp, float* __restrict__ out){
  __shared__ float red[256];
  float s = 0.f;
  for (int i=threadIdx.x; i<NROWA; i+=256) s += mm[i] + logf(rexp[i]);
  red[threadIdx.x] = s; __syncthreads();
  for (int st=128; st>0; st>>=1){ if (threadIdx.x<st) red[threadIdx.x]+=red[threadIdx.x+st]; __syncthreads(); }
  if (threadIdx.x==0) out[0] = red[0]*(1.f/BATCH);
}

extern "C" void kernel_launch(void* const* d_in, const int* in_sizes, int n_in,
                              void* d_out, int out_size, void* d_ws, size_t ws_size,
                              hipStream_t stream) {
  const int*   pairs   = (const int*)d_in[0];
  const int*   ent_adj = (const int*)d_in[1];
  const int*   rel_adj = (const int*)d_in[2];
  const int*   adj     = (const int*)d_in[3];
  const int*   r_index = (const int*)d_in[4];
  const float* r_val   = (const float*)d_in[5];
  const float* ent_emb = (const float*)d_in[7];
  const float* rel_emb = (const float*)d_in[8];
  const float* attn_e  = (const float*)d_in[9];
  const float* attn_r  = (const float*)d_in[10];

  char* base = (char*)d_ws;
  size_t off = 0;
  auto take = [&](size_t bytes)->char*{
    char* p = base + off;
    off = (off + bytes + 511) & ~(size_t)511;
    return p;
  };
  // persistent GEMM-phase region (~53.5 MB)
  __bf16* EP    = (__bf16*)take((size_t)NTILE_E*TILE_ELEMS*2);
  __bf16* AP    = (__bf16*)take((size_t)NTILE_A*TILE_ELEMS*2);
  float*  ESQ   = (float*)take((size_t)EPAD*4);
  float*  ASQ   = (float*)take((size_t)NROWA*4);
  float*  POS   = (float*)take((size_t)BATCH*4);
  float*  RS1   = (float*)take((size_t)NROWA*4);
  float*  RS2   = (float*)take((size_t)NROWA*4);
  float*  RMIN  = (float*)take((size_t)NROWA*4);
  float*  NEGL  = (float*)take((size_t)NROWA*4);
  float*  NEGR  = (float*)take((size_t)NROWA*4);
  float*  MM    = (float*)take((size_t)NROWA*4);
  float*  CCv   = (float*)take((size_t)NROWA*4);
  float*  ALv   = (float*)take((size_t)NROWA*4);
  float*  REXP  = (float*)take((size_t)NROWA*4);

  // graph-phase region (dead by GEMM time) — overlapped by NEG16 (123 MB per chunk)
  size_t offG = off;
  __bf16* OUTB = (__bf16*)take((size_t)N_NODE*OUTD*2);     // 46.1 MB, interleaved layout
  __bf16* TRI  = (__bf16*)take((size_t)N_TRI*DIM*2);       // 51.2 MB
  float*  ATT4 = (float*)take((size_t)4*N_TRI*4);          // 3.2 MB
  int* RP_E  = (int*)take((size_t)(N_NODE+1)*4);
  int* RP_R  = (int*)take((size_t)(N_NODE+1)*4);
  int* RP_A  = (int*)take((size_t)(N_NODE+1)*4);
  int* IDX_E = (int*)take((size_t)N_TRI*4);
  int* IDX_R = (int*)take((size_t)N_TRI*4);
  int* IDX_A = (int*)take((size_t)N_TRI*4);
  int* CNT6  = (int*)take((size_t)6*N_NODE*4);
  int* CNT_E = CNT6,            *CNT_R = CNT6 + N_NODE,   *CNT_A = CNT6 + 2*N_NODE;
  int* CUR_E = CNT6 + 3*N_NODE, *CUR_R = CNT6 + 4*N_NODE, *CUR_A = CNT6 + 5*N_NODE;

  _Float16* NEG16 = (_Float16*)(base + offG);   // 235*16*16384*2 = 123.2 MB

  const int* cols = adj + N_TRI;

  // ---- init ----
  k_fill<<<192,256,0,stream>>>((float*)CNT6, (long)6*N_NODE, 0.f);

  // ---- CSR builds ----
  k_hist<<<782,256,0,stream>>>(ent_adj, CNT_E);
  k_hist<<<782,256,0,stream>>>(rel_adj, CNT_R);
  k_hist<<<782,256,0,stream>>>(adj,     CNT_A);
  k_scan3<<<3,256,0,stream>>>(CNT_E, RP_E, CNT_R, RP_R, CNT_A, RP_A, N_NODE);
  k_place<<<782,256,0,stream>>>(ent_adj, ent_adj+N_TRI, RP_E, CUR_E, IDX_E, 1);
  k_place<<<782,256,0,stream>>>(rel_adj, rel_adj+N_TRI, RP_R, CUR_R, IDX_R, 1);
  k_place<<<782,256,0,stream>>>(adj,     (const int*)0, RP_A, CUR_A, IDX_A, 0);

  // ---- feature pipeline (interleaved bf16 features) ----
  k_feat0<<<7500,256,0,stream>>>(RP_E, IDX_E, RP_R, IDX_R, ent_emb, rel_emb, OUTB);
  k_trinorm<<<50000,256,0,stream>>>(r_index+N_TRI, r_val, rel_emb, TRI, attn_e, attn_r, ATT4);
  k_gat<<<7500,256,0,stream>>>(RP_A, IDX_A, cols, TRI,
                               ATT4 + 0*N_TRI, ATT4 + 2*N_TRI, OUTB, 0, 256);
  k_gat<<<7500,256,0,stream>>>(RP_A, IDX_A, cols, TRI,
                               ATT4 + 1*N_TRI, ATT4 + 3*N_TRI, OUTB, 256, 512);

  // ---- loss prep ----
  k_packE<<<7520,256,0,stream>>>(OUTB, EP, ESQ);
  k_packA<<<512,256,0,stream>>>(pairs, EP, OUTB, ESQ, AP, ASQ, POS);
  k_fill<<<16,256,0,stream>>>(RS1, (long)NROWA, 0.f);
  k_fill<<<16,256,0,stream>>>(RS2, (long)NROWA, 0.f);
  k_fill<<<16,256,0,stream>>>(RMIN,(long)NROWA, 1e30f);

  // ---- loss phase: 2 row-chunks of 16 bi-tiles; NEG16 L3-resident per chunk ----
  for (int ch=0; ch<NTILE_A/NCHB; ++ch){
    int biOff = ch*NCHB;
    int iOff  = biOff*128;
    dim3 gg(NCHB, NTILE_E, 1);
    k_gemm<<<gg,256,0,stream>>>(AP, EP, ASQ, ESQ, NEG16, biOff);
    k_mom<<<gg,256,0,stream>>>(NEG16, pairs, RS1, RS2, RMIN, biOff);
    k_corr<<<NCHB*128/4,256,0,stream>>>(pairs, AP, EP, ASQ, ESQ, NEGL, NEGR, iOff);
    k_stats<<<NCHB*128/256,256,0,stream>>>(RS1, RS2, RMIN, NEGL, NEGR, ASQ, POS, pairs,
                                           MM, CCv, ALv, REXP, iOff);
    k_p2s<<<gg,256,0,stream>>>(NEG16, CCv, ALv, pairs, REXP, biOff);
  }
  k_final<<<1,256,0,stream>>>(MM, REXP, (float*)d_out);
}

// Round 13
// 759.677 us; speedup vs baseline: 1.6293x; 1.1408x over previous
//
#include <hip/hip_runtime.h>
#include <hip/hip_bf16.h>
#include <math.h>

#define N_NODE 30000
#define N_TRI  200000
#define DIM    128
#define OUTD   768
#define BATCH  2048
#define NROWA  4096
#define EPAD   30080   // 235*128
#define PADN   80      // EPAD - N_NODE
#define NTILE_E 235
#define NTILE_A 32
#define NCHB   16      // bi-tiles per loss chunk (2 chunks)
#define NBLK_SCAN 118  // ceil(30000/256)
#define TILE_ELEMS (128*OUTD)
#define KBLK_ELEMS (128*32)
#define GAMMA_C 3.0f
#define LAMB_C  30.0f
#define TAU_C   10.0f

typedef __attribute__((ext_vector_type(8)))  __bf16 bf16x8;
typedef __attribute__((ext_vector_type(4)))  __bf16 bf16x4;
typedef __attribute__((ext_vector_type(2)))  __bf16 bf16x2;
typedef __attribute__((ext_vector_type(8)))  _Float16 half8;
typedef __attribute__((ext_vector_type(4)))  float f32x4;

__device__ __forceinline__ float waveSum(float v){
#pragma unroll
  for (int m=1;m<64;m<<=1) v += __shfl_xor(v, m, 64);
  return v;
}

__device__ __forceinline__ void atomicMinF(float* a, float v){
  if (v >= 0.f) atomicMin((int*)a, __float_as_int(v));
  else          atomicMax((unsigned int*)a, __float_as_uint(v));
}

__device__ __forceinline__ void gl2lds16(const void* g, void* l){
  __builtin_amdgcn_global_load_lds(
      (const __attribute__((address_space(1))) char*)g,
      (__attribute__((address_space(3))) char*)l, 16, 0, 0);
}

__device__ __forceinline__ int swz_off(int r, int q){
  return r*32 + ((q ^ ((r>>1)&3))<<3);
}

// ---------------- fill ----------------
__global__ void k_fill(float* __restrict__ p, long n, float v){
  long i = (long)blockIdx.x*blockDim.x + threadIdx.x;
  long st = (long)gridDim.x*blockDim.x;
  for (; i<n; i+=st) p[i]=v;
}

// ---------------- CSR build ----------------
__global__ __launch_bounds__(256) void k_hist(const int* __restrict__ rows, int* __restrict__ cnt){
  int t = blockIdx.x*256 + threadIdx.x;
  if (t < N_TRI) atomicAdd(&cnt[rows[t]], 1);
}

// 3-stage parallel exclusive scan (replaces the 134 µs serial k_scan3)
__global__ __launch_bounds__(256) void k_scanA(
    const int* __restrict__ c0, const int* __restrict__ c1, const int* __restrict__ c2,
    int* __restrict__ r0, int* __restrict__ r1, int* __restrict__ r2,
    int* __restrict__ btot, int n){
  const int* cnt = blockIdx.y==0 ? c0 : (blockIdx.y==1 ? c1 : c2);
  int* rp        = blockIdx.y==0 ? r0 : (blockIdx.y==1 ? r1 : r2);
  __shared__ int buf[256];
  int i = blockIdx.x*256 + threadIdx.x;
  int v = (i<n) ? cnt[i] : 0;
  buf[threadIdx.x] = v;
  __syncthreads();
  for (int off=1; off<256; off<<=1){
    int t = (threadIdx.x>=off) ? buf[threadIdx.x-off] : 0;
    __syncthreads();
    buf[threadIdx.x] += t;
    __syncthreads();
  }
  if (i<n) rp[i] = buf[threadIdx.x] - v;   // block-local exclusive
  if (threadIdx.x==255) btot[blockIdx.y*NBLK_SCAN + blockIdx.x] = buf[255];
}

__global__ __launch_bounds__(128) void k_scanB(int* __restrict__ btot,
    int* __restrict__ r0, int* __restrict__ r1, int* __restrict__ r2, int n){
  __shared__ int buf[128];
  int c = blockIdx.x;
  int v = (threadIdx.x < NBLK_SCAN) ? btot[c*NBLK_SCAN + threadIdx.x] : 0;
  buf[threadIdx.x] = v;
  __syncthreads();
  for (int off=1; off<128; off<<=1){
    int t = (threadIdx.x>=off) ? buf[threadIdx.x-off] : 0;
    __syncthreads();
    buf[threadIdx.x] += t;
    __syncthreads();
  }
  if (threadIdx.x < NBLK_SCAN) btot[c*NBLK_SCAN + threadIdx.x] = buf[threadIdx.x] - v;  // exclusive
  if (threadIdx.x == 127){
    int* rp = c==0 ? r0 : (c==1 ? r1 : r2);
    rp[n] = buf[127];
  }
}

__global__ __launch_bounds__(256) void k_scanC(
    int* __restrict__ r0, int* __restrict__ r1, int* __restrict__ r2,
    const int* __restrict__ btot, int n){
  int* rp = blockIdx.y==0 ? r0 : (blockIdx.y==1 ? r1 : r2);
  int i = blockIdx.x*256 + threadIdx.x;
  if (i<n) rp[i] += btot[blockIdx.y*NBLK_SCAN + blockIdx.x];
}

__global__ __launch_bounds__(256) void k_place(const int* __restrict__ rows, const int* __restrict__ vals,
                        const int* __restrict__ rowptr, int* __restrict__ cur, int* __restrict__ idx, int mode){
  int t = blockIdx.x*256 + threadIdx.x;
  if (t < N_TRI){
    int r = rows[t];
    int p = atomicAdd(&cur[r], 1);
    idx[rowptr[r] + p] = mode ? vals[t] : t;
  }
}

// ---------------- fused sparse means + tanh -> interleaved bf16 features ----------------
__global__ __launch_bounds__(256) void k_feat0(
    const int* __restrict__ rpE, const int* __restrict__ idxE,
    const int* __restrict__ rpR, const int* __restrict__ idxR,
    const float* __restrict__ ent_emb, const float* __restrict__ rel_emb,
    __bf16* __restrict__ outb){
  int wave = threadIdx.x>>6, lane = threadIdx.x&63;
  int i = blockIdx.x*4 + wave;
  if (i >= N_NODE) return;
  int bE = rpE[i], eE = rpE[i+1];
  int bR = rpR[i], eR = rpR[i+1];
  float2 aE = {0.f,0.f}, aR = {0.f,0.f};
  for (int k=bE; k<eE; ++k){
    int c = idxE[k];
    float2 v = *(const float2*)(ent_emb + (size_t)c*DIM + lane*2);
    aE.x += v.x; aE.y += v.y;
  }
  for (int k=bR; k<eR; ++k){
    int c = idxR[k];
    float2 v = *(const float2*)(rel_emb + (size_t)c*DIM + lane*2);
    aR.x += v.x; aR.y += v.y;
  }
  float ie = 1.f/fmaxf((float)(eE-bE), 1.f);
  float ir = 1.f/fmaxf((float)(eR-bR), 1.f);
  bf16x2 oE, oR;
  oE[0] = (__bf16)tanhf(aE.x*ie); oE[1] = (__bf16)tanhf(aE.y*ie);
  oR[0] = (__bf16)tanhf(aR.x*ir); oR[1] = (__bf16)tanhf(aR.y*ir);
  *(bf16x2*)(outb + (size_t)i*OUTD +   0 + lane*2) = oE;   // e0
  *(bf16x2*)(outb + (size_t)i*OUTD + 128 + lane*2) = oR;   // r0
}

// ---------------- tri_rel direct + norm(bf16) + att logits ----------------
__global__ __launch_bounds__(256) void k_trinorm(
    const int* __restrict__ ridx1, const float* __restrict__ rval,
    const float* __restrict__ rel_emb,
    __bf16* __restrict__ tri, const float* __restrict__ attnE,
    const float* __restrict__ attnR, float* __restrict__ att4){
  __shared__ float ak[4][DIM];
  int tid = threadIdx.x;
  for (int idx=tid; idx<4*DIM; idx+=256){
    int k = idx>>7, d = idx&127;
    ak[k][d] = (k<2) ? attnE[k*DIM + d] : attnR[(k-2)*DIM + d];
  }
  __syncthreads();
  int wave = tid>>6, lane = tid&63;
  int t = blockIdx.x*4 + wave;
  if (t >= N_TRI) return;
  int rr = ridx1[t];
  float rv = rval[t];
  float2 v = *(const float2*)(rel_emb + (size_t)rr*DIM + lane*2);
  v.x *= rv; v.y *= rv;
  float ss = waveSum(v.x*v.x + v.y*v.y);
  float inv = 1.f/fmaxf(sqrtf(ss), 1e-12f);
  v.x *= inv; v.y *= inv;
  bf16x2 b; b[0] = (__bf16)v.x; b[1] = (__bf16)v.y;
  *(bf16x2*)(tri + (size_t)t*DIM + lane*2) = b;
#pragma unroll
  for (int k=0;k<4;k++){
    float p = waveSum(v.x*ak[k][lane*2] + v.y*ak[k][lane*2+1]);
    if (lane==0) att4[(size_t)k*N_TRI + t] = p;
  }
}

// ---------------- fused GAT layer: half-wave per branch, 2-edge software pipeline ----------------
__global__ __launch_bounds__(256) void k_gat(
    const int* __restrict__ rowptr, const int* __restrict__ idx, const int* __restrict__ cols,
    const __bf16* __restrict__ tri,
    const float* __restrict__ attE, const float* __restrict__ attR,
    __bf16* __restrict__ outb, int inOff, int outOff){
  int wave = threadIdx.x>>6, lane = threadIdx.x&63;
  int i = blockIdx.x*4 + wave;
  if (i >= N_NODE) return;
  int l31 = lane&31;
  const float* att = (lane < 32) ? attE : attR;
  int beg = rowptr[i], end = rowptr[i+1];
  float a0=0.f, a1=0.f, a2=0.f, a3=0.f;
  if (end > beg){
    float m = -1e30f;
    for (int k=beg+l31; k<end; k+=32) m = fmaxf(m, att[idx[k]]);
#pragma unroll
    for (int mm=1; mm<32; mm<<=1) m = fmaxf(m, __shfl_xor(m, mm, 64));
    float z = 0.f;
    for (int k=beg+l31; k<end; k+=32) z += __expf(att[idx[k]]-m);
#pragma unroll
    for (int mm=1; mm<32; mm<<=1) z += __shfl_xor(z, mm, 64);
    float iz = 1.f/z;
    int t0 = idx[beg];
    int c0 = cols[t0];
    bf16x4 u4 = *(const bf16x4*)(tri + (size_t)t0*DIM + l31*4);
    bf16x4 f4 = *(const bf16x4*)(outb + (size_t)c0*OUTD + inOff + lane*4);
    float atv = att[t0];
    for (int k=beg; k<end; ++k){
      bf16x4 u4c = u4, f4c = f4;
      float atc = atv;
      if (k+1 < end){
        int t1 = idx[k+1];
        int c1 = cols[t1];
        u4 = *(const bf16x4*)(tri + (size_t)t1*DIM + l31*4);
        f4 = *(const bf16x4*)(outb + (size_t)c1*OUTD + inOff + lane*4);
        atv = att[t1];
      }
      float u0=(float)u4c[0], u1=(float)u4c[1], u2=(float)u4c[2], u3=(float)u4c[3];
      float f0=(float)f4c[0], f1=(float)f4c[1], f2=(float)f4c[2], f3=(float)f4c[3];
      float d = f0*u0 + f1*u1 + f2*u2 + f3*u3;
#pragma unroll
      for (int mm=1; mm<32; mm<<=1) d += __shfl_xor(d, mm, 64);
      float w = __expf(atc-m)*iz;
      float d2 = 2.f*d;
      a0 = fmaf(w, fmaf(-d2, u0, f0), a0);
      a1 = fmaf(w, fmaf(-d2, u1, f1), a1);
      a2 = fmaf(w, fmaf(-d2, u2, f2), a2);
      a3 = fmaf(w, fmaf(-d2, u3, f3), a3);
    }
  }
  bf16x4 o;
  o[0] = (__bf16)tanhf(a0); o[1] = (__bf16)tanhf(a1);
  o[2] = (__bf16)tanhf(a2); o[3] = (__bf16)tanhf(a3);
  *(bf16x4*)(outb + (size_t)i*OUTD + outOff + lane*4) = o;
}

// ---------------- pack E (interleaved bf16 -> canonical swizzled tiles + sumsq) ----------------
__global__ __launch_bounds__(256) void k_packE(const __bf16* __restrict__ outb, __bf16* __restrict__ Ep, float* __restrict__ esq){
  const int perm[6] = {0,2,4,1,3,5};
  int wave = threadIdx.x>>6, lane = threadIdx.x&63;
  int j = blockIdx.x*4 + wave;
  if (j >= EPAD) return;
  int jt = j>>7, r = j&127;
  __bf16* tb = Ep + (size_t)jt*TILE_ELEMS;
  float ss = 0.f;
  for (int c=lane; c<96; c+=64){
    int kb = c>>2, q = c&3;
    bf16x8 o;
    if (j < N_NODE){
      int ib = perm[c>>4], wb = c&15;
      o = *(const bf16x8*)(outb + (size_t)j*OUTD + ib*128 + wb*8);
#pragma unroll
      for (int e=0;e<8;e++){ float v = (float)o[e]; ss += v*v; }
    } else {
#pragma unroll
      for (int e=0;e<8;e++) o[e] = (__bf16)0.f;
    }
    *(bf16x8*)(tb + kb*KBLK_ELEMS + swz_off(r, q)) = o;
  }
  ss = waveSum(ss);
  if (lane==0) esq[j] = (j < N_NODE) ? ss : 0.f;
}

__global__ __launch_bounds__(256) void k_packA(const int* __restrict__ pairs, const __bf16* __restrict__ Ep,
    const __bf16* __restrict__ outb, const float* __restrict__ esq,
    __bf16* __restrict__ Ap, float* __restrict__ asq, float* __restrict__ pos){
  int wave = threadIdx.x>>6, lane = threadIdx.x&63;
  int p = blockIdx.x*4 + wave;
  if (p >= BATCH) return;
  int l = pairs[2*p], r = pairs[2*p+1];
  float ss = 0.f;
#pragma unroll
  for (int c=0;c<6;c++){
    int d = c*128 + lane*2;
    bf16x2 a = *(const bf16x2*)(outb + (size_t)l*OUTD + d);
    bf16x2 b = *(const bf16x2*)(outb + (size_t)r*OUTD + d);
    float dx = (float)a[0]-(float)b[0], dy = (float)a[1]-(float)b[1];
    ss += dx*dx + dy*dy;
  }
  ss = waveSum(ss);
  if (lane==0){ pos[p] = ss; asq[p] = esq[l]; asq[p+BATCH] = esq[r]; }
  int lt = l>>7, lr = l&127;
  int rt2 = r>>7, rr = r&127;
  int p0t = p>>7, p0r = p&127;
  int p1t = (p+BATCH)>>7, p1r = (p+BATCH)&127;
  for (int c=lane; c<96; c+=64){
    int kb = c>>2, q = c&3;
    bf16x8 vl = *(const bf16x8*)(Ep + (size_t)lt*TILE_ELEMS + kb*KBLK_ELEMS + swz_off(lr, q));
    *(bf16x8*)(Ap + (size_t)p0t*TILE_ELEMS + kb*KBLK_ELEMS + swz_off(p0r, q)) = vl;
    bf16x8 vr = *(const bf16x8*)(Ep + (size_t)rt2*TILE_ELEMS + kb*KBLK_ELEMS + swz_off(rr, q));
    *(bf16x8*)(Ap + (size_t)p1t*TILE_ELEMS + kb*KBLK_ELEMS + swz_off(p1r, q)) = vr;
  }
}

// ---------------- GEMM (16x16x32, BK=64): epilogue-lite, always stores neg16 ----------------
__global__ __launch_bounds__(256) void k_gemm(
    const __bf16* __restrict__ Ap, const __bf16* __restrict__ Ep,
    const float* __restrict__ asq, const float* __restrict__ esq,
    _Float16* __restrict__ neg16, int biOff)
{
  __shared__ __bf16 sA[2*KBLK_ELEMS];   // 16 KB
  __shared__ __bf16 sB[2*KBLK_ELEMS];   // 16 KB
  int tid = threadIdx.x;

  int wave = tid>>6, lane = tid&63, quad = lane>>4, l16 = lane&15;
  int biL = blockIdx.x, bj = blockIdx.y;
  int bi = biOff + biL;
  int wi = wave>>1, wj = wave&1;

  const __bf16* Asrc = Ap + (size_t)bi*TILE_ELEMS;
  const __bf16* Bsrc = Ep + (size_t)bj*TILE_ELEMS;

  int a_off[4], b_off[4];
#pragma unroll
  for (int rt=0; rt<4; ++rt){ int row = wi*64 + rt*16 + l16; a_off[rt] = swz_off(row, quad); }
#pragma unroll
  for (int ct=0; ct<4; ++ct){ int row = wj*64 + ct*16 + l16; b_off[ct] = swz_off(row, quad); }

  const __bf16* gsrc = (wave<2 ? Asrc : Bsrc);
  __bf16* ldsb = (wave<2 ? sA : sB);
  int half = (wave&1)*KBLK_ELEMS;

  const f32x4 zf = {0.f,0.f,0.f,0.f};
  f32x4 acc[4][4];
#pragma unroll
  for (int rt=0; rt<4; ++rt)
#pragma unroll
    for (int ct=0; ct<4; ++ct) acc[rt][ct] = zf;

  for (int kb2=0; kb2<12; ++kb2){
    __syncthreads();
    const __bf16* g = gsrc + kb2*(2*KBLK_ELEMS) + half + lane*8;
#pragma unroll
    for (int s=0; s<8; ++s)
      gl2lds16(g + s*512, ldsb + half + s*512);
    __syncthreads();
#pragma unroll
    for (int ks=0; ks<2; ++ks){
      int o = ks*KBLK_ELEMS;
      bf16x8 af[4], bf[4];
#pragma unroll
      for (int rt=0; rt<4; ++rt) af[rt] = *(const bf16x8*)(sA + o + a_off[rt]);
#pragma unroll
      for (int ct=0; ct<4; ++ct) bf[ct] = *(const bf16x8*)(sB + o + b_off[ct]);
#pragma unroll
      for (int rt=0; rt<4; ++rt)
#pragma unroll
        for (int ct=0; ct<4; ++ct)
          acc[rt][ct] = __builtin_amdgcn_mfma_f32_16x16x32_bf16(af[rt], bf[ct], acc[rt][ct], 0,0,0);
    }
  }

  // ---- epilogue-lite: convert + coalesced store ----
  int jbase = bj*128 + wj*64;
  float esqv[4];
#pragma unroll
  for (int ct=0; ct<4; ++ct) esqv[ct] = esq[jbase + ct*16 + l16];

  size_t tBase = ((size_t)bj*NCHB + biL)*16384;
#pragma unroll
  for (int rt=0; rt<4; ++rt){
    _Float16 h16[16];
#pragma unroll
    for (int reg=0; reg<4; ++reg){
      int il = wi*64 + rt*16 + quad*4 + reg;
      int i  = bi*128 + il;
      float av = asq[i];
#pragma unroll
      for (int ct=0; ct<4; ++ct){
        float neg = (av + esqv[ct]) - 2.f*acc[rt][ct][reg];
        h16[reg*4+ct] = (_Float16)neg;
      }
    }
    _Float16* dst = neg16 + tBase + ((size_t)(wave*4 + rt))*1024 + lane*16;
    *(half8*)(dst)     = *(half8*)&h16[0];
    *(half8*)(dst + 8) = *(half8*)&h16[8];
  }
}

// ---------------- moments streamer over stored fp16 neg ----------------
__global__ __launch_bounds__(256) void k_mom(
    const _Float16* __restrict__ neg16, const int* __restrict__ pairs,
    float* __restrict__ rs1, float* __restrict__ rs2, float* __restrict__ rmin, int biOff)
{
  __shared__ float red[768];
  int tid = threadIdx.x;
  int wave = tid>>6, lane = tid&63, quad = lane>>4, l16 = lane&15;
  int biL = blockIdx.x, bj = blockIdx.y;
  int bi = biOff + biL;
  int wi = wave>>1, wj = wave&1;
  int jbase = bj*128 + wj*64;
  bool val[4]; int jcol[4];
#pragma unroll
  for (int ct=0; ct<4; ++ct){
    jcol[ct] = jbase + ct*16 + l16;
    val[ct] = jcol[ct] < N_NODE;
  }
  size_t tBase = ((size_t)bj*NCHB + biL)*16384;
#pragma unroll
  for (int rt=0; rt<4; ++rt){
    const _Float16* src = neg16 + tBase + ((size_t)(wave*4 + rt))*1024 + lane*16;
    half8 v0 = *(const half8*)(src);
    half8 v1 = *(const half8*)(src + 8);
    _Float16 h16[16];
    *(half8*)&h16[0] = v0; *(half8*)&h16[8] = v1;
#pragma unroll
    for (int reg=0; reg<4; ++reg){
      int il = wi*64 + rt*16 + quad*4 + reg;
      int i  = bi*128 + il;
      int p  = i & (BATCH-1);
      int li = pairs[2*p], ri = pairs[2*p+1];
      float s=0.f, q=0.f, mn=1e30f;
#pragma unroll
      for (int ct=0; ct<4; ++ct){
        float neg = (float)h16[reg*4+ct];
        s += neg;
        q = fmaf(neg, neg, q);
        bool bad = (jcol[ct]==li) | (jcol[ct]==ri) | (!val[ct]);
        mn = fminf(mn, bad ? 1e30f : neg);
      }
#pragma unroll
      for (int m=1;m<16;m<<=1){
        s += __shfl_xor(s,m,64); q += __shfl_xor(q,m,64);
        mn = fminf(mn, __shfl_xor(mn,m,64));
      }
      if (l16 == 0){
        red[il*2+wj] = s; red[256 + il*2+wj] = q; red[512 + il*2+wj] = mn;
      }
    }
  }
  __syncthreads();
  if (tid < 128){
    int i = bi*128 + tid;
    atomicAdd(rs1+i, red[tid*2] + red[tid*2+1]);
    atomicAdd(rs2+i, red[256 + tid*2] + red[256 + tid*2+1]);
    atomicMinF(rmin+i, fminf(red[512 + tid*2], red[512 + tid*2+1]));
  }
}

// ---------------- streaming pass 2 (exp) over stored fp16 neg ----------------
__global__ __launch_bounds__(256) void k_p2s(
    const _Float16* __restrict__ neg16, const float* __restrict__ CC, const float* __restrict__ AL,
    const int* __restrict__ pairs, float* __restrict__ rexp, int biOff)
{
  __shared__ float red[256];
  int tid = threadIdx.x;
  int wave = tid>>6, lane = tid&63, quad = lane>>4, l16 = lane&15;
  int biL = blockIdx.x, bj = blockIdx.y;
  int bi = biOff + biL;
  int wi = wave>>1, wj = wave&1;
  int jbase = bj*128 + wj*64;
  bool val[4]; int jcol[4];
#pragma unroll
  for (int ct=0; ct<4; ++ct){
    jcol[ct] = jbase + ct*16 + l16;
    val[ct] = jcol[ct] < N_NODE;
  }
  size_t tBase = ((size_t)bj*NCHB + biL)*16384;
#pragma unroll
  for (int rt=0; rt<4; ++rt){
    const _Float16* src = neg16 + tBase + ((size_t)(wave*4 + rt))*1024 + lane*16;
    half8 v0 = *(const half8*)(src);
    half8 v1 = *(const half8*)(src + 8);
    _Float16 h16[16];
    *(half8*)&h16[0] = v0; *(half8*)&h16[8] = v1;
#pragma unroll
    for (int reg=0; reg<4; ++reg){
      int il = wi*64 + rt*16 + quad*4 + reg;
      int i  = bi*128 + il;
      int p  = i & (BATCH-1);
      int li = pairs[2*p], ri = pairs[2*p+1];
      float C = CC[i], A = AL[i];
      float s = 0.f;
#pragma unroll
      for (int ct=0; ct<4; ++ct){
        float neg = (float)h16[reg*4+ct];
        bool bad = (jcol[ct]==li) | (jcol[ct]==ri) | (!val[ct]);
        s += bad ? 0.f : __expf(fmaf(-A, neg, C));
      }
#pragma unroll
      for (int m=1;m<16;m<<=1) s += __shfl_xor(s,m,64);
      if (l16 == 0) red[il*2+wj] = s;
    }
  }
  __syncthreads();
  if (tid < 128){
    int i = bi*128 + tid;
    atomicAdd(rexp+i, red[tid*2] + red[tid*2+1]);
  }
}

// ---------------- per-row special-column dots ----------------
__global__ __launch_bounds__(256) void k_corr(
    const int* __restrict__ pairs, const __bf16* __restrict__ Ap, const __bf16* __restrict__ Ep,
    const float* __restrict__ asq, const float* __restrict__ esq,
    float* __restrict__ negl, float* __restrict__ negr, int iOff)
{
  int wave = threadIdx.x>>6, lane = threadIdx.x&63;
  int i = iOff + blockIdx.x*4 + wave;
  int p = i & (BATCH-1);
  int li = pairs[2*p], ri = pairs[2*p+1];
  const __bf16* Ar = Ap + (size_t)(i>>7)*TILE_ELEMS;  int ra = i&127;
  const __bf16* E1 = Ep + (size_t)(li>>7)*TILE_ELEMS; int r1 = li&127;
  const __bf16* E2 = Ep + (size_t)(ri>>7)*TILE_ELEMS; int r2 = ri&127;
  float d1=0.f, d2=0.f;
  for (int c=lane; c<96; c+=64){
    int kb = c>>2, q = c&3;
    bf16x8 a  = *(const bf16x8*)(Ar + kb*KBLK_ELEMS + swz_off(ra, q));
    bf16x8 e1 = *(const bf16x8*)(E1 + kb*KBLK_ELEMS + swz_off(r1, q));
    bf16x8 e2 = *(const bf16x8*)(E2 + kb*KBLK_ELEMS + swz_off(r2, q));
#pragma unroll
    for (int e=0;e<8;e++){
      d1 = fmaf((float)a[e], (float)e1[e], d1);
      d2 = fmaf((float)a[e], (float)e2[e], d2);
    }
  }
  d1 = waveSum(d1); d2 = waveSum(d2);
  if (lane==0){
    float av = asq[i];
    negl[i] = av + esq[li] - 2.f*d1;
    negr[i] = av + esq[ri] - 2.f*d2;
  }
}

// ---------------- stats ----------------
__global__ __launch_bounds__(256) void k_stats(
    const float* __restrict__ rs1, const float* __restrict__ rs2, const float* __restrict__ rmin,
    const float* __restrict__ negl, const float* __restrict__ negr,
    const float* __restrict__ asq, const float* __restrict__ pos, const int* __restrict__ pairs,
    float* __restrict__ MM, float* __restrict__ CC, float* __restrict__ AL, float* __restrict__ rexp, int iOff)
{
  int i = iOff + blockIdx.x*256 + threadIdx.x;
  int p = i & (BATCH-1);
  int li = pairs[2*p], ri = pairs[2*p+1];
  float K = pos[p] + GAMMA_C;
  float av = asq[i];
  float S1 = rs1[i] - (float)PADN*av;
  float S2 = rs2[i] - (float)PADN*av*av;
  float nl = negl[i], nr = negr[i];
  float Sx, Sxx, mx;
  const float invN = 1.f/(float)N_NODE;
  if (li != ri){
    Sx  = -(S1 - nl - nr) - 2.f*K;
    Sxx = (S2 - nl*nl - nr*nr) + 2.f*K*K;
    mx  = fmaxf(K - rmin[i], 0.f);
    float mu = K + Sx*invN;
    float m2 = Sx*invN;
    float var = Sxx*invN - m2*m2;
    float sd = sqrtf(fmaxf(var, 1e-30f));
    float M = LAMB_C*(mx-mu)/sd + TAU_C;
    MM[i] = M; CC[i] = LAMB_C*(K-mu)/sd + TAU_C - M; AL[i] = LAMB_C/sd;
    rexp[i] = 2.f*__expf(LAMB_C*(0.f-mu)/sd + TAU_C - M);
  } else {
    float lossm = nl - K;
    float x = lossm - K;
    Sx  = -(S1 - nl) + x;
    Sxx = (S2 - nl*nl) + x*x;
    mx  = fmaxf(K - rmin[i], lossm);
    float mu = K + Sx*invN;
    float m2 = Sx*invN;
    float var = Sxx*invN - m2*m2;
    float sd = sqrtf(fmaxf(var, 1e-30f));
    float M = LAMB_C*(mx-mu)/sd + TAU_C;
    MM[i] = M; CC[i] = LAMB_C*(K-mu)/sd + TAU_C - M; AL[i] = LAMB_C/sd;
    rexp[i] = __expf(LAMB_C*(lossm-mu)/sd + TAU_C - M);
  }
}

__global__ __launch_bounds__(256) void k_final(const float* __restrict__ mm, const float* __restrict__ rexp, float* __restrict__ out){
  __shared__ float red[256];
  float s = 0.f;
  for (int i=threadIdx.x; i<NROWA; i+=256) s += mm[i] + logf(rexp[i]);
  red[threadIdx.x] = s; __syncthreads();
  for (int st=128; st>0; st>>=1){ if (threadIdx.x<st) red[threadIdx.x]+=red[threadIdx.x+st]; __syncthreads(); }
  if (threadIdx.x==0) out[0] = red[0]*(1.f/BATCH);
}

extern "C" void kernel_launch(void* const* d_in, const int* in_sizes, int n_in,
                              void* d_out, int out_size, void* d_ws, size_t ws_size,
                              hipStream_t stream) {
  const int*   pairs   = (const int*)d_in[0];
  const int*   ent_adj = (const int*)d_in[1];
  const int*   rel_adj = (const int*)d_in[2];
  const int*   adj     = (const int*)d_in[3];
  const int*   r_index = (const int*)d_in[4];
  const float* r_val   = (const float*)d_in[5];
  const float* ent_emb = (const float*)d_in[7];
  const float* rel_emb = (const float*)d_in[8];
  const float* attn_e  = (const float*)d_in[9];
  const float* attn_r  = (const float*)d_in[10];

  char* base = (char*)d_ws;
  size_t off = 0;
  auto take = [&](size_t bytes)->char*{
    char* p = base + off;
    off = (off + bytes + 511) & ~(size_t)511;
    return p;
  };
  // persistent GEMM-phase region (~53.5 MB)
  __bf16* EP    = (__bf16*)take((size_t)NTILE_E*TILE_ELEMS*2);
  __bf16* AP    = (__bf16*)take((size_t)NTILE_A*TILE_ELEMS*2);
  float*  ESQ   = (float*)take((size_t)EPAD*4);
  float*  ASQ   = (float*)take((size_t)NROWA*4);
  float*  POS   = (float*)take((size_t)BATCH*4);
  float*  RS1   = (float*)take((size_t)NROWA*4);
  float*  RS2   = (float*)take((size_t)NROWA*4);
  float*  RMIN  = (float*)take((size_t)NROWA*4);
  float*  NEGL  = (float*)take((size_t)NROWA*4);
  float*  NEGR  = (float*)take((size_t)NROWA*4);
  float*  MM    = (float*)take((size_t)NROWA*4);
  float*  CCv   = (float*)take((size_t)NROWA*4);
  float*  ALv   = (float*)take((size_t)NROWA*4);
  float*  REXP  = (float*)take((size_t)NROWA*4);

  // graph-phase region (dead by GEMM time) — overlapped by NEG16 (123 MB per chunk)
  size_t offG = off;
  __bf16* OUTB = (__bf16*)take((size_t)N_NODE*OUTD*2);     // 46.1 MB, interleaved layout
  __bf16* TRI  = (__bf16*)take((size_t)N_TRI*DIM*2);       // 51.2 MB
  float*  ATT4 = (float*)take((size_t)4*N_TRI*4);          // 3.2 MB
  int* RP_E  = (int*)take((size_t)(N_NODE+1)*4);
  int* RP_R  = (int*)take((size_t)(N_NODE+1)*4);
  int* RP_A  = (int*)take((size_t)(N_NODE+1)*4);
  int* IDX_E = (int*)take((size_t)N_TRI*4);
  int* IDX_R = (int*)take((size_t)N_TRI*4);
  int* IDX_A = (int*)take((size_t)N_TRI*4);
  int* CNT6  = (int*)take((size_t)6*N_NODE*4);
  int* BTOT  = (int*)take((size_t)3*NBLK_SCAN*4);
  int* CNT_E = CNT6,            *CNT_R = CNT6 + N_NODE,   *CNT_A = CNT6 + 2*N_NODE;
  int* CUR_E = CNT6 + 3*N_NODE, *CUR_R = CNT6 + 4*N_NODE, *CUR_A = CNT6 + 5*N_NODE;

  _Float16* NEG16 = (_Float16*)(base + offG);   // 235*16*16384*2 = 123.2 MB per chunk

  const int* cols = adj + N_TRI;

  // ---- init ----
  k_fill<<<192,256,0,stream>>>((float*)CNT6, (long)6*N_NODE, 0.f);

  // ---- CSR builds ----
  k_hist<<<782,256,0,stream>>>(ent_adj, CNT_E);
  k_hist<<<782,256,0,stream>>>(rel_adj, CNT_R);
  k_hist<<<782,256,0,stream>>>(adj,     CNT_A);
  dim3 gsA(NBLK_SCAN, 3, 1);
  k_scanA<<<gsA,256,0,stream>>>(CNT_E, CNT_R, CNT_A, RP_E, RP_R, RP_A, BTOT, N_NODE);
  k_scanB<<<3,128,0,stream>>>(BTOT, RP_E, RP_R, RP_A, N_NODE);
  k_scanC<<<gsA,256,0,stream>>>(RP_E, RP_R, RP_A, BTOT, N_NODE);
  k_place<<<782,256,0,stream>>>(ent_adj, ent_adj+N_TRI, RP_E, CUR_E, IDX_E, 1);
  k_place<<<782,256,0,stream>>>(rel_adj, rel_adj+N_TRI, RP_R, CUR_R, IDX_R, 1);
  k_place<<<782,256,0,stream>>>(adj,     (const int*)0, RP_A, CUR_A, IDX_A, 0);

  // ---- feature pipeline (interleaved bf16 features) ----
  k_feat0<<<7500,256,0,stream>>>(RP_E, IDX_E, RP_R, IDX_R, ent_emb, rel_emb, OUTB);
  k_trinorm<<<50000,256,0,stream>>>(r_index+N_TRI, r_val, rel_emb, TRI, attn_e, attn_r, ATT4);
  k_gat<<<7500,256,0,stream>>>(RP_A, IDX_A, cols, TRI,
                               ATT4 + 0*N_TRI, ATT4 + 2*N_TRI, OUTB, 0, 256);
  k_gat<<<7500,256,0,stream>>>(RP_A, IDX_A, cols, TRI,
                               ATT4 + 1*N_TRI, ATT4 + 3*N_TRI, OUTB, 256, 512);

  // ---- loss prep ----
  k_packE<<<7520,256,0,stream>>>(OUTB, EP, ESQ);
  k_packA<<<512,256,0,stream>>>(pairs, EP, OUTB, ESQ, AP, ASQ, POS);
  k_fill<<<16,256,0,stream>>>(RS1, (long)NROWA, 0.f);
  k_fill<<<16,256,0,stream>>>(RS2, (long)NROWA, 0.f);
  k_fill<<<16,256,0,stream>>>(RMIN,(long)NROWA, 1e30f);

  // ---- loss phase: 2 row-chunks of 16 bi-tiles; NEG16 L3-resident per chunk ----
  for (int ch=0; ch<NTILE_A/NCHB; ++ch){
    int biOff = ch*NCHB;
    int iOff  = biOff*128;
    dim3 gg(NCHB, NTILE_E, 1);
    k_gemm<<<gg,256,0,stream>>>(AP, EP, ASQ, ESQ, NEG16, biOff);
    k_mom<<<gg,256,0,stream>>>(NEG16, pairs, RS1, RS2, RMIN, biOff);
    k_corr<<<NCHB*128/4,256,0,stream>>>(pairs, AP, EP, ASQ, ESQ, NEGL, NEGR, iOff);
    k_stats<<<NCHB*128/256,256,0,stream>>>(RS1, RS2, RMIN, NEGL, NEGR, ASQ, POS, pairs,
                                           MM, CCv, ALv, REXP, iOff);
    k_p2s<<<gg,256,0,stream>>>(NEG16, CCv, ALv, pairs, REXP, biOff);
  }
  k_final<<<1,256,0,stream>>>(MM, REXP, (float*)d_out);
}

// Round 14
// 740.554 us; speedup vs baseline: 1.6714x; 1.0258x over previous
//
#include <hip/hip_runtime.h>
#include <hip/hip_bf16.h>
#include <math.h>

#define N_NODE 30000
#define N_TRI  200000
#define DIM    128
#define OUTD   768
#define BATCH  2048
#define NROWA  4096
#define EPAD   30080   // 235*128
#define PADN   80      // EPAD - N_NODE
#define NTILE_E 235
#define NTILE_A 32
#define NCHB   16      // bi-tiles per loss chunk (2 chunks)
#define NBLK_SCAN 118  // ceil(30000/256)
#define TILE_ELEMS (128*OUTD)
#define KBLK_ELEMS (128*32)
#define GAMMA_C 3.0f
#define LAMB_C  30.0f
#define TAU_C   10.0f

typedef __attribute__((ext_vector_type(8)))  __bf16 bf16x8;
typedef __attribute__((ext_vector_type(4)))  __bf16 bf16x4;
typedef __attribute__((ext_vector_type(2)))  __bf16 bf16x2;
typedef __attribute__((ext_vector_type(8)))  _Float16 half8;
typedef __attribute__((ext_vector_type(4)))  float f32x4;

__device__ __forceinline__ float waveSum(float v){
#pragma unroll
  for (int m=1;m<64;m<<=1) v += __shfl_xor(v, m, 64);
  return v;
}
__device__ __forceinline__ float halfSum(float v){
#pragma unroll
  for (int m=1;m<32;m<<=1) v += __shfl_xor(v, m, 64);
  return v;
}

__device__ __forceinline__ void atomicMinF(float* a, float v){
  if (v >= 0.f) atomicMin((int*)a, __float_as_int(v));
  else          atomicMax((unsigned int*)a, __float_as_uint(v));
}

__device__ __forceinline__ void gl2lds16(const void* g, void* l){
  __builtin_amdgcn_global_load_lds(
      (const __attribute__((address_space(1))) char*)g,
      (__attribute__((address_space(3))) char*)l, 16, 0, 0);
}

__device__ __forceinline__ int swz_off(int r, int q){
  return r*32 + ((q ^ ((r>>1)&3))<<3);
}

// ---------------- fill ----------------
__global__ void k_fill(float* __restrict__ p, long n, float v){
  long i = (long)blockIdx.x*blockDim.x + threadIdx.x;
  long st = (long)gridDim.x*blockDim.x;
  for (; i<n; i+=st) p[i]=v;
}

// ---------------- CSR build ----------------
__global__ __launch_bounds__(256) void k_hist(const int* __restrict__ rows, int* __restrict__ cnt){
  int t = blockIdx.x*256 + threadIdx.x;
  if (t < N_TRI) atomicAdd(&cnt[rows[t]], 1);
}

// 3-stage parallel exclusive scan
__global__ __launch_bounds__(256) void k_scanA(
    const int* __restrict__ c0, const int* __restrict__ c1, const int* __restrict__ c2,
    int* __restrict__ r0, int* __restrict__ r1, int* __restrict__ r2,
    int* __restrict__ btot, int n){
  const int* cnt = blockIdx.y==0 ? c0 : (blockIdx.y==1 ? c1 : c2);
  int* rp        = blockIdx.y==0 ? r0 : (blockIdx.y==1 ? r1 : r2);
  __shared__ int buf[256];
  int i = blockIdx.x*256 + threadIdx.x;
  int v = (i<n) ? cnt[i] : 0;
  buf[threadIdx.x] = v;
  __syncthreads();
  for (int off=1; off<256; off<<=1){
    int t = (threadIdx.x>=off) ? buf[threadIdx.x-off] : 0;
    __syncthreads();
    buf[threadIdx.x] += t;
    __syncthreads();
  }
  if (i<n) rp[i] = buf[threadIdx.x] - v;   // block-local exclusive
  if (threadIdx.x==255) btot[blockIdx.y*NBLK_SCAN + blockIdx.x] = buf[255];
}

__global__ __launch_bounds__(128) void k_scanB(int* __restrict__ btot,
    int* __restrict__ r0, int* __restrict__ r1, int* __restrict__ r2, int n){
  __shared__ int buf[128];
  int c = blockIdx.x;
  int v = (threadIdx.x < NBLK_SCAN) ? btot[c*NBLK_SCAN + threadIdx.x] : 0;
  buf[threadIdx.x] = v;
  __syncthreads();
  for (int off=1; off<128; off<<=1){
    int t = (threadIdx.x>=off) ? buf[threadIdx.x-off] : 0;
    __syncthreads();
    buf[threadIdx.x] += t;
    __syncthreads();
  }
  if (threadIdx.x < NBLK_SCAN) btot[c*NBLK_SCAN + threadIdx.x] = buf[threadIdx.x] - v;  // exclusive
  if (threadIdx.x == 127){
    int* rp = c==0 ? r0 : (c==1 ? r1 : r2);
    rp[n] = buf[127];
  }
}

__global__ __launch_bounds__(256) void k_scanC(
    int* __restrict__ r0, int* __restrict__ r1, int* __restrict__ r2,
    const int* __restrict__ btot, int n){
  int* rp = blockIdx.y==0 ? r0 : (blockIdx.y==1 ? r1 : r2);
  int i = blockIdx.x*256 + threadIdx.x;
  if (i<n) rp[i] += btot[blockIdx.y*NBLK_SCAN + blockIdx.x];
}

__global__ __launch_bounds__(256) void k_place(const int* __restrict__ rows, const int* __restrict__ vals,
                        const int* __restrict__ rowptr, int* __restrict__ cur, int* __restrict__ idx, int mode){
  int t = blockIdx.x*256 + threadIdx.x;
  if (t < N_TRI){
    int r = rows[t];
    int p = atomicAdd(&cur[r], 1);
    idx[rowptr[r] + p] = mode ? vals[t] : t;
  }
}

// ---------------- fused sparse means + tanh -> interleaved bf16 features ----------------
__global__ __launch_bounds__(256) void k_feat0(
    const int* __restrict__ rpE, const int* __restrict__ idxE,
    const int* __restrict__ rpR, const int* __restrict__ idxR,
    const float* __restrict__ ent_emb, const float* __restrict__ rel_emb,
    __bf16* __restrict__ outb){
  int wave = threadIdx.x>>6, lane = threadIdx.x&63;
  int i = blockIdx.x*4 + wave;
  if (i >= N_NODE) return;
  int bE = rpE[i], eE = rpE[i+1];
  int bR = rpR[i], eR = rpR[i+1];
  float2 aE = {0.f,0.f}, aR = {0.f,0.f};
  for (int k=bE; k<eE; ++k){
    int c = idxE[k];
    float2 v = *(const float2*)(ent_emb + (size_t)c*DIM + lane*2);
    aE.x += v.x; aE.y += v.y;
  }
  for (int k=bR; k<eR; ++k){
    int c = idxR[k];
    float2 v = *(const float2*)(rel_emb + (size_t)c*DIM + lane*2);
    aR.x += v.x; aR.y += v.y;
  }
  float ie = 1.f/fmaxf((float)(eE-bE), 1.f);
  float ir = 1.f/fmaxf((float)(eR-bR), 1.f);
  bf16x2 oE, oR;
  oE[0] = (__bf16)tanhf(aE.x*ie); oE[1] = (__bf16)tanhf(aE.y*ie);
  oR[0] = (__bf16)tanhf(aR.x*ir); oR[1] = (__bf16)tanhf(aR.y*ir);
  *(bf16x2*)(outb + (size_t)i*OUTD +   0 + lane*2) = oE;   // e0
  *(bf16x2*)(outb + (size_t)i*OUTD + 128 + lane*2) = oR;   // r0
}

// ---------------- tri_rel direct + norm(bf16) + att logits — half-wave per triple ----------------
__global__ __launch_bounds__(256) void k_trinorm(
    const int* __restrict__ ridx1, const float* __restrict__ rval,
    const float* __restrict__ rel_emb,
    __bf16* __restrict__ tri, const float* __restrict__ attnE,
    const float* __restrict__ attnR, float* __restrict__ att4){
  __shared__ float ak[4][DIM];
  int tid = threadIdx.x;
  for (int idx=tid; idx<4*DIM; idx+=256){
    int k = idx>>7, d = idx&127;
    ak[k][d] = (k<2) ? attnE[k*DIM + d] : attnR[(k-2)*DIM + d];
  }
  __syncthreads();
  int half = tid>>5, l31 = tid&31;
  int t = blockIdx.x*8 + half;
  if (t >= N_TRI) return;
  int rr = ridx1[t];
  float rv = rval[t];
  float4 v = *(const float4*)(rel_emb + (size_t)rr*DIM + l31*4);
  v.x *= rv; v.y *= rv; v.z *= rv; v.w *= rv;
  float ss = halfSum(v.x*v.x + v.y*v.y + v.z*v.z + v.w*v.w);
  float inv = 1.f/fmaxf(sqrtf(ss), 1e-12f);
  v.x *= inv; v.y *= inv; v.z *= inv; v.w *= inv;
  bf16x4 b; b[0]=(__bf16)v.x; b[1]=(__bf16)v.y; b[2]=(__bf16)v.z; b[3]=(__bf16)v.w;
  *(bf16x4*)(tri + (size_t)t*DIM + l31*4) = b;
#pragma unroll
  for (int k=0;k<4;k++){
    const float* a = &ak[k][l31*4];
    float p = halfSum(v.x*a[0] + v.y*a[1] + v.z*a[2] + v.w*a[3]);
    if (l31==0) att4[(size_t)k*N_TRI + t] = p;
  }
}

// ---------------- fused GAT layer: single-pass (bounded logits -> no max; unnormalized acc + z) ----------------
// lanes 0-31: e-branch, lanes 32-63: r-branch; 2-edge software pipeline
__global__ __launch_bounds__(256) void k_gat(
    const int* __restrict__ rowptr, const int* __restrict__ idx, const int* __restrict__ cols,
    const __bf16* __restrict__ tri,
    const float* __restrict__ attE, const float* __restrict__ attR,
    __bf16* __restrict__ outb, int inOff, int outOff){
  int wave = threadIdx.x>>6, lane = threadIdx.x&63;
  int i = blockIdx.x*4 + wave;
  if (i >= N_NODE) return;
  int l31 = lane&31;
  const float* att = (lane < 32) ? attE : attR;
  int beg = rowptr[i], end = rowptr[i+1];
  float a0=0.f, a1=0.f, a2=0.f, a3=0.f;
  if (end > beg){
    float z = 0.f;
    int t0 = idx[beg];
    int c0 = cols[t0];
    bf16x4 u4 = *(const bf16x4*)(tri + (size_t)t0*DIM + l31*4);
    bf16x4 f4 = *(const bf16x4*)(outb + (size_t)c0*OUTD + inOff + lane*4);
    float atv = att[t0];
    for (int k=beg; k<end; ++k){
      bf16x4 u4c = u4, f4c = f4;
      float atc = atv;
      if (k+1 < end){
        int t1 = idx[k+1];
        int c1 = cols[t1];
        u4 = *(const bf16x4*)(tri + (size_t)t1*DIM + l31*4);
        f4 = *(const bf16x4*)(outb + (size_t)c1*OUTD + inOff + lane*4);
        atv = att[t1];
      }
      float u0=(float)u4c[0], u1=(float)u4c[1], u2=(float)u4c[2], u3=(float)u4c[3];
      float f0=(float)f4c[0], f1=(float)f4c[1], f2=(float)f4c[2], f3=(float)f4c[3];
      float d = f0*u0 + f1*u1 + f2*u2 + f3*u3;
#pragma unroll
      for (int mm=1; mm<32; mm<<=1) d += __shfl_xor(d, mm, 64);
      float w = __expf(atc);        // |att| <= ~2.5, safe without shift
      z += w;
      float d2 = 2.f*d;
      a0 = fmaf(w, fmaf(-d2, u0, f0), a0);
      a1 = fmaf(w, fmaf(-d2, u1, f1), a1);
      a2 = fmaf(w, fmaf(-d2, u2, f2), a2);
      a3 = fmaf(w, fmaf(-d2, u3, f3), a3);
    }
    float iz = 1.f/z;               // z lane-uniform (serial edge loop)
    a0 *= iz; a1 *= iz; a2 *= iz; a3 *= iz;
  }
  bf16x4 o;
  o[0] = (__bf16)tanhf(a0); o[1] = (__bf16)tanhf(a1);
  o[2] = (__bf16)tanhf(a2); o[3] = (__bf16)tanhf(a3);
  *(bf16x4*)(outb + (size_t)i*OUTD + outOff + lane*4) = o;
}

// ---------------- pack E (interleaved bf16 -> canonical swizzled tiles + sumsq) ----------------
__global__ __launch_bounds__(256) void k_packE(const __bf16* __restrict__ outb, __bf16* __restrict__ Ep, float* __restrict__ esq){
  const int perm[6] = {0,2,4,1,3,5};
  int wave = threadIdx.x>>6, lane = threadIdx.x&63;
  int j = blockIdx.x*4 + wave;
  if (j >= EPAD) return;
  int jt = j>>7, r = j&127;
  __bf16* tb = Ep + (size_t)jt*TILE_ELEMS;
  float ss = 0.f;
  for (int c=lane; c<96; c+=64){
    int kb = c>>2, q = c&3;
    bf16x8 o;
    if (j < N_NODE){
      int ib = perm[c>>4], wb = c&15;
      o = *(const bf16x8*)(outb + (size_t)j*OUTD + ib*128 + wb*8);
#pragma unroll
      for (int e=0;e<8;e++){ float v = (float)o[e]; ss += v*v; }
    } else {
#pragma unroll
      for (int e=0;e<8;e++) o[e] = (__bf16)0.f;
    }
    *(bf16x8*)(tb + kb*KBLK_ELEMS + swz_off(r, q)) = o;
  }
  ss = waveSum(ss);
  if (lane==0) esq[j] = (j < N_NODE) ? ss : 0.f;
}

__global__ __launch_bounds__(256) void k_packA(const int* __restrict__ pairs, const __bf16* __restrict__ Ep,
    const __bf16* __restrict__ outb, const float* __restrict__ esq,
    __bf16* __restrict__ Ap, float* __restrict__ asq, float* __restrict__ pos){
  int wave = threadIdx.x>>6, lane = threadIdx.x&63;
  int p = blockIdx.x*4 + wave;
  if (p >= BATCH) return;
  int l = pairs[2*p], r = pairs[2*p+1];
  float ss = 0.f;
#pragma unroll
  for (int c=0;c<6;c++){
    int d = c*128 + lane*2;
    bf16x2 a = *(const bf16x2*)(outb + (size_t)l*OUTD + d);
    bf16x2 b = *(const bf16x2*)(outb + (size_t)r*OUTD + d);
    float dx = (float)a[0]-(float)b[0], dy = (float)a[1]-(float)b[1];
    ss += dx*dx + dy*dy;
  }
  ss = waveSum(ss);
  if (lane==0){ pos[p] = ss; asq[p] = esq[l]; asq[p+BATCH] = esq[r]; }
  int lt = l>>7, lr = l&127;
  int rt2 = r>>7, rr = r&127;
  int p0t = p>>7, p0r = p&127;
  int p1t = (p+BATCH)>>7, p1r = (p+BATCH)&127;
  for (int c=lane; c<96; c+=64){
    int kb = c>>2, q = c&3;
    bf16x8 vl = *(const bf16x8*)(Ep + (size_t)lt*TILE_ELEMS + kb*KBLK_ELEMS + swz_off(lr, q));
    *(bf16x8*)(Ap + (size_t)p0t*TILE_ELEMS + kb*KBLK_ELEMS + swz_off(p0r, q)) = vl;
    bf16x8 vr = *(const bf16x8*)(Ep + (size_t)rt2*TILE_ELEMS + kb*KBLK_ELEMS + swz_off(rr, q));
    *(bf16x8*)(Ap + (size_t)p1t*TILE_ELEMS + kb*KBLK_ELEMS + swz_off(p1r, q)) = vr;
  }
}

// ---------------- GEMM (16x16x32, BK=64): epilogue-lite, always stores neg16 ----------------
__global__ __launch_bounds__(256) void k_gemm(
    const __bf16* __restrict__ Ap, const __bf16* __restrict__ Ep,
    const float* __restrict__ asq, const float* __restrict__ esq,
    _Float16* __restrict__ neg16, int biOff)
{
  __shared__ __bf16 sA[2*KBLK_ELEMS];   // 16 KB
  __shared__ __bf16 sB[2*KBLK_ELEMS];   // 16 KB
  int tid = threadIdx.x;

  int wave = tid>>6, lane = tid&63, quad = lane>>4, l16 = lane&15;
  int biL = blockIdx.x, bj = blockIdx.y;
  int bi = biOff + biL;
  int wi = wave>>1, wj = wave&1;

  const __bf16* Asrc = Ap + (size_t)bi*TILE_ELEMS;
  const __bf16* Bsrc = Ep + (size_t)bj*TILE_ELEMS;

  int a_off[4], b_off[4];
#pragma unroll
  for (int rt=0; rt<4; ++rt){ int row = wi*64 + rt*16 + l16; a_off[rt] = swz_off(row, quad); }
#pragma unroll
  for (int ct=0; ct<4; ++ct){ int row = wj*64 + ct*16 + l16; b_off[ct] = swz_off(row, quad); }

  const __bf16* gsrc = (wave<2 ? Asrc : Bsrc);
  __bf16* ldsb = (wave<2 ? sA : sB);
  int half = (wave&1)*KBLK_ELEMS;

  const f32x4 zf = {0.f,0.f,0.f,0.f};
  f32x4 acc[4][4];
#pragma unroll
  for (int rt=0; rt<4; ++rt)
#pragma unroll
    for (int ct=0; ct<4; ++ct) acc[rt][ct] = zf;

  for (int kb2=0; kb2<12; ++kb2){
    __syncthreads();
    const __bf16* g = gsrc + kb2*(2*KBLK_ELEMS) + half + lane*8;
#pragma unroll
    for (int s=0; s<8; ++s)
      gl2lds16(g + s*512, ldsb + half + s*512);
    __syncthreads();
#pragma unroll
    for (int ks=0; ks<2; ++ks){
      int o = ks*KBLK_ELEMS;
      bf16x8 af[4], bf[4];
#pragma unroll
      for (int rt=0; rt<4; ++rt) af[rt] = *(const bf16x8*)(sA + o + a_off[rt]);
#pragma unroll
      for (int ct=0; ct<4; ++ct) bf[ct] = *(const bf16x8*)(sB + o + b_off[ct]);
#pragma unroll
      for (int rt=0; rt<4; ++rt)
#pragma unroll
        for (int ct=0; ct<4; ++ct)
          acc[rt][ct] = __builtin_amdgcn_mfma_f32_16x16x32_bf16(af[rt], bf[ct], acc[rt][ct], 0,0,0);
    }
  }

  // ---- epilogue-lite: convert + coalesced store ----
  int jbase = bj*128 + wj*64;
  float esqv[4];
#pragma unroll
  for (int ct=0; ct<4; ++ct) esqv[ct] = esq[jbase + ct*16 + l16];

  size_t tBase = ((size_t)bj*NCHB + biL)*16384;
#pragma unroll
  for (int rt=0; rt<4; ++rt){
    _Float16 h16[16];
#pragma unroll
    for (int reg=0; reg<4; ++reg){
      int il = wi*64 + rt*16 + quad*4 + reg;
      int i  = bi*128 + il;
      float av = asq[i];
#pragma unroll
      for (int ct=0; ct<4; ++ct){
        float neg = (av + esqv[ct]) - 2.f*acc[rt][ct][reg];
        h16[reg*4+ct] = (_Float16)neg;
      }
    }
    _Float16* dst = neg16 + tBase + ((size_t)(wave*4 + rt))*1024 + lane*16;
    *(half8*)(dst)     = *(half8*)&h16[0];
    *(half8*)(dst + 8) = *(half8*)&h16[8];
  }
}

// ---------------- moments streamer over stored fp16 neg ----------------
__global__ __launch_bounds__(256) void k_mom(
    const _Float16* __restrict__ neg16, const int* __restrict__ pairs,
    float* __restrict__ rs1, float* __restrict__ rs2, float* __restrict__ rmin, int biOff)
{
  __shared__ float red[768];
  int tid = threadIdx.x;
  int wave = tid>>6, lane = tid&63, quad = lane>>4, l16 = lane&15;
  int biL = blockIdx.x, bj = blockIdx.y;
  int bi = biOff + biL;
  int wi = wave>>1, wj = wave&1;
  int jbase = bj*128 + wj*64;
  bool val[4]; int jcol[4];
#pragma unroll
  for (int ct=0; ct<4; ++ct){
    jcol[ct] = jbase + ct*16 + l16;
    val[ct] = jcol[ct] < N_NODE;
  }
  size_t tBase = ((size_t)bj*NCHB + biL)*16384;
#pragma unroll
  for (int rt=0; rt<4; ++rt){
    const _Float16* src = neg16 + tBase + ((size_t)(wave*4 + rt))*1024 + lane*16;
    half8 v0 = *(const half8*)(src);
    half8 v1 = *(const half8*)(src + 8);
    _Float16 h16[16];
    *(half8*)&h16[0] = v0; *(half8*)&h16[8] = v1;
#pragma unroll
    for (int reg=0; reg<4; ++reg){
      int il = wi*64 + rt*16 + quad*4 + reg;
      int i  = bi*128 + il;
      int p  = i & (BATCH-1);
      int li = pairs[2*p], ri = pairs[2*p+1];
      float s=0.f, q=0.f, mn=1e30f;
#pragma unroll
      for (int ct=0; ct<4; ++ct){
        float neg = (float)h16[reg*4+ct];
        s += neg;
        q = fmaf(neg, neg, q);
        bool bad = (jcol[ct]==li) | (jcol[ct]==ri) | (!val[ct]);
        mn = fminf(mn, bad ? 1e30f : neg);
      }
#pragma unroll
      for (int m=1;m<16;m<<=1){
        s += __shfl_xor(s,m,64); q += __shfl_xor(q,m,64);
        mn = fminf(mn, __shfl_xor(mn,m,64));
      }
      if (l16 == 0){
        red[il*2+wj] = s; red[256 + il*2+wj] = q; red[512 + il*2+wj] = mn;
      }
    }
  }
  __syncthreads();
  if (tid < 128){
    int i = bi*128 + tid;
    atomicAdd(rs1+i, red[tid*2] + red[tid*2+1]);
    atomicAdd(rs2+i, red[256 + tid*2] + red[256 + tid*2+1]);
    atomicMinF(rmin+i, fminf(red[512 + tid*2], red[512 + tid*2+1]));
  }
}

// ---------------- streaming pass 2 (exp) over stored fp16 neg ----------------
__global__ __launch_bounds__(256) void k_p2s(
    const _Float16* __restrict__ neg16, const float* __restrict__ CC, const float* __restrict__ AL,
    const int* __restrict__ pairs, float* __restrict__ rexp, int biOff)
{
  __shared__ float red[256];
  int tid = threadIdx.x;
  int wave = tid>>6, lane = tid&63, quad = lane>>4, l16 = lane&15;
  int biL = blockIdx.x, bj = blockIdx.y;
  int bi = biOff + biL;
  int wi = wave>>1, wj = wave&1;
  int jbase = bj*128 + wj*64;
  bool val[4]; int jcol[4];
#pragma unroll
  for (int ct=0; ct<4; ++ct){
    jcol[ct] = jbase + ct*16 + l16;
    val[ct] = jcol[ct] < N_NODE;
  }
  size_t tBase = ((size_t)bj*NCHB + biL)*16384;
#pragma unroll
  for (int rt=0; rt<4; ++rt){
    const _Float16* src = neg16 + tBase + ((size_t)(wave*4 + rt))*1024 + lane*16;
    half8 v0 = *(const half8*)(src);
    half8 v1 = *(const half8*)(src + 8);
    _Float16 h16[16];
    *(half8*)&h16[0] = v0; *(half8*)&h16[8] = v1;
#pragma unroll
    for (int reg=0; reg<4; ++reg){
      int il = wi*64 + rt*16 + quad*4 + reg;
      int i  = bi*128 + il;
      int p  = i & (BATCH-1);
      int li = pairs[2*p], ri = pairs[2*p+1];
      float C = CC[i], A = AL[i];
      float s = 0.f;
#pragma unroll
      for (int ct=0; ct<4; ++ct){
        float neg = (float)h16[reg*4+ct];
        bool bad = (jcol[ct]==li) | (jcol[ct]==ri) | (!val[ct]);
        s += bad ? 0.f : __expf(fmaf(-A, neg, C));
      }
#pragma unroll
      for (int m=1;m<16;m<<=1) s += __shfl_xor(s,m,64);
      if (l16 == 0) red[il*2+wj] = s;
    }
  }
  __syncthreads();
  if (tid < 128){
    int i = bi*128 + tid;
    atomicAdd(rexp+i, red[tid*2] + red[tid*2+1]);
  }
}

// ---------------- per-row special-column dots ----------------
__global__ __launch_bounds__(256) void k_corr(
    const int* __restrict__ pairs, const __bf16* __restrict__ Ap, const __bf16* __restrict__ Ep,
    const float* __restrict__ asq, const float* __restrict__ esq,
    float* __restrict__ negl, float* __restrict__ negr, int iOff)
{
  int wave = threadIdx.x>>6, lane = threadIdx.x&63;
  int i = iOff + blockIdx.x*4 + wave;
  int p = i & (BATCH-1);
  int li = pairs[2*p], ri = pairs[2*p+1];
  const __bf16* Ar = Ap + (size_t)(i>>7)*TILE_ELEMS;  int ra = i&127;
  const __bf16* E1 = Ep + (size_t)(li>>7)*TILE_ELEMS; int r1 = li&127;
  const __bf16* E2 = Ep + (size_t)(ri>>7)*TILE_ELEMS; int r2 = ri&127;
  float d1=0.f, d2=0.f;
  for (int c=lane; c<96; c+=64){
    int kb = c>>2, q = c&3;
    bf16x8 a  = *(const bf16x8*)(Ar + kb*KBLK_ELEMS + swz_off(ra, q));
    bf16x8 e1 = *(const bf16x8*)(E1 + kb*KBLK_ELEMS + swz_off(r1, q));
    bf16x8 e2 = *(const bf16x8*)(E2 + kb*KBLK_ELEMS + swz_off(r2, q));
#pragma unroll
    for (int e=0;e<8;e++){
      d1 = fmaf((float)a[e], (float)e1[e], d1);
      d2 = fmaf((float)a[e], (float)e2[e], d2);
    }
  }
  d1 = waveSum(d1); d2 = waveSum(d2);
  if (lane==0){
    float av = asq[i];
    negl[i] = av + esq[li] - 2.f*d1;
    negr[i] = av + esq[ri] - 2.f*d2;
  }
}

// ---------------- stats ----------------
__global__ __launch_bounds__(256) void k_stats(
    const float* __restrict__ rs1, const float* __restrict__ rs2, const float* __restrict__ rmin,
    const float* __restrict__ negl, const float* __restrict__ negr,
    const float* __restrict__ asq, const float* __restrict__ pos, const int* __restrict__ pairs,
    float* __restrict__ MM, float* __restrict__ CC, float* __restrict__ AL, float* __restrict__ rexp, int iOff)
{
  int i = iOff + blockIdx.x*256 + threadIdx.x;
  int p = i & (BATCH-1);
  int li = pairs[2*p], ri = pairs[2*p+1];
  float K = pos[p] + GAMMA_C;
  float av = asq[i];
  float S1 = rs1[i] - (float)PADN*av;
  float S2 = rs2[i] - (float)PADN*av*av;
  float nl = negl[i], nr = negr[i];
  float Sx, Sxx, mx;
  const float invN = 1.f/(float)N_NODE;
  if (li != ri){
    Sx  = -(S1 - nl - nr) - 2.f*K;
    Sxx = (S2 - nl*nl - nr*nr) + 2.f*K*K;
    mx  = fmaxf(K - rmin[i], 0.f);
    float mu = K + Sx*invN;
    float m2 = Sx*invN;
    float var = Sxx*invN - m2*m2;
    float sd = sqrtf(fmaxf(var, 1e-30f));
    float M = LAMB_C*(mx-mu)/sd + TAU_C;
    MM[i] = M; CC[i] = LAMB_C*(K-mu)/sd + TAU_C - M; AL[i] = LAMB_C/sd;
    rexp[i] = 2.f*__expf(LAMB_C*(0.f-mu)/sd + TAU_C - M);
  } else {
    float lossm = nl - K;
    float x = lossm - K;
    Sx  = -(S1 - nl) + x;
    Sxx = (S2 - nl*nl) + x*x;
    mx  = fmaxf(K - rmin[i], lossm);
    float mu = K + Sx*invN;
    float m2 = Sx*invN;
    float var = Sxx*invN - m2*m2;
    float sd = sqrtf(fmaxf(var, 1e-30f));
    float M = LAMB_C*(mx-mu)/sd + TAU_C;
    MM[i] = M; CC[i] = LAMB_C*(K-mu)/sd + TAU_C - M; AL[i] = LAMB_C/sd;
    rexp[i] = __expf(LAMB_C*(lossm-mu)/sd + TAU_C - M);
  }
}

__global__ __launch_bounds__(256) void k_final(const float* __restrict__ mm, const float* __restrict__ rexp, float* __restrict__ out){
  __shared__ float red[256];
  float s = 0.f;
  for (int i=threadIdx.x; i<NROWA; i+=256) s += mm[i] + logf(rexp[i]);
  red[threadIdx.x] = s; __syncthreads();
  for (int st=128; st>0; st>>=1){ if (threadIdx.x<st) red[threadIdx.x]+=red[threadIdx.x+st]; __syncthreads(); }
  if (threadIdx.x==0) out[0] = red[0]*(1.f/BATCH);
}

extern "C" void kernel_launch(void* const* d_in, const int* in_sizes, int n_in,
                              void* d_out, int out_size, void* d_ws, size_t ws_size,
                              hipStream_t stream) {
  const int*   pairs   = (const int*)d_in[0];
  const int*   ent_adj = (const int*)d_in[1];
  const int*   rel_adj = (const int*)d_in[2];
  const int*   adj     = (const int*)d_in[3];
  const int*   r_index = (const int*)d_in[4];
  const float* r_val   = (const float*)d_in[5];
  const float* ent_emb = (const float*)d_in[7];
  const float* rel_emb = (const float*)d_in[8];
  const float* attn_e  = (const float*)d_in[9];
  const float* attn_r  = (const float*)d_in[10];

  char* base = (char*)d_ws;
  size_t off = 0;
  auto take = [&](size_t bytes)->char*{
    char* p = base + off;
    off = (off + bytes + 511) & ~(size_t)511;
    return p;
  };
  // persistent GEMM-phase region (~53.5 MB)
  __bf16* EP    = (__bf16*)take((size_t)NTILE_E*TILE_ELEMS*2);
  __bf16* AP    = (__bf16*)take((size_t)NTILE_A*TILE_ELEMS*2);
  float*  ESQ   = (float*)take((size_t)EPAD*4);
  float*  ASQ   = (float*)take((size_t)NROWA*4);
  float*  POS   = (float*)take((size_t)BATCH*4);
  float*  RS1   = (float*)take((size_t)NROWA*4);
  float*  RS2   = (float*)take((size_t)NROWA*4);
  float*  RMIN  = (float*)take((size_t)NROWA*4);
  float*  NEGL  = (float*)take((size_t)NROWA*4);
  float*  NEGR  = (float*)take((size_t)NROWA*4);
  float*  MM    = (float*)take((size_t)NROWA*4);
  float*  CCv   = (float*)take((size_t)NROWA*4);
  float*  ALv   = (float*)take((size_t)NROWA*4);
  float*  REXP  = (float*)take((size_t)NROWA*4);

  // graph-phase region (dead by GEMM time) — overlapped by NEG16 (123 MB per chunk)
  size_t offG = off;
  __bf16* OUTB = (__bf16*)take((size_t)N_NODE*OUTD*2);     // 46.1 MB, interleaved layout
  __bf16* TRI  = (__bf16*)take((size_t)N_TRI*DIM*2);       // 51.2 MB
  float*  ATT4 = (float*)take((size_t)4*N_TRI*4);          // 3.2 MB
  int* RP_E  = (int*)take((size_t)(N_NODE+1)*4);
  int* RP_R  = (int*)take((size_t)(N_NODE+1)*4);
  int* RP_A  = (int*)take((size_t)(N_NODE+1)*4);
  int* IDX_E = (int*)take((size_t)N_TRI*4);
  int* IDX_R = (int*)take((size_t)N_TRI*4);
  int* IDX_A = (int*)take((size_t)N_TRI*4);
  int* CNT6  = (int*)take((size_t)6*N_NODE*4);
  int* BTOT  = (int*)take((size_t)3*NBLK_SCAN*4);
  int* CNT_E = CNT6,            *CNT_R = CNT6 + N_NODE,   *CNT_A = CNT6 + 2*N_NODE;
  int* CUR_E = CNT6 + 3*N_NODE, *CUR_R = CNT6 + 4*N_NODE, *CUR_A = CNT6 + 5*N_NODE;

  _Float16* NEG16 = (_Float16*)(base + offG);   // 123.2 MB per chunk

  const int* cols = adj + N_TRI;

  // ---- init ----
  k_fill<<<192,256,0,stream>>>((float*)CNT6, (long)6*N_NODE, 0.f);

  // ---- CSR builds ----
  k_hist<<<782,256,0,stream>>>(ent_adj, CNT_E);
  k_hist<<<782,256,0,stream>>>(rel_adj, CNT_R);
  k_hist<<<782,256,0,stream>>>(adj,     CNT_A);
  dim3 gsA(NBLK_SCAN, 3, 1);
  k_scanA<<<gsA,256,0,stream>>>(CNT_E, CNT_R, CNT_A, RP_E, RP_R, RP_A, BTOT, N_NODE);
  k_scanB<<<3,128,0,stream>>>(BTOT, RP_E, RP_R, RP_A, N_NODE);
  k_scanC<<<gsA,256,0,stream>>>(RP_E, RP_R, RP_A, BTOT, N_NODE);
  k_place<<<782,256,0,stream>>>(ent_adj, ent_adj+N_TRI, RP_E, CUR_E, IDX_E, 1);
  k_place<<<782,256,0,stream>>>(rel_adj, rel_adj+N_TRI, RP_R, CUR_R, IDX_R, 1);
  k_place<<<782,256,0,stream>>>(adj,     (const int*)0, RP_A, CUR_A, IDX_A, 0);

  // ---- feature pipeline (interleaved bf16 features) ----
  k_feat0<<<7500,256,0,stream>>>(RP_E, IDX_E, RP_R, IDX_R, ent_emb, rel_emb, OUTB);
  k_trinorm<<<25000,256,0,stream>>>(r_index+N_TRI, r_val, rel_emb, TRI, attn_e, attn_r, ATT4);
  k_gat<<<7500,256,0,stream>>>(RP_A, IDX_A, cols, TRI,
                               ATT4 + 0*N_TRI, ATT4 + 2*N_TRI, OUTB, 0, 256);
  k_gat<<<7500,256,0,stream>>>(RP_A, IDX_A, cols, TRI,
                               ATT4 + 1*N_TRI, ATT4 + 3*N_TRI, OUTB, 256, 512);

  // ---- loss prep ----
  k_packE<<<7520,256,0,stream>>>(OUTB, EP, ESQ);
  k_packA<<<512,256,0,stream>>>(pairs, EP, OUTB, ESQ, AP, ASQ, POS);
  k_fill<<<16,256,0,stream>>>(RS1, (long)NROWA, 0.f);
  k_fill<<<16,256,0,stream>>>(RS2, (long)NROWA, 0.f);
  k_fill<<<16,256,0,stream>>>(RMIN,(long)NROWA, 1e30f);

  // ---- loss phase: 2 row-chunks of 16 bi-tiles; NEG16 L3-resident per chunk ----
  for (int ch=0; ch<NTILE_A/NCHB; ++ch){
    int biOff = ch*NCHB;
    int iOff  = biOff*128;
    dim3 gg(NCHB, NTILE_E, 1);
    k_gemm<<<gg,256,0,stream>>>(AP, EP, ASQ, ESQ, NEG16, biOff);
    k_mom<<<gg,256,0,stream>>>(NEG16, pairs, RS1, RS2, RMIN, biOff);
    k_corr<<<NCHB*128/4,256,0,stream>>>(pairs, AP, EP, ASQ, ESQ, NEGL, NEGR, iOff);
    k_stats<<<NCHB*128/256,256,0,stream>>>(RS1, RS2, RMIN, NEGL, NEGR, ASQ, POS, pairs,
                                           MM, CCv, ALv, REXP, iOff);
    k_p2s<<<gg,256,0,stream>>>(NEG16, CCv, ALv, pairs, REXP, biOff);
  }
  k_final<<<1,256,0,stream>>>(MM, REXP, (float*)d_out);
}

// Round 16
// 674.723 us; speedup vs baseline: 1.8345x; 1.0976x over previous
//
#include <hip/hip_runtime.h>
#include <hip/hip_bf16.h>
#include <math.h>

#define N_NODE 30000
#define N_TRI  200000
#define DIM    128
#define OUTD   768
#define BATCH  2048
#define NROWA  4096
#define EPAD   30080   // 235*128
#define PADN   80      // EPAD - N_NODE
#define NTILE_E 235
#define NTILE_A 32
#define NCHB   16      // bi-tiles per loss chunk (2 chunks)
#define NBLK_SCAN 118  // ceil(30000/256)
#define TILE_ELEMS (128*OUTD)
#define KBLK_ELEMS (128*32)
#define GAMMA_C 3.0f
#define LAMB_C  30.0f
#define TAU_C   10.0f

typedef __attribute__((ext_vector_type(8)))  __bf16 bf16x8;
typedef __attribute__((ext_vector_type(4)))  __bf16 bf16x4;
typedef __attribute__((ext_vector_type(2)))  __bf16 bf16x2;
typedef __attribute__((ext_vector_type(8)))  _Float16 half8;
typedef __attribute__((ext_vector_type(4)))  float f32x4;

__device__ __forceinline__ float waveSum(float v){
#pragma unroll
  for (int m=1;m<64;m<<=1) v += __shfl_xor(v, m, 64);
  return v;
}
__device__ __forceinline__ float halfSum(float v){
#pragma unroll
  for (int m=1;m<32;m<<=1) v += __shfl_xor(v, m, 64);
  return v;
}

__device__ __forceinline__ void atomicMinF(float* a, float v){
  if (v >= 0.f) atomicMin((int*)a, __float_as_int(v));
  else          atomicMax((unsigned int*)a, __float_as_uint(v));
}

__device__ __forceinline__ void gl2lds16(const void* g, void* l){
  __builtin_amdgcn_global_load_lds(
      (const __attribute__((address_space(1))) char*)g,
      (__attribute__((address_space(3))) char*)l, 16, 0, 0);
}

__device__ __forceinline__ int swz_off(int r, int q){
  return r*32 + ((q ^ ((r>>1)&3))<<3);
}

// ---------------- fill ----------------
__global__ void k_fill(float* __restrict__ p, long n, float v){
  long i = (long)blockIdx.x*blockDim.x + threadIdx.x;
  long st = (long)gridDim.x*blockDim.x;
  for (; i<n; i+=st) p[i]=v;
}

// ---------------- CSR build ----------------
__global__ __launch_bounds__(256) void k_hist(const int* __restrict__ rows, int* __restrict__ cnt){
  int t = blockIdx.x*256 + threadIdx.x;
  if (t < N_TRI) atomicAdd(&cnt[rows[t]], 1);
}

// 3-stage parallel exclusive scan
__global__ __launch_bounds__(256) void k_scanA(
    const int* __restrict__ c0, const int* __restrict__ c1, const int* __restrict__ c2,
    int* __restrict__ r0, int* __restrict__ r1, int* __restrict__ r2,
    int* __restrict__ btot, int n){
  const int* cnt = blockIdx.y==0 ? c0 : (blockIdx.y==1 ? c1 : c2);
  int* rp        = blockIdx.y==0 ? r0 : (blockIdx.y==1 ? r1 : r2);
  __shared__ int buf[256];
  int i = blockIdx.x*256 + threadIdx.x;
  int v = (i<n) ? cnt[i] : 0;
  buf[threadIdx.x] = v;
  __syncthreads();
  for (int off=1; off<256; off<<=1){
    int t = (threadIdx.x>=off) ? buf[threadIdx.x-off] : 0;
    __syncthreads();
    buf[threadIdx.x] += t;
    __syncthreads();
  }
  if (i<n) rp[i] = buf[threadIdx.x] - v;   // block-local exclusive
  if (threadIdx.x==255) btot[blockIdx.y*NBLK_SCAN + blockIdx.x] = buf[255];
}

__global__ __launch_bounds__(128) void k_scanB(int* __restrict__ btot,
    int* __restrict__ r0, int* __restrict__ r1, int* __restrict__ r2, int n){
  __shared__ int buf[128];
  int c = blockIdx.x;
  int v = (threadIdx.x < NBLK_SCAN) ? btot[c*NBLK_SCAN + threadIdx.x] : 0;
  buf[threadIdx.x] = v;
  __syncthreads();
  for (int off=1; off<128; off<<=1){
    int t = (threadIdx.x>=off) ? buf[threadIdx.x-off] : 0;
    __syncthreads();
    buf[threadIdx.x] += t;
    __syncthreads();
  }
  if (threadIdx.x < NBLK_SCAN) btot[c*NBLK_SCAN + threadIdx.x] = buf[threadIdx.x] - v;  // exclusive
  if (threadIdx.x == 127){
    int* rp = c==0 ? r0 : (c==1 ? r1 : r2);
    rp[n] = buf[127];
  }
}

__global__ __launch_bounds__(256) void k_scanC(
    int* __restrict__ r0, int* __restrict__ r1, int* __restrict__ r2,
    const int* __restrict__ btot, int n){
  int* rp = blockIdx.y==0 ? r0 : (blockIdx.y==1 ? r1 : r2);
  int i = blockIdx.x*256 + threadIdx.x;
  if (i<n) rp[i] += btot[blockIdx.y*NBLK_SCAN + blockIdx.x];
}

__global__ __launch_bounds__(256) void k_place(const int* __restrict__ rows, const int* __restrict__ vals,
                        const int* __restrict__ rowptr, int* __restrict__ cur, int* __restrict__ idx, int mode){
  int t = blockIdx.x*256 + threadIdx.x;
  if (t < N_TRI){
    int r = rows[t];
    int p = atomicAdd(&cur[r], 1);
    idx[rowptr[r] + p] = mode ? vals[t] : t;
  }
}

// ---------------- fused sparse means + tanh -> interleaved bf16 features ----------------
__global__ __launch_bounds__(256) void k_feat0(
    const int* __restrict__ rpE, const int* __restrict__ idxE,
    const int* __restrict__ rpR, const int* __restrict__ idxR,
    const float* __restrict__ ent_emb, const float* __restrict__ rel_emb,
    __bf16* __restrict__ outb){
  int wave = threadIdx.x>>6, lane = threadIdx.x&63;
  int i = blockIdx.x*4 + wave;
  if (i >= N_NODE) return;
  int bE = rpE[i], eE = rpE[i+1];
  int bR = rpR[i], eR = rpR[i+1];
  float2 aE = {0.f,0.f}, aR = {0.f,0.f};
  for (int k=bE; k<eE; ++k){
    int c = idxE[k];
    float2 v = *(const float2*)(ent_emb + (size_t)c*DIM + lane*2);
    aE.x += v.x; aE.y += v.y;
  }
  for (int k=bR; k<eR; ++k){
    int c = idxR[k];
    float2 v = *(const float2*)(rel_emb + (size_t)c*DIM + lane*2);
    aR.x += v.x; aR.y += v.y;
  }
  float ie = 1.f/fmaxf((float)(eE-bE), 1.f);
  float ir = 1.f/fmaxf((float)(eR-bR), 1.f);
  bf16x2 oE, oR;
  oE[0] = (__bf16)tanhf(aE.x*ie); oE[1] = (__bf16)tanhf(aE.y*ie);
  oR[0] = (__bf16)tanhf(aR.x*ir); oR[1] = (__bf16)tanhf(aR.y*ir);
  *(bf16x2*)(outb + (size_t)i*OUTD +   0 + lane*2) = oE;   // e0
  *(bf16x2*)(outb + (size_t)i*OUTD + 128 + lane*2) = oR;   // r0
}

// ---------------- tri_rel direct + norm(bf16) + att logits — half-wave per triple ----------------
__global__ __launch_bounds__(256) void k_trinorm(
    const int* __restrict__ ridx1, const float* __restrict__ rval,
    const float* __restrict__ rel_emb,
    __bf16* __restrict__ tri, const float* __restrict__ attnE,
    const float* __restrict__ attnR, float* __restrict__ att4){
  __shared__ float ak[4][DIM];
  int tid = threadIdx.x;
  for (int idx=tid; idx<4*DIM; idx+=256){
    int k = idx>>7, d = idx&127;
    ak[k][d] = (k<2) ? attnE[k*DIM + d] : attnR[(k-2)*DIM + d];
  }
  __syncthreads();
  int half = tid>>5, l31 = tid&31;
  int t = blockIdx.x*8 + half;
  if (t >= N_TRI) return;
  int rr = ridx1[t];
  float rv = rval[t];
  float4 v = *(const float4*)(rel_emb + (size_t)rr*DIM + l31*4);
  v.x *= rv; v.y *= rv; v.z *= rv; v.w *= rv;
  float ss = halfSum(v.x*v.x + v.y*v.y + v.z*v.z + v.w*v.w);
  float inv = 1.f/fmaxf(sqrtf(ss), 1e-12f);
  v.x *= inv; v.y *= inv; v.z *= inv; v.w *= inv;
  bf16x4 b; b[0]=(__bf16)v.x; b[1]=(__bf16)v.y; b[2]=(__bf16)v.z; b[3]=(__bf16)v.w;
  *(bf16x4*)(tri + (size_t)t*DIM + l31*4) = b;
#pragma unroll
  for (int k=0;k<4;k++){
    const float* a = &ak[k][l31*4];
    float p = halfSum(v.x*a[0] + v.y*a[1] + v.z*a[2] + v.w*a[3]);
    if (l31==0) att4[(size_t)k*N_TRI + t] = p;
  }
}

// ---------------- fused GAT layer: single-pass, half-wave per branch ----------------
__global__ __launch_bounds__(256) void k_gat(
    const int* __restrict__ rowptr, const int* __restrict__ idx, const int* __restrict__ cols,
    const __bf16* __restrict__ tri,
    const float* __restrict__ attE, const float* __restrict__ attR,
    __bf16* __restrict__ outb, int inOff, int outOff){
  int wave = threadIdx.x>>6, lane = threadIdx.x&63;
  int i = blockIdx.x*4 + wave;
  if (i >= N_NODE) return;
  int l31 = lane&31;
  const float* att = (lane < 32) ? attE : attR;
  int beg = rowptr[i], end = rowptr[i+1];
  float a0=0.f, a1=0.f, a2=0.f, a3=0.f;
  if (end > beg){
    float z = 0.f;
    int t0 = idx[beg];
    int c0 = cols[t0];
    bf16x4 u4 = *(const bf16x4*)(tri + (size_t)t0*DIM + l31*4);
    bf16x4 f4 = *(const bf16x4*)(outb + (size_t)c0*OUTD + inOff + lane*4);
    float atv = att[t0];
    for (int k=beg; k<end; ++k){
      bf16x4 u4c = u4, f4c = f4;
      float atc = atv;
      if (k+1 < end){
        int t1 = idx[k+1];
        int c1 = cols[t1];
        u4 = *(const bf16x4*)(tri + (size_t)t1*DIM + l31*4);
        f4 = *(const bf16x4*)(outb + (size_t)c1*OUTD + inOff + lane*4);
        atv = att[t1];
      }
      float u0=(float)u4c[0], u1=(float)u4c[1], u2=(float)u4c[2], u3=(float)u4c[3];
      float f0=(float)f4c[0], f1=(float)f4c[1], f2=(float)f4c[2], f3=(float)f4c[3];
      float d = f0*u0 + f1*u1 + f2*u2 + f3*u3;
#pragma unroll
      for (int mm=1; mm<32; mm<<=1) d += __shfl_xor(d, mm, 64);
      float w = __expf(atc);        // |att| <= ~2.5, safe without shift
      z += w;
      float d2 = 2.f*d;
      a0 = fmaf(w, fmaf(-d2, u0, f0), a0);
      a1 = fmaf(w, fmaf(-d2, u1, f1), a1);
      a2 = fmaf(w, fmaf(-d2, u2, f2), a2);
      a3 = fmaf(w, fmaf(-d2, u3, f3), a3);
    }
    float iz = 1.f/z;               // z lane-uniform (serial edge loop)
    a0 *= iz; a1 *= iz; a2 *= iz; a3 *= iz;
  }
  bf16x4 o;
  o[0] = (__bf16)tanhf(a0); o[1] = (__bf16)tanhf(a1);
  o[2] = (__bf16)tanhf(a2); o[3] = (__bf16)tanhf(a3);
  *(bf16x4*)(outb + (size_t)i*OUTD + outOff + lane*4) = o;
}

// ---------------- pack E ----------------
__global__ __launch_bounds__(256) void k_packE(const __bf16* __restrict__ outb, __bf16* __restrict__ Ep, float* __restrict__ esq){
  const int perm[6] = {0,2,4,1,3,5};
  int wave = threadIdx.x>>6, lane = threadIdx.x&63;
  int j = blockIdx.x*4 + wave;
  if (j >= EPAD) return;
  int jt = j>>7, r = j&127;
  __bf16* tb = Ep + (size_t)jt*TILE_ELEMS;
  float ss = 0.f;
  for (int c=lane; c<96; c+=64){
    int kb = c>>2, q = c&3;
    bf16x8 o;
    if (j < N_NODE){
      int ib = perm[c>>4], wb = c&15;
      o = *(const bf16x8*)(outb + (size_t)j*OUTD + ib*128 + wb*8);
#pragma unroll
      for (int e=0;e<8;e++){ float v = (float)o[e]; ss += v*v; }
    } else {
#pragma unroll
      for (int e=0;e<8;e++) o[e] = (__bf16)0.f;
    }
    *(bf16x8*)(tb + kb*KBLK_ELEMS + swz_off(r, q)) = o;
  }
  ss = waveSum(ss);
  if (lane==0) esq[j] = (j < N_NODE) ? ss : 0.f;
}

__global__ __launch_bounds__(256) void k_packA(const int* __restrict__ pairs, const __bf16* __restrict__ Ep,
    const __bf16* __restrict__ outb, const float* __restrict__ esq,
    __bf16* __restrict__ Ap, float* __restrict__ asq, float* __restrict__ pos){
  int wave = threadIdx.x>>6, lane = threadIdx.x&63;
  int p = blockIdx.x*4 + wave;
  if (p >= BATCH) return;
  int l = pairs[2*p], r = pairs[2*p+1];
  float ss = 0.f;
#pragma unroll
  for (int c=0;c<6;c++){
    int d = c*128 + lane*2;
    bf16x2 a = *(const bf16x2*)(outb + (size_t)l*OUTD + d);
    bf16x2 b = *(const bf16x2*)(outb + (size_t)r*OUTD + d);
    float dx = (float)a[0]-(float)b[0], dy = (float)a[1]-(float)b[1];
    ss += dx*dx + dy*dy;
  }
  ss = waveSum(ss);
  if (lane==0){ pos[p] = ss; asq[p] = esq[l]; asq[p+BATCH] = esq[r]; }
  int lt = l>>7, lr = l&127;
  int rt2 = r>>7, rr = r&127;
  int p0t = p>>7, p0r = p&127;
  int p1t = (p+BATCH)>>7, p1r = (p+BATCH)&127;
  for (int c=lane; c<96; c+=64){
    int kb = c>>2, q = c&3;
    bf16x8 vl = *(const bf16x8*)(Ep + (size_t)lt*TILE_ELEMS + kb*KBLK_ELEMS + swz_off(lr, q));
    *(bf16x8*)(Ap + (size_t)p0t*TILE_ELEMS + kb*KBLK_ELEMS + swz_off(p0r, q)) = vl;
    bf16x8 vr = *(const bf16x8*)(Ep + (size_t)rt2*TILE_ELEMS + kb*KBLK_ELEMS + swz_off(rr, q));
    *(bf16x8*)(Ap + (size_t)p1t*TILE_ELEMS + kb*KBLK_ELEMS + swz_off(p1r, q)) = vr;
  }
}

// ---------------- GEMM (16x16x32, BK=64): stores neg16 + fused LDS-scratch moments ----------------
// Scratch layout [3][128][32], column = wj*16 + l16 (race-free: each slot written once).
__global__ __launch_bounds__(256) void k_gemm(
    const __bf16* __restrict__ Ap, const __bf16* __restrict__ Ep,
    const float* __restrict__ asq, const float* __restrict__ esq,
    const int* __restrict__ pairs,
    float* __restrict__ rs1, float* __restrict__ rs2, float* __restrict__ rmin,
    _Float16* __restrict__ neg16, int biOff)
{
  __shared__ char smem[49152];
  __bf16* sA = (__bf16*)smem;                 // 16 KB
  __bf16* sB = (__bf16*)(smem + 16384);       // 16 KB
  int tid = threadIdx.x;

  int wave = tid>>6, lane = tid&63, quad = lane>>4, l16 = lane&15;
  int biL = blockIdx.x, bj = blockIdx.y;
  int bi = biOff + biL;
  int wi = wave>>1, wj = wave&1;

  const __bf16* Asrc = Ap + (size_t)bi*TILE_ELEMS;
  const __bf16* Bsrc = Ep + (size_t)bj*TILE_ELEMS;

  int a_off[4], b_off[4];
#pragma unroll
  for (int rt=0; rt<4; ++rt){ int row = wi*64 + rt*16 + l16; a_off[rt] = swz_off(row, quad); }
#pragma unroll
  for (int ct=0; ct<4; ++ct){ int row = wj*64 + ct*16 + l16; b_off[ct] = swz_off(row, quad); }

  const __bf16* gsrc = (wave<2 ? Asrc : Bsrc);
  __bf16* ldsb = (wave<2 ? sA : sB);
  int half = (wave&1)*KBLK_ELEMS;

  const f32x4 zf = {0.f,0.f,0.f,0.f};
  f32x4 acc[4][4];
#pragma unroll
  for (int rt=0; rt<4; ++rt)
#pragma unroll
    for (int ct=0; ct<4; ++ct) acc[rt][ct] = zf;

  for (int kb2=0; kb2<12; ++kb2){
    __syncthreads();
    const __bf16* g = gsrc + kb2*(2*KBLK_ELEMS) + half + lane*8;
#pragma unroll
    for (int s=0; s<8; ++s)
      gl2lds16(g + s*512, ldsb + half + s*512);
    __syncthreads();
#pragma unroll
    for (int ks=0; ks<2; ++ks){
      int o = ks*KBLK_ELEMS;
      bf16x8 af[4], bf[4];
#pragma unroll
      for (int rt=0; rt<4; ++rt) af[rt] = *(const bf16x8*)(sA + o + a_off[rt]);
#pragma unroll
      for (int ct=0; ct<4; ++ct) bf[ct] = *(const bf16x8*)(sB + o + b_off[ct]);
#pragma unroll
      for (int rt=0; rt<4; ++rt)
#pragma unroll
        for (int ct=0; ct<4; ++ct)
          acc[rt][ct] = __builtin_amdgcn_mfma_f32_16x16x32_bf16(af[rt], bf[ct], acc[rt][ct], 0,0,0);
    }
  }

  // ---- epilogue: neg16 store + LDS-scratch moment partials ----
  int jbase = bj*128 + wj*64;
  float esqv[4]; bool val[4]; int jcol[4];
#pragma unroll
  for (int ct=0; ct<4; ++ct){
    jcol[ct] = jbase + ct*16 + l16;
    val[ct] = jcol[ct] < N_NODE;
    esqv[ct] = esq[jcol[ct]];
  }

  __syncthreads();   // staging LDS now dead; safe to reuse
  float* red = (float*)smem;   // [3][128][32] fp32 = 49152 B
  int col = wj*16 + l16;

  size_t tBase = ((size_t)bj*NCHB + biL)*16384;
#pragma unroll
  for (int rt=0; rt<4; ++rt){
    _Float16 h16[16];
#pragma unroll
    for (int reg=0; reg<4; ++reg){
      int il = wi*64 + rt*16 + quad*4 + reg;
      int i  = bi*128 + il;
      int p  = i & (BATCH-1);
      int li = pairs[2*p], ri = pairs[2*p+1];
      float av = asq[i];
      float s=0.f, q=0.f, mn=1e30f;
#pragma unroll
      for (int ct=0; ct<4; ++ct){
        float neg = (av + esqv[ct]) - 2.f*acc[rt][ct][reg];
        s += neg;
        q = fmaf(neg, neg, q);
        bool bad = (jcol[ct]==li) | (jcol[ct]==ri) | (!val[ct]);
        mn = fminf(mn, bad ? 1e30f : neg);
        h16[reg*4+ct] = (_Float16)neg;
      }
      red[        il*32 + col] = s;
      red[4096 +  il*32 + col] = q;
      red[8192 +  il*32 + col] = mn;
    }
    _Float16* dst = neg16 + tBase + ((size_t)(wave*4 + rt))*1024 + lane*16;
    *(half8*)(dst)     = *(half8*)&h16[0];
    *(half8*)(dst + 8) = *(half8*)&h16[8];
  }
  __syncthreads();
  if (tid < 128){
    int il = tid;
    float s = 0.f, q = 0.f, mn = 1e30f;
#pragma unroll
    for (int c4=0; c4<8; ++c4){
      f32x4 sv = *(f32x4*)&red[il*32 + c4*4];
      s += sv[0]+sv[1]+sv[2]+sv[3];
    }
#pragma unroll
    for (int c4=0; c4<8; ++c4){
      f32x4 qv = *(f32x4*)&red[4096 + il*32 + c4*4];
      q += qv[0]+qv[1]+qv[2]+qv[3];
    }
#pragma unroll
    for (int c4=0; c4<8; ++c4){
      f32x4 mv = *(f32x4*)&red[8192 + il*32 + c4*4];
      mn = fminf(mn, fminf(fminf(mv[0],mv[1]), fminf(mv[2],mv[3])));
    }
    int i = bi*128 + il;
    atomicAdd(rs1+i, s);
    atomicAdd(rs2+i, q);
    atomicMinF(rmin+i, mn);
  }
}

// ---------------- streaming pass 2 (exp) over stored fp16 neg ----------------
__global__ __launch_bounds__(256) void k_p2s(
    const _Float16* __restrict__ neg16, const float* __restrict__ CC, const float* __restrict__ AL,
    const int* __restrict__ pairs, float* __restrict__ rexp, int biOff)
{
  __shared__ float red[256];
  int tid = threadIdx.x;
  int wave = tid>>6, lane = tid&63, quad = lane>>4, l16 = lane&15;
  int biL = blockIdx.x, bj = blockIdx.y;
  int bi = biOff + biL;
  int wi = wave>>1, wj = wave&1;
  int jbase = bj*128 + wj*64;
  bool val[4]; int jcol[4];
#pragma unroll
  for (int ct=0; ct<4; ++ct){
    jcol[ct] = jbase + ct*16 + l16;
    val[ct] = jcol[ct] < N_NODE;
  }
  size_t tBase = ((size_t)bj*NCHB + biL)*16384;
#pragma unroll
  for (int rt=0; rt<4; ++rt){
    const _Float16* src = neg16 + tBase + ((size_t)(wave*4 + rt))*1024 + lane*16;
    half8 v0 = *(const half8*)(src);
    half8 v1 = *(const half8*)(src + 8);
    _Float16 h16[16];
    *(half8*)&h16[0] = v0; *(half8*)&h16[8] = v1;
#pragma unroll
    for (int reg=0; reg<4; ++reg){
      int il = wi*64 + rt*16 + quad*4 + reg;
      int i  = bi*128 + il;
      int p  = i & (BATCH-1);
      int li = pairs[2*p], ri = pairs[2*p+1];
      float C = CC[i], A = AL[i];
      float s = 0.f;
#pragma unroll
      for (int ct=0; ct<4; ++ct){
        float neg = (float)h16[reg*4+ct];
        bool bad = (jcol[ct]==li) | (jcol[ct]==ri) | (!val[ct]);
        s += bad ? 0.f : __expf(fmaf(-A, neg, C));
      }
#pragma unroll
      for (int m=1;m<16;m<<=1) s += __shfl_xor(s,m,64);
      if (l16 == 0) red[il*2+wj] = s;
    }
  }
  __syncthreads();
  if (tid < 128){
    int i = bi*128 + tid;
    atomicAdd(rexp+i, red[tid*2] + red[tid*2+1]);
  }
}

// ---------------- per-row special-column dots ----------------
__global__ __launch_bounds__(256) void k_corr(
    const int* __restrict__ pairs, const __bf16* __restrict__ Ap, const __bf16* __restrict__ Ep,
    const float* __restrict__ asq, const float* __restrict__ esq,
    float* __restrict__ negl, float* __restrict__ negr, int iOff)
{
  int wave = threadIdx.x>>6, lane = threadIdx.x&63;
  int i = iOff + blockIdx.x*4 + wave;
  int p = i & (BATCH-1);
  int li = pairs[2*p], ri = pairs[2*p+1];
  const __bf16* Ar = Ap + (size_t)(i>>7)*TILE_ELEMS;  int ra = i&127;
  const __bf16* E1 = Ep + (size_t)(li>>7)*TILE_ELEMS; int r1 = li&127;
  const __bf16* E2 = Ep + (size_t)(ri>>7)*TILE_ELEMS; int r2 = ri&127;
  float d1=0.f, d2=0.f;
  for (int c=lane; c<96; c+=64){
    int kb = c>>2, q = c&3;
    bf16x8 a  = *(const bf16x8*)(Ar + kb*KBLK_ELEMS + swz_off(ra, q));
    bf16x8 e1 = *(const bf16x8*)(E1 + kb*KBLK_ELEMS + swz_off(r1, q));
    bf16x8 e2 = *(const bf16x8*)(E2 + kb*KBLK_ELEMS + swz_off(r2, q));
#pragma unroll
    for (int e=0;e<8;e++){
      d1 = fmaf((float)a[e], (float)e1[e], d1);
      d2 = fmaf((float)a[e], (float)e2[e], d2);
    }
  }
  d1 = waveSum(d1); d2 = waveSum(d2);
  if (lane==0){
    float av = asq[i];
    negl[i] = av + esq[li] - 2.f*d1;
    negr[i] = av + esq[ri] - 2.f*d2;
  }
}

// ---------------- stats ----------------
__global__ __launch_bounds__(256) void k_stats(
    const float* __restrict__ rs1, const float* __restrict__ rs2, const float* __restrict__ rmin,
    const float* __restrict__ negl, const float* __restrict__ negr,
    const float* __restrict__ asq, const float* __restrict__ pos, const int* __restrict__ pairs,
    float* __restrict__ MM, float* __restrict__ CC, float* __restrict__ AL, float* __restrict__ rexp, int iOff)
{
  int i = iOff + blockIdx.x*256 + threadIdx.x;
  int p = i & (BATCH-1);
  int li = pairs[2*p], ri = pairs[2*p+1];
  float K = pos[p] + GAMMA_C;
  float av = asq[i];
  float S1 = rs1[i] - (float)PADN*av;
  float S2 = rs2[i] - (float)PADN*av*av;
  float nl = negl[i], nr = negr[i];
  float Sx, Sxx, mx;
  const float invN = 1.f/(float)N_NODE;
  if (li != ri){
    Sx  = -(S1 - nl - nr) - 2.f*K;
    Sxx = (S2 - nl*nl - nr*nr) + 2.f*K*K;
    mx  = fmaxf(K - rmin[i], 0.f);
    float mu = K + Sx*invN;
    float m2 = Sx*invN;
    float var = Sxx*invN - m2*m2;
    float sd = sqrtf(fmaxf(var, 1e-30f));
    float M = LAMB_C*(mx-mu)/sd + TAU_C;
    MM[i] = M; CC[i] = LAMB_C*(K-mu)/sd + TAU_C - M; AL[i] = LAMB_C/sd;
    rexp[i] = 2.f*__expf(LAMB_C*(0.f-mu)/sd + TAU_C - M);
  } else {
    float lossm = nl - K;
    float x = lossm - K;
    Sx  = -(S1 - nl) + x;
    Sxx = (S2 - nl*nl) + x*x;
    mx  = fmaxf(K - rmin[i], lossm);
    float mu = K + Sx*invN;
    float m2 = Sx*invN;
    float var = Sxx*invN - m2*m2;
    float sd = sqrtf(fmaxf(var, 1e-30f));
    float M = LAMB_C*(mx-mu)/sd + TAU_C;
    MM[i] = M; CC[i] = LAMB_C*(K-mu)/sd + TAU_C - M; AL[i] = LAMB_C/sd;
    rexp[i] = __expf(LAMB_C*(lossm-mu)/sd + TAU_C - M);
  }
}

__global__ __launch_bounds__(256) void k_final(const float* __restrict__ mm, const float* __restrict__ rexp, float* __restrict__ out){
  __shared__ float red[256];
  float s = 0.f;
  for (int i=threadIdx.x; i<NROWA; i+=256) s += mm[i] + logf(rexp[i]);
  red[threadIdx.x] = s; __syncthreads();
  for (int st=128; st>0; st>>=1){ if (threadIdx.x<st) red[threadIdx.x]+=red[threadIdx.x+st]; __syncthreads(); }
  if (threadIdx.x==0) out[0] = red[0]*(1.f/BATCH);
}

extern "C" void kernel_launch(void* const* d_in, const int* in_sizes, int n_in,
                              void* d_out, int out_size, void* d_ws, size_t ws_size,
                              hipStream_t stream) {
  const int*   pairs   = (const int*)d_in[0];
  const int*   ent_adj = (const int*)d_in[1];
  const int*   rel_adj = (const int*)d_in[2];
  const int*   adj     = (const int*)d_in[3];
  const int*   r_index = (const int*)d_in[4];
  const float* r_val   = (const float*)d_in[5];
  const float* ent_emb = (const float*)d_in[7];
  const float* rel_emb = (const float*)d_in[8];
  const float* attn_e  = (const float*)d_in[9];
  const float* attn_r  = (const float*)d_in[10];

  char* base = (char*)d_ws;
  size_t off = 0;
  auto take = [&](size_t bytes)->char*{
    char* p = base + off;
    off = (off + bytes + 511) & ~(size_t)511;
    return p;
  };
  // persistent GEMM-phase region (~53.5 MB)
  __bf16* EP    = (__bf16*)take((size_t)NTILE_E*TILE_ELEMS*2);
  __bf16* AP    = (__bf16*)take((size_t)NTILE_A*TILE_ELEMS*2);
  float*  ESQ   = (float*)take((size_t)EPAD*4);
  float*  ASQ   = (float*)take((size_t)NROWA*4);
  float*  POS   = (float*)take((size_t)BATCH*4);
  float*  RS1   = (float*)take((size_t)NROWA*4);
  float*  RS2   = (float*)take((size_t)NROWA*4);
  float*  RMIN  = (float*)take((size_t)NROWA*4);
  float*  NEGL  = (float*)take((size_t)NROWA*4);
  float*  NEGR  = (float*)take((size_t)NROWA*4);
  float*  MM    = (float*)take((size_t)NROWA*4);
  float*  CCv   = (float*)take((size_t)NROWA*4);
  float*  ALv   = (float*)take((size_t)NROWA*4);
  float*  REXP  = (float*)take((size_t)NROWA*4);

  // graph-phase region (dead by GEMM time) — overlapped by NEG16 (123 MB per chunk)
  size_t offG = off;
  __bf16* OUTB = (__bf16*)take((size_t)N_NODE*OUTD*2);     // 46.1 MB, interleaved layout
  __bf16* TRI  = (__bf16*)take((size_t)N_TRI*DIM*2);       // 51.2 MB
  float*  ATT4 = (float*)take((size_t)4*N_TRI*4);          // 3.2 MB
  int* RP_E  = (int*)take((size_t)(N_NODE+1)*4);
  int* RP_R  = (int*)take((size_t)(N_NODE+1)*4);
  int* RP_A  = (int*)take((size_t)(N_NODE+1)*4);
  int* IDX_E = (int*)take((size_t)N_TRI*4);
  int* IDX_R = (int*)take((size_t)N_TRI*4);
  int* IDX_A = (int*)take((size_t)N_TRI*4);
  int* CNT6  = (int*)take((size_t)6*N_NODE*4);
  int* BTOT  = (int*)take((size_t)3*NBLK_SCAN*4);
  int* CNT_E = CNT6,            *CNT_R = CNT6 + N_NODE,   *CNT_A = CNT6 + 2*N_NODE;
  int* CUR_E = CNT6 + 3*N_NODE, *CUR_R = CNT6 + 4*N_NODE, *CUR_A = CNT6 + 5*N_NODE;

  _Float16* NEG16 = (_Float16*)(base + offG);   // 123.2 MB per chunk

  const int* cols = adj + N_TRI;

  // ---- init ----
  k_fill<<<192,256,0,stream>>>((float*)CNT6, (long)6*N_NODE, 0.f);

  // ---- CSR builds ----
  k_hist<<<782,256,0,stream>>>(ent_adj, CNT_E);
  k_hist<<<782,256,0,stream>>>(rel_adj, CNT_R);
  k_hist<<<782,256,0,stream>>>(adj,     CNT_A);
  dim3 gsA(NBLK_SCAN, 3, 1);
  k_scanA<<<gsA,256,0,stream>>>(CNT_E, CNT_R, CNT_A, RP_E, RP_R, RP_A, BTOT, N_NODE);
  k_scanB<<<3,128,0,stream>>>(BTOT, RP_E, RP_R, RP_A, N_NODE);
  k_scanC<<<gsA,256,0,stream>>>(RP_E, RP_R, RP_A, BTOT, N_NODE);
  k_place<<<782,256,0,stream>>>(ent_adj, ent_adj+N_TRI, RP_E, CUR_E, IDX_E, 1);
  k_place<<<782,256,0,stream>>>(rel_adj, rel_adj+N_TRI, RP_R, CUR_R, IDX_R, 1);
  k_place<<<782,256,0,stream>>>(adj,     (const int*)0, RP_A, CUR_A, IDX_A, 0);

  // ---- feature pipeline (interleaved bf16 features) ----
  k_feat0<<<7500,256,0,stream>>>(RP_E, IDX_E, RP_R, IDX_R, ent_emb, rel_emb, OUTB);
  k_trinorm<<<25000,256,0,stream>>>(r_index+N_TRI, r_val, rel_emb, TRI, attn_e, attn_r, ATT4);
  k_gat<<<7500,256,0,stream>>>(RP_A, IDX_A, cols, TRI,
                               ATT4 + 0*N_TRI, ATT4 + 2*N_TRI, OUTB, 0, 256);
  k_gat<<<7500,256,0,stream>>>(RP_A, IDX_A, cols, TRI,
                               ATT4 + 1*N_TRI, ATT4 + 3*N_TRI, OUTB, 256, 512);

  // ---- loss prep ----
  k_packE<<<7520,256,0,stream>>>(OUTB, EP, ESQ);
  k_packA<<<512,256,0,stream>>>(pairs, EP, OUTB, ESQ, AP, ASQ, POS);
  k_fill<<<16,256,0,stream>>>(RS1, (long)NROWA, 0.f);
  k_fill<<<16,256,0,stream>>>(RS2, (long)NROWA, 0.f);
  k_fill<<<16,256,0,stream>>>(RMIN,(long)NROWA, 1e30f);

  // ---- loss phase: 2 row-chunks; moments fused into GEMM epilogue ----
  for (int ch=0; ch<NTILE_A/NCHB; ++ch){
    int biOff = ch*NCHB;
    int iOff  = biOff*128;
    dim3 gg(NCHB, NTILE_E, 1);
    k_gemm<<<gg,256,0,stream>>>(AP, EP, ASQ, ESQ, pairs, RS1, RS2, RMIN, NEG16, biOff);
    k_corr<<<NCHB*128/4,256,0,stream>>>(pairs, AP, EP, ASQ, ESQ, NEGL, NEGR, iOff);
    k_stats<<<NCHB*128/256,256,0,stream>>>(RS1, RS2, RMIN, NEGL, NEGR, ASQ, POS, pairs,
                                           MM, CCv, ALv, REXP, iOff);
    k_p2s<<<gg,256,0,stream>>>(NEG16, CCv, ALv, pairs, REXP, biOff);
  }
  k_final<<<1,256,0,stream>>>(MM, REXP, (float*)d_out);
}